// Round 1
// baseline (1165.248 us; speedup 1.0000x reference)
//
#include <hip/hip_runtime.h>
#include <hip/hip_bf16.h>

#define DIM 192
#define HEADS 6
#define QKV_N 576
#define HIDDEN 768
#define M_ROWS 65536

typedef unsigned short ushortT;

__device__ __forceinline__ float bf2f(ushortT u) {
    union { unsigned int i; float f; } c; c.i = ((unsigned int)u) << 16; return c.f;
}
__device__ __forceinline__ ushortT f2bf(float f) {
    union { float f; unsigned int i; } c; c.f = f;
    unsigned int i = c.i;
    return (ushortT)((i + 0x7fffu + ((i >> 16) & 1u)) >> 16);
}

// ---------------- pos-bias MLP: 961 rows of (di,dj) -> [961][6] table ----------------
__device__ __forceinline__ void ln_relu_mm12(const float* in, const float* g, const float* b,
                                             const float* w, const float* bb, float* out, int nout) {
    float m = 0.f;
#pragma unroll
    for (int j = 0; j < 12; ++j) m += in[j];
    m *= (1.0f / 12.0f);
    float v = 0.f;
#pragma unroll
    for (int j = 0; j < 12; ++j) { float d = in[j] - m; v += d * d; }
    v *= (1.0f / 12.0f);
    float r = rsqrtf(v + 1e-5f);
    float t[12];
#pragma unroll
    for (int j = 0; j < 12; ++j) t[j] = fmaxf((in[j] - m) * r * g[j] + b[j], 0.0f);
    for (int j2 = 0; j2 < nout; ++j2) {
        float s = bb[j2];
#pragma unroll
        for (int j = 0; j < 12; ++j) s = fmaf(t[j], w[j * nout + j2], s);
        out[j2] = s;
    }
}

__global__ void pos_mlp_kernel(const float* __restrict__ pw, const float* __restrict__ pb,
                               const float* __restrict__ g1, const float* __restrict__ b1,
                               const float* __restrict__ w1, const float* __restrict__ bb1,
                               const float* __restrict__ g2, const float* __restrict__ b2,
                               const float* __restrict__ w2, const float* __restrict__ bb2,
                               const float* __restrict__ g3, const float* __restrict__ b3,
                               const float* __restrict__ w3, const float* __restrict__ bb3,
                               float* __restrict__ btab) {
    int t = blockIdx.x * blockDim.x + threadIdx.x;
    if (t >= 961) return;
    float di = (float)(t / 31 - 15);
    float dj = (float)(t % 31 - 15);
    float a[12], h[12];
#pragma unroll
    for (int j = 0; j < 12; ++j) a[j] = di * pw[j] + dj * pw[12 + j] + pb[j];
    ln_relu_mm12(a, g1, b1, w1, bb1, h, 12);
    ln_relu_mm12(h, g2, b2, w2, bb2, a, 12);
    float outh[6];
    ln_relu_mm12(a, g3, b3, w3, bb3, outh, 6);
#pragma unroll
    for (int hh = 0; hh < 6; ++hh) btab[t * 6 + hh] = outh[hh];
}

// ---------------- expand bias to BT[h][key m][query n] for coalesced attn reads ------
__global__ __launch_bounds__(256) void bias_expand_kernel(const float* __restrict__ btab,
                                                          float* __restrict__ BT) {
    int blk = blockIdx.x;            // h*256 + m
    int h = blk >> 8;
    int m = blk & 255;
    int n = threadIdx.x;
    int dii = (n >> 4) - (m >> 4) + 15;
    int djj = (n & 15) - (m & 15) + 15;
    BT[(size_t)blk * 256 + n] = btab[(dii * 31 + djj) * 6 + h];
}

// ---------------- LayerNorm fp32 -> bf16, one wave per row (192) ---------------------
__global__ __launch_bounds__(256) void ln_kernel(const float* __restrict__ x,
                                                 const float* __restrict__ g,
                                                 const float* __restrict__ b,
                                                 ushortT* __restrict__ out) {
    int lane = threadIdx.x & 63;
    size_t row = (size_t)blockIdx.x * 4 + (threadIdx.x >> 6);
    const float* xr = x + row * DIM;
    float v0 = xr[lane], v1 = xr[lane + 64], v2 = xr[lane + 128];
    float s = v0 + v1 + v2;
    float ss = v0 * v0 + v1 * v1 + v2 * v2;
#pragma unroll
    for (int off = 32; off > 0; off >>= 1) {
        s += __shfl_xor(s, off);
        ss += __shfl_xor(ss, off);
    }
    float mean = s * (1.0f / DIM);
    float rstd = rsqrtf(ss * (1.0f / DIM) - mean * mean + 1e-5f);
    ushortT* o = out + row * DIM;
    o[lane]       = f2bf((v0 - mean) * rstd * g[lane]       + b[lane]);
    o[lane + 64]  = f2bf((v1 - mean) * rstd * g[lane + 64]  + b[lane + 64]);
    o[lane + 128] = f2bf((v2 - mean) * rstd * g[lane + 128] + b[lane + 128]);
}

// ---------------- generic tiled GEMM: C = A(bf16)[M,K] @ W(f32)[K,N] + bias ----------
// MODE 0: out bf16 ; MODE 1: gelu -> bf16 ; MODE 2: f32 out = resid + v ; MODE 3: f32 out += v
template <int MODE>
__global__ __launch_bounds__(256) void gemm_kernel(const ushortT* __restrict__ A,
                                                   const float* __restrict__ W,
                                                   const float* __restrict__ bias,
                                                   const float* __restrict__ resid,
                                                   void* __restrict__ outp,
                                                   int N, int K) {
    __shared__ float As[16][64];
    __shared__ float Ws[16][68];
    int t = threadIdx.x;
    int bm = blockIdx.x * 64;
    int bn = blockIdx.y * 64;
    int tx = t & 15, ty = t >> 4;
    float acc[4][4] = {};
    int arow = t >> 2, acol = (t & 3) * 4;
    int wrow = t >> 4, wcol = (t & 15) * 4;
    const ushortT* aptr = A + (size_t)(bm + arow) * K + acol;
    const float* wptr = W + (size_t)wrow * N + bn + wcol;
    for (int k0 = 0; k0 < K; k0 += 16) {
        ushort4 av = *(const ushort4*)(aptr + k0);
        As[acol + 0][arow] = bf2f(av.x);
        As[acol + 1][arow] = bf2f(av.y);
        As[acol + 2][arow] = bf2f(av.z);
        As[acol + 3][arow] = bf2f(av.w);
        float4 wv = *(const float4*)(wptr + (size_t)k0 * N);
        *(float4*)&Ws[wrow][wcol] = wv;
        __syncthreads();
#pragma unroll
        for (int k = 0; k < 16; ++k) {
            float4 a4 = *(const float4*)&As[k][ty * 4];
            float4 b4 = *(const float4*)&Ws[k][tx * 4];
            acc[0][0] = fmaf(a4.x, b4.x, acc[0][0]);
            acc[0][1] = fmaf(a4.x, b4.y, acc[0][1]);
            acc[0][2] = fmaf(a4.x, b4.z, acc[0][2]);
            acc[0][3] = fmaf(a4.x, b4.w, acc[0][3]);
            acc[1][0] = fmaf(a4.y, b4.x, acc[1][0]);
            acc[1][1] = fmaf(a4.y, b4.y, acc[1][1]);
            acc[1][2] = fmaf(a4.y, b4.z, acc[1][2]);
            acc[1][3] = fmaf(a4.y, b4.w, acc[1][3]);
            acc[2][0] = fmaf(a4.z, b4.x, acc[2][0]);
            acc[2][1] = fmaf(a4.z, b4.y, acc[2][1]);
            acc[2][2] = fmaf(a4.z, b4.z, acc[2][2]);
            acc[2][3] = fmaf(a4.z, b4.w, acc[2][3]);
            acc[3][0] = fmaf(a4.w, b4.x, acc[3][0]);
            acc[3][1] = fmaf(a4.w, b4.y, acc[3][1]);
            acc[3][2] = fmaf(a4.w, b4.z, acc[3][2]);
            acc[3][3] = fmaf(a4.w, b4.w, acc[3][3]);
        }
        __syncthreads();
    }
#pragma unroll
    for (int i = 0; i < 4; ++i) {
        size_t row = (size_t)bm + ty * 4 + i;
#pragma unroll
        for (int j = 0; j < 4; ++j) {
            int col = bn + tx * 4 + j;
            float v = acc[i][j] + bias[col];
            size_t off = row * (size_t)N + col;
            if (MODE == 0) {
                ((ushortT*)outp)[off] = f2bf(v);
            } else if (MODE == 1) {
                v = 0.5f * v * (1.0f + erff(v * 0.70710678118654752f));
                ((ushortT*)outp)[off] = f2bf(v);
            } else if (MODE == 2) {
                ((float*)outp)[off] = resid[off] + v;
            } else {
                ((float*)outp)[off] += v;
            }
        }
    }
}

// ---------------- attention: one block per (window, head), online softmax ------------
__global__ __launch_bounds__(256) void attn_kernel(const ushortT* __restrict__ qkv,
                                                   const float* __restrict__ BT,
                                                   ushortT* __restrict__ O) {
    __shared__ float Kt[32][256];
    __shared__ float Vt[32][256];
    int wh = blockIdx.x;         // w*6 + h
    int w = wh / 6;
    int h = wh - w * 6;
    int wi = w >> 4, wj = w & 15;
    int tid = threadIdx.x;
    int ti = tid >> 4, tj = tid & 15;
    size_t grow = (size_t)(wi * 16 + ti) * 256 + wj * 16 + tj;
    const ushortT* base = qkv + grow * QKV_N + h * 32;
    const float SCALE = 0.17677669529663687f;  // 1/sqrt(32)
    float q[32];
#pragma unroll
    for (int c = 0; c < 32; c += 4) {
        ushort4 u = *(const ushort4*)(base + c);
        q[c + 0] = bf2f(u.x) * SCALE;
        q[c + 1] = bf2f(u.y) * SCALE;
        q[c + 2] = bf2f(u.z) * SCALE;
        q[c + 3] = bf2f(u.w) * SCALE;
        ushort4 ku = *(const ushort4*)(base + 192 + c);
        Kt[c + 0][tid] = bf2f(ku.x);
        Kt[c + 1][tid] = bf2f(ku.y);
        Kt[c + 2][tid] = bf2f(ku.z);
        Kt[c + 3][tid] = bf2f(ku.w);
        ushort4 vu = *(const ushort4*)(base + 384 + c);
        Vt[c + 0][tid] = bf2f(vu.x);
        Vt[c + 1][tid] = bf2f(vu.y);
        Vt[c + 2][tid] = bf2f(vu.z);
        Vt[c + 3][tid] = bf2f(vu.w);
    }
    __syncthreads();
    const float* btp = BT + (size_t)h * 65536 + tid;  // BT[h][m][n=tid]
    float mrun = -3.4e38f, l = 0.f;
    float o[32];
#pragma unroll
    for (int d = 0; d < 32; ++d) o[d] = 0.f;
    for (int mm = 0; mm < 256; ++mm) {
        float s = btp[mm << 8];
#pragma unroll
        for (int d = 0; d < 32; ++d) s = fmaf(q[d], Kt[d][mm], s);
        float mnew = fmaxf(mrun, s);
        float corr = __expf(mrun - mnew);
        float p = __expf(s - mnew);
        l = l * corr + p;
#pragma unroll
        for (int d = 0; d < 32; ++d) o[d] = fmaf(o[d], corr, p * Vt[d][mm]);
        mrun = mnew;
    }
    float inv = 1.0f / l;
    ushortT* op = O + grow * DIM + h * 32;
#pragma unroll
    for (int c = 0; c < 32; c += 4) {
        ushort4 u;
        u.x = f2bf(o[c + 0] * inv);
        u.y = f2bf(o[c + 1] * inv);
        u.z = f2bf(o[c + 2] * inv);
        u.w = f2bf(o[c + 3] * inv);
        *(ushort4*)(op + c) = u;
    }
}

// ---------------- launch --------------------------------------------------------------
extern "C" void kernel_launch(void* const* d_in, const int* in_sizes, int n_in,
                              void* d_out, int out_size, void* d_ws, size_t ws_size,
                              hipStream_t stream) {
    const float* x        = (const float*)d_in[0];
    const float* gamma1   = (const float*)d_in[1];
    const float* beta1    = (const float*)d_in[2];
    const float* qkv_w    = (const float*)d_in[3];
    const float* qkv_b    = (const float*)d_in[4];
    const float* proj_w   = (const float*)d_in[5];
    const float* proj_b   = (const float*)d_in[6];
    const float* pos_proj_w = (const float*)d_in[7];
    const float* pos_proj_b = (const float*)d_in[8];
    const float* ln1_g    = (const float*)d_in[9];
    const float* ln1_b    = (const float*)d_in[10];
    const float* pos1_w   = (const float*)d_in[11];
    const float* pos1_b   = (const float*)d_in[12];
    const float* ln2_g    = (const float*)d_in[13];
    const float* ln2_b    = (const float*)d_in[14];
    const float* pos2_w   = (const float*)d_in[15];
    const float* pos2_b   = (const float*)d_in[16];
    const float* ln3_g    = (const float*)d_in[17];
    const float* ln3_b    = (const float*)d_in[18];
    const float* pos3_w   = (const float*)d_in[19];
    const float* pos3_b   = (const float*)d_in[20];
    const float* gamma2   = (const float*)d_in[21];
    const float* beta2    = (const float*)d_in[22];
    const float* fc1_w    = (const float*)d_in[23];
    const float* fc1_b    = (const float*)d_in[24];
    const float* fc2_w    = (const float*)d_in[25];
    const float* fc2_b    = (const float*)d_in[26];
    float* out = (float*)d_out;

    char* ws = (char*)d_ws;
    // region0: qkv (75.5MB) then y1 (100.7MB)
    ushortT* qkv = (ushortT*)(ws + 0);
    ushortT* y1  = (ushortT*)(ws + 0);
    // region1: xn -> O -> xn2 (25.2MB)
    ushortT* xn  = (ushortT*)(ws + 100663296);
    ushortT* Obuf = xn;
    ushortT* xn2 = xn;
    float* btab = (float*)(ws + 125829120);        // 961*6 floats
    float* BT   = (float*)(ws + 125861888);        // 6*256*256 floats

    // 1. position-bias MLP table
    pos_mlp_kernel<<<4, 256, 0, stream>>>(pos_proj_w, pos_proj_b,
                                          ln1_g, ln1_b, pos1_w, pos1_b,
                                          ln2_g, ln2_b, pos2_w, pos2_b,
                                          ln3_g, ln3_b, pos3_w, pos3_b, btab);
    // 2. expand to BT[h][m][n]
    bias_expand_kernel<<<1536, 256, 0, stream>>>(btab, BT);
    // 3. LN1: x -> xn (bf16)
    ln_kernel<<<M_ROWS / 4, 256, 0, stream>>>(x, gamma1, beta1, xn);
    // 4. QKV GEMM: xn @ qkv_w -> qkv (bf16)
    gemm_kernel<0><<<dim3(M_ROWS / 64, QKV_N / 64), 256, 0, stream>>>(
        xn, qkv_w, qkv_b, nullptr, qkv, QKV_N, DIM);
    // 5. attention per (window, head) -> Obuf (bf16) [overwrites xn]
    attn_kernel<<<1536, 256, 0, stream>>>(qkv, BT, Obuf);
    // 6. proj GEMM + residual -> d_out (f32)  x2 = x + O @ proj_w + b
    gemm_kernel<2><<<dim3(M_ROWS / 64, DIM / 64), 256, 0, stream>>>(
        Obuf, proj_w, proj_b, x, out, DIM, DIM);
    // 7. LN2: d_out -> xn2 (bf16) [overwrites Obuf]
    ln_kernel<<<M_ROWS / 4, 256, 0, stream>>>(out, gamma2, beta2, xn2);
    // 8. fc1 + GELU: xn2 @ fc1_w -> y1 (bf16) [overwrites qkv]
    gemm_kernel<1><<<dim3(M_ROWS / 64, HIDDEN / 64), 256, 0, stream>>>(
        xn2, fc1_w, fc1_b, nullptr, y1, HIDDEN, DIM);
    // 9. fc2: y1 @ fc2_w added into d_out (f32)
    gemm_kernel<3><<<dim3(M_ROWS / 64, DIM / 64), 256, 0, stream>>>(
        y1, fc2_w, fc2_b, nullptr, out, DIM, HIDDEN);
}

// Round 2
// 360.090 us; speedup vs baseline: 3.2360x; 3.2360x over previous
//
#include <hip/hip_runtime.h>
#include <hip/hip_bf16.h>

#define DIM 192
#define HEADS 6
#define QKV_N 576
#define HIDDEN 768
#define M_ROWS 65536

typedef unsigned short ushortT;
typedef __attribute__((ext_vector_type(8))) short short8v;
typedef __attribute__((ext_vector_type(4))) float f32x4;

__device__ __forceinline__ float bf2f(ushortT u) {
    union { unsigned int i; float f; } c; c.i = ((unsigned int)u) << 16; return c.f;
}
__device__ __forceinline__ ushortT f2bf(float f) {
    union { float f; unsigned int i; } c; c.f = f;
    unsigned int i = c.i;
    return (ushortT)((i + 0x7fffu + ((i >> 16) & 1u)) >> 16);
}

#define GLOBAL_LOAD_LDS16(gp, lp) \
    __builtin_amdgcn_global_load_lds((const __attribute__((address_space(1))) void*)(gp), \
                                     (__attribute__((address_space(3))) void*)(lp), 16, 0, 0)

// ---------------- pos-bias MLP: 961 rows of (di,dj) -> [961][6] table ----------------
__device__ __forceinline__ void ln_relu_mm12(const float* in, const float* g, const float* b,
                                             const float* w, const float* bb, float* out, int nout) {
    float m = 0.f;
#pragma unroll
    for (int j = 0; j < 12; ++j) m += in[j];
    m *= (1.0f / 12.0f);
    float v = 0.f;
#pragma unroll
    for (int j = 0; j < 12; ++j) { float d = in[j] - m; v += d * d; }
    v *= (1.0f / 12.0f);
    float r = rsqrtf(v + 1e-5f);
    float t[12];
#pragma unroll
    for (int j = 0; j < 12; ++j) t[j] = fmaxf((in[j] - m) * r * g[j] + b[j], 0.0f);
    for (int j2 = 0; j2 < nout; ++j2) {
        float s = bb[j2];
#pragma unroll
        for (int j = 0; j < 12; ++j) s = fmaf(t[j], w[j * nout + j2], s);
        out[j2] = s;
    }
}

__global__ void pos_mlp_kernel(const float* __restrict__ pw, const float* __restrict__ pb,
                               const float* __restrict__ g1, const float* __restrict__ b1,
                               const float* __restrict__ w1, const float* __restrict__ bb1,
                               const float* __restrict__ g2, const float* __restrict__ b2,
                               const float* __restrict__ w2, const float* __restrict__ bb2,
                               const float* __restrict__ g3, const float* __restrict__ b3,
                               const float* __restrict__ w3, const float* __restrict__ bb3,
                               float* __restrict__ btab) {
    int t = blockIdx.x * blockDim.x + threadIdx.x;
    if (t >= 961) return;
    float di = (float)(t / 31 - 15);
    float dj = (float)(t % 31 - 15);
    float a[12], h[12];
#pragma unroll
    for (int j = 0; j < 12; ++j) a[j] = di * pw[j] + dj * pw[12 + j] + pb[j];
    ln_relu_mm12(a, g1, b1, w1, bb1, h, 12);
    ln_relu_mm12(h, g2, b2, w2, bb2, a, 12);
    float outh[6];
    ln_relu_mm12(a, g3, b3, w3, bb3, outh, 6);
#pragma unroll
    for (int hh = 0; hh < 6; ++hh) btab[t * 6 + hh] = outh[hh];
}

// ---------------- expand bias to BTq[h][query q][key kv] ------------------------------
__global__ __launch_bounds__(256) void bias_expand_kernel(const float* __restrict__ btab,
                                                          float* __restrict__ BTq) {
    int blk = blockIdx.x;            // h*256 + q
    int h = blk >> 8;
    int q = blk & 255;
    int kv = threadIdx.x;
    int dii = (q >> 4) - (kv >> 4) + 15;
    int djj = (q & 15) - (kv & 15) + 15;
    BTq[(size_t)blk * 256 + kv] = btab[(dii * 31 + djj) * 6 + h];
}

// ---------------- weight transpose + bf16 convert: W[K][N] f32 -> Wt[N][K] bf16 ------
__global__ __launch_bounds__(256) void transpose_w_kernel(const float* __restrict__ W,
                                                          ushortT* __restrict__ Wt,
                                                          int K, int N) {
    __shared__ float tile[32][33];
    int bx = blockIdx.x * 32;   // n
    int by = blockIdx.y * 32;   // k
    int tx = threadIdx.x, ty = threadIdx.y;   // 32, 8
#pragma unroll
    for (int i = 0; i < 32; i += 8)
        tile[ty + i][tx] = W[(size_t)(by + ty + i) * N + bx + tx];
    __syncthreads();
#pragma unroll
    for (int i = 0; i < 32; i += 8)
        Wt[(size_t)(bx + ty + i) * K + by + tx] = f2bf(tile[tx][ty + i]);
}

// ---------------- LayerNorm fp32 -> bf16, one wave per row (192) ---------------------
__global__ __launch_bounds__(256) void ln_kernel(const float* __restrict__ x,
                                                 const float* __restrict__ g,
                                                 const float* __restrict__ b,
                                                 ushortT* __restrict__ out) {
    int lane = threadIdx.x & 63;
    size_t row = (size_t)blockIdx.x * 4 + (threadIdx.x >> 6);
    const float* xr = x + row * DIM;
    float v0 = xr[lane], v1 = xr[lane + 64], v2 = xr[lane + 128];
    float s = v0 + v1 + v2;
    float ss = v0 * v0 + v1 * v1 + v2 * v2;
#pragma unroll
    for (int off = 32; off > 0; off >>= 1) {
        s += __shfl_xor(s, off);
        ss += __shfl_xor(ss, off);
    }
    float mean = s * (1.0f / DIM);
    float rstd = rsqrtf(ss * (1.0f / DIM) - mean * mean + 1e-5f);
    ushortT* o = out + row * DIM;
    o[lane]       = f2bf((v0 - mean) * rstd * g[lane]       + b[lane]);
    o[lane + 64]  = f2bf((v1 - mean) * rstd * g[lane + 64]  + b[lane + 64]);
    o[lane + 128] = f2bf((v2 - mean) * rstd * g[lane + 128] + b[lane + 128]);
}

// ---------------- MFMA GEMM: C = A(bf16 [M][K]) @ Wt(bf16 [N][K])^T + bias -----------
// BM=128, BN=64, BK=64; 256 threads = 4 waves (2x2); per-wave 64x32 (acc[4][2] f32x4)
// MODE 0: bf16 out ; 1: gelu->bf16 ; 2: f32 out = resid + v ; 3: f32 out += v
template <int MODE>
__global__ __launch_bounds__(256) void mfma_gemm(const ushortT* __restrict__ A,
                                                 const ushortT* __restrict__ Wt,
                                                 const float* __restrict__ bias,
                                                 const float* __restrict__ resid,
                                                 void* __restrict__ outp,
                                                 int N, int K) {
    __shared__ ushortT As[128 * 64];
    __shared__ ushortT Bs[64 * 64];
    int tid = threadIdx.x;
    int lane = tid & 63, wid = tid >> 6;
    int l15 = lane & 15, l4 = lane >> 4;
    int wr = wid >> 1, wc = wid & 1;
    int bm = blockIdx.x * 128, bn = blockIdx.y * 64;

    f32x4 acc[4][2];
#pragma unroll
    for (int mf = 0; mf < 4; ++mf)
#pragma unroll
        for (int nf = 0; nf < 2; ++nf)
#pragma unroll
            for (int r = 0; r < 4; ++r) acc[mf][nf][r] = 0.f;

    const ushortT* agp = A + (size_t)(bm + (tid >> 3)) * K + (tid & 7) * 8;
    const ushortT* bgp = Wt + (size_t)(bn + (tid >> 3)) * K + (tid & 7) * 8;

    for (int k0 = 0; k0 < K; k0 += 64) {
#pragma unroll
        for (int i = 0; i < 4; ++i)
            GLOBAL_LOAD_LDS16(agp + (size_t)i * 32 * K + k0, As + i * 2048 + wid * 512);
#pragma unroll
        for (int i = 0; i < 2; ++i)
            GLOBAL_LOAD_LDS16(bgp + (size_t)i * 32 * K + k0, Bs + i * 2048 + wid * 512);
        __syncthreads();
#pragma unroll
        for (int ks = 0; ks < 2; ++ks) {
            short8v af[4], bf[2];
#pragma unroll
            for (int mf = 0; mf < 4; ++mf)
                af[mf] = *(const short8v*)&As[(wr * 64 + mf * 16 + l15) * 64 + ks * 32 + l4 * 8];
#pragma unroll
            for (int nf = 0; nf < 2; ++nf)
                bf[nf] = *(const short8v*)&Bs[(wc * 32 + nf * 16 + l15) * 64 + ks * 32 + l4 * 8];
#pragma unroll
            for (int mf = 0; mf < 4; ++mf)
#pragma unroll
                for (int nf = 0; nf < 2; ++nf)
                    acc[mf][nf] = __builtin_amdgcn_mfma_f32_16x16x32_bf16(af[mf], bf[nf], acc[mf][nf], 0, 0, 0);
        }
        __syncthreads();
    }
    // epilogue
#pragma unroll
    for (int mf = 0; mf < 4; ++mf) {
        size_t row = (size_t)bm + wr * 64 + mf * 16 + l4 * 4;
#pragma unroll
        for (int nf = 0; nf < 2; ++nf) {
            int col = bn + wc * 32 + nf * 16 + l15;
            float bv = bias[col];
#pragma unroll
            for (int r = 0; r < 4; ++r) {
                size_t off = (row + r) * (size_t)N + col;
                float v = acc[mf][nf][r] + bv;
                if (MODE == 0) {
                    ((ushortT*)outp)[off] = f2bf(v);
                } else if (MODE == 1) {
                    v = 0.5f * v * (1.0f + erff(v * 0.70710678118654752f));
                    ((ushortT*)outp)[off] = f2bf(v);
                } else if (MODE == 2) {
                    ((float*)outp)[off] = resid[off] + v;
                } else {
                    ((float*)outp)[off] += v;
                }
            }
        }
    }
}

// ---------------- MFMA flash attention: block per (window, head) ---------------------
// 4 waves x 64 q-rows; KV chunks of 32; Q/K frags direct from global; V^T + P in LDS.
__global__ __launch_bounds__(256) void attn_mfma_kernel(const ushortT* __restrict__ qkv,
                                                        const float* __restrict__ BTq,
                                                        ushortT* __restrict__ O) {
    __shared__ ushortT Vt[32][264];       // V^T padded: row stride 528B (33 granules)
    __shared__ ushortT Ps[4][64][40];     // per-wave P chunk, row stride 80B (5 granules)
    int wh = blockIdx.x;
    int w = wh / 6, h = wh - w * 6;
    int wi = w >> 4, wj = w & 15;
    int tid = threadIdx.x, lane = tid & 63, wid = tid >> 6;
    int l15 = lane & 15, l4 = lane >> 4;

    // stage V^T: thread t = kv token
    {
        int q = tid;
        size_t gr = (size_t)((wi * 16 + (q >> 4)) * 256 + wj * 16 + (q & 15));
        const ushortT* vp = qkv + gr * 576 + 384 + h * 32;
#pragma unroll
        for (int d0 = 0; d0 < 32; d0 += 8) {
            short8v u = *(const short8v*)(vp + d0);
#pragma unroll
            for (int j = 0; j < 8; ++j) Vt[d0 + j][q] = (ushortT)u[j];
        }
    }
    // Q fragments (A operand) direct from global
    short8v qf[4];
    int qbase = wid * 64;
#pragma unroll
    for (int mf = 0; mf < 4; ++mf) {
        int q = qbase + mf * 16 + l15;
        size_t gr = (size_t)((wi * 16 + (q >> 4)) * 256 + wj * 16 + (q & 15));
        qf[mf] = *(const short8v*)(qkv + gr * 576 + h * 32 + l4 * 8);
    }
    __syncthreads();

    float m_run[4][4], l_run[4][4];
    f32x4 accO[4][2];
#pragma unroll
    for (int mf = 0; mf < 4; ++mf)
#pragma unroll
        for (int r = 0; r < 4; ++r) {
            m_run[mf][r] = -1e30f;
            l_run[mf][r] = 0.f;
            accO[mf][0][r] = 0.f;
            accO[mf][1][r] = 0.f;
        }
    const float SCALE = 0.17677669529663687f;   // 1/sqrt(32)
    const float* bbase = BTq + ((size_t)h * 256 + qbase + 4 * l4) * 256 + l15;

    for (int kc = 0; kc < 8; ++kc) {
        // K fragments (B operand) direct from global
        short8v kf[2];
#pragma unroll
        for (int cf = 0; cf < 2; ++cf) {
            int kv = kc * 32 + cf * 16 + l15;
            size_t gr = (size_t)((wi * 16 + (kv >> 4)) * 256 + wj * 16 + (kv & 15));
            kf[cf] = *(const short8v*)(qkv + gr * 576 + 192 + h * 32 + l4 * 8);
        }
        // S = Q K^T
        f32x4 s[4][2];
#pragma unroll
        for (int mf = 0; mf < 4; ++mf)
#pragma unroll
            for (int cf = 0; cf < 2; ++cf) {
#pragma unroll
                for (int r = 0; r < 4; ++r) s[mf][cf][r] = 0.f;
                s[mf][cf] = __builtin_amdgcn_mfma_f32_16x16x32_bf16(qf[mf], kf[cf], s[mf][cf], 0, 0, 0);
            }
        // online softmax, write P (bf16) to wave-private LDS
#pragma unroll
        for (int mf = 0; mf < 4; ++mf) {
#pragma unroll
            for (int r = 0; r < 4; ++r) {
                int bo = (mf * 16 + r) * 256 + kc * 32;
                float sb0 = s[mf][0][r] * SCALE + bbase[bo];
                float sb1 = s[mf][1][r] * SCALE + bbase[bo + 16];
                float mx = fmaxf(sb0, sb1);
                mx = fmaxf(mx, __shfl_xor(mx, 1));
                mx = fmaxf(mx, __shfl_xor(mx, 2));
                mx = fmaxf(mx, __shfl_xor(mx, 4));
                mx = fmaxf(mx, __shfl_xor(mx, 8));
                float mold = m_run[mf][r];
                float mnew = fmaxf(mold, mx);
                float corr = __expf(mold - mnew);
                m_run[mf][r] = mnew;
                float p0 = __expf(sb0 - mnew);
                float p1 = __expf(sb1 - mnew);
                l_run[mf][r] = l_run[mf][r] * corr + p0 + p1;
                accO[mf][0][r] *= corr;
                accO[mf][1][r] *= corr;
                int prow = mf * 16 + 4 * l4 + r;
                Ps[wid][prow][l15] = f2bf(p0);
                Ps[wid][prow][16 + l15] = f2bf(p1);
            }
        }
        // PV: A = P (from LDS), B = V^T (from LDS)
        short8v vb[2];
#pragma unroll
        for (int nf = 0; nf < 2; ++nf)
            vb[nf] = *(const short8v*)&Vt[nf * 16 + l15][kc * 32 + l4 * 8];
#pragma unroll
        for (int mf = 0; mf < 4; ++mf) {
            short8v pa = *(const short8v*)&Ps[wid][mf * 16 + l15][l4 * 8];
#pragma unroll
            for (int nf = 0; nf < 2; ++nf)
                accO[mf][nf] = __builtin_amdgcn_mfma_f32_16x16x32_bf16(pa, vb[nf], accO[mf][nf], 0, 0, 0);
        }
    }
    // reduce l across the 16-lane col group, normalize, write O
#pragma unroll
    for (int mf = 0; mf < 4; ++mf)
#pragma unroll
        for (int r = 0; r < 4; ++r) {
            float l = l_run[mf][r];
            l += __shfl_xor(l, 1);
            l += __shfl_xor(l, 2);
            l += __shfl_xor(l, 4);
            l += __shfl_xor(l, 8);
            l_run[mf][r] = 1.0f / l;
        }
#pragma unroll
    for (int mf = 0; mf < 4; ++mf) {
        int q0 = qbase + mf * 16 + 4 * l4;
#pragma unroll
        for (int r = 0; r < 4; ++r) {
            int q = q0 + r;
            size_t gr = (size_t)((wi * 16 + (q >> 4)) * 256 + wj * 16 + (q & 15));
            ushortT* op = O + gr * 192 + h * 32 + l15;
            float inv = l_run[mf][r];
            op[0]  = f2bf(accO[mf][0][r] * inv);
            op[16] = f2bf(accO[mf][1][r] * inv);
        }
    }
}

// ---------------- launch --------------------------------------------------------------
extern "C" void kernel_launch(void* const* d_in, const int* in_sizes, int n_in,
                              void* d_out, int out_size, void* d_ws, size_t ws_size,
                              hipStream_t stream) {
    const float* x        = (const float*)d_in[0];
    const float* gamma1   = (const float*)d_in[1];
    const float* beta1    = (const float*)d_in[2];
    const float* qkv_w    = (const float*)d_in[3];
    const float* qkv_b    = (const float*)d_in[4];
    const float* proj_w   = (const float*)d_in[5];
    const float* proj_b   = (const float*)d_in[6];
    const float* pos_proj_w = (const float*)d_in[7];
    const float* pos_proj_b = (const float*)d_in[8];
    const float* ln1_g    = (const float*)d_in[9];
    const float* ln1_b    = (const float*)d_in[10];
    const float* pos1_w   = (const float*)d_in[11];
    const float* pos1_b   = (const float*)d_in[12];
    const float* ln2_g    = (const float*)d_in[13];
    const float* ln2_b    = (const float*)d_in[14];
    const float* pos2_w   = (const float*)d_in[15];
    const float* pos2_b   = (const float*)d_in[16];
    const float* ln3_g    = (const float*)d_in[17];
    const float* ln3_b    = (const float*)d_in[18];
    const float* pos3_w   = (const float*)d_in[19];
    const float* pos3_b   = (const float*)d_in[20];
    const float* gamma2   = (const float*)d_in[21];
    const float* beta2    = (const float*)d_in[22];
    const float* fc1_w    = (const float*)d_in[23];
    const float* fc1_b    = (const float*)d_in[24];
    const float* fc2_w    = (const float*)d_in[25];
    const float* fc2_b    = (const float*)d_in[26];
    float* out = (float*)d_out;

    char* ws = (char*)d_ws;
    // region0: qkv bf16 (75.5MB), later y1 bf16 (100.7MB)
    ushortT* qkv = (ushortT*)(ws + 0);
    ushortT* y1  = (ushortT*)(ws + 0);
    // region1: xn -> O -> xn2 (25.2MB)
    ushortT* xn   = (ushortT*)(ws + 100663296);
    ushortT* Obuf = xn;
    ushortT* xn2  = xn;
    float* btab = (float*)(ws + 125829120);          // 961*6 f32
    float* BTq  = (float*)(ws + 125861888);          // 6*256*256 f32 -> ends 127434752
    ushortT* qkv_wt = (ushortT*)(ws + 127434752);    // 576*192 bf16
    ushortT* proj_wt = (ushortT*)(ws + 127655936);   // 192*192 bf16
    ushortT* fc1_wt  = (ushortT*)(ws + 127729664);   // 768*192 bf16
    ushortT* fc2_wt  = (ushortT*)(ws + 128024576);   // 192*768 bf16

    // 0. weight transpose + bf16 convert
    transpose_w_kernel<<<dim3(QKV_N / 32, DIM / 32), dim3(32, 8), 0, stream>>>(qkv_w, qkv_wt, DIM, QKV_N);
    transpose_w_kernel<<<dim3(DIM / 32, DIM / 32), dim3(32, 8), 0, stream>>>(proj_w, proj_wt, DIM, DIM);
    transpose_w_kernel<<<dim3(HIDDEN / 32, DIM / 32), dim3(32, 8), 0, stream>>>(fc1_w, fc1_wt, DIM, HIDDEN);
    transpose_w_kernel<<<dim3(DIM / 32, HIDDEN / 32), dim3(32, 8), 0, stream>>>(fc2_w, fc2_wt, HIDDEN, DIM);
    // 1. position-bias MLP table
    pos_mlp_kernel<<<4, 256, 0, stream>>>(pos_proj_w, pos_proj_b,
                                          ln1_g, ln1_b, pos1_w, pos1_b,
                                          ln2_g, ln2_b, pos2_w, pos2_b,
                                          ln3_g, ln3_b, pos3_w, pos3_b, btab);
    // 2. expand to BTq[h][q][kv]
    bias_expand_kernel<<<1536, 256, 0, stream>>>(btab, BTq);
    // 3. LN1: x -> xn (bf16)
    ln_kernel<<<M_ROWS / 4, 256, 0, stream>>>(x, gamma1, beta1, xn);
    // 4. QKV GEMM
    mfma_gemm<0><<<dim3(M_ROWS / 128, QKV_N / 64), 256, 0, stream>>>(
        xn, qkv_wt, qkv_b, nullptr, qkv, QKV_N, DIM);
    // 5. attention -> Obuf (overwrites xn)
    attn_mfma_kernel<<<1536, 256, 0, stream>>>(qkv, BTq, Obuf);
    // 6. proj GEMM + residual -> d_out (f32)
    mfma_gemm<2><<<dim3(M_ROWS / 128, DIM / 64), 256, 0, stream>>>(
        Obuf, proj_wt, proj_b, x, out, DIM, DIM);
    // 7. LN2: d_out -> xn2 (overwrites Obuf)
    ln_kernel<<<M_ROWS / 4, 256, 0, stream>>>(out, gamma2, beta2, xn2);
    // 8. fc1 + GELU -> y1 (overwrites qkv)
    mfma_gemm<1><<<dim3(M_ROWS / 128, HIDDEN / 64), 256, 0, stream>>>(
        xn2, fc1_wt, fc1_b, nullptr, y1, HIDDEN, DIM);
    // 9. fc2 accumulated into d_out
    mfma_gemm<3><<<dim3(M_ROWS / 128, DIM / 64), 256, 0, stream>>>(
        y1, fc2_wt, fc2_b, nullptr, out, DIM, HIDDEN);
}

// Round 3
// 296.760 us; speedup vs baseline: 3.9266x; 1.2134x over previous
//
#include <hip/hip_runtime.h>
#include <hip/hip_bf16.h>

#define DIM 192
#define HEADS 6
#define QKV_N 576
#define HIDDEN 768
#define M_ROWS 65536

typedef unsigned short ushortT;
typedef __attribute__((ext_vector_type(8))) short short8v;
typedef __attribute__((ext_vector_type(4))) float f32x4;
typedef __attribute__((ext_vector_type(4))) unsigned int u32x4;

// 1/sqrt(32) * log2(e) folded into Q columns at QKV epilogue
#define QSCALE_L2E 0.2550348649f
#define LOG2E 1.4426950408889634f

__device__ __forceinline__ float bf2f(ushortT u) {
    union { unsigned int i; float f; } c; c.i = ((unsigned int)u) << 16; return c.f;
}
__device__ __forceinline__ ushortT f2bf(float f) {
    union { float f; unsigned int i; } c; c.f = f;
    unsigned int i = c.i;
    return (ushortT)((i + 0x7fffu + ((i >> 16) & 1u)) >> 16);
}

#define GLOBAL_LOAD_LDS16(gp, lp) \
    __builtin_amdgcn_global_load_lds((const __attribute__((address_space(1))) void*)(gp), \
                                     (__attribute__((address_space(3))) void*)(lp), 16, 0, 0)

// ---------------- pos-bias MLP: 961 rows of (di,dj) -> [961][6] table ----------------
__device__ __forceinline__ void ln_relu_mm12(const float* in, const float* g, const float* b,
                                             const float* w, const float* bb, float* out, int nout) {
    float m = 0.f;
#pragma unroll
    for (int j = 0; j < 12; ++j) m += in[j];
    m *= (1.0f / 12.0f);
    float v = 0.f;
#pragma unroll
    for (int j = 0; j < 12; ++j) { float d = in[j] - m; v += d * d; }
    v *= (1.0f / 12.0f);
    float r = rsqrtf(v + 1e-5f);
    float t[12];
#pragma unroll
    for (int j = 0; j < 12; ++j) t[j] = fmaxf((in[j] - m) * r * g[j] + b[j], 0.0f);
    for (int j2 = 0; j2 < nout; ++j2) {
        float s = bb[j2];
#pragma unroll
        for (int j = 0; j < 12; ++j) s = fmaf(t[j], w[j * nout + j2], s);
        out[j2] = s;
    }
}

__global__ void pos_mlp_kernel(const float* __restrict__ pw, const float* __restrict__ pb,
                               const float* __restrict__ g1, const float* __restrict__ b1,
                               const float* __restrict__ w1, const float* __restrict__ bb1,
                               const float* __restrict__ g2, const float* __restrict__ b2,
                               const float* __restrict__ w2, const float* __restrict__ bb2,
                               const float* __restrict__ g3, const float* __restrict__ b3,
                               const float* __restrict__ w3, const float* __restrict__ bb3,
                               float* __restrict__ btab) {
    int t = blockIdx.x * blockDim.x + threadIdx.x;
    if (t >= 961) return;
    float di = (float)(t / 31 - 15);
    float dj = (float)(t % 31 - 15);
    float a[12], h[12];
#pragma unroll
    for (int j = 0; j < 12; ++j) a[j] = di * pw[j] + dj * pw[12 + j] + pb[j];
    ln_relu_mm12(a, g1, b1, w1, bb1, h, 12);
    ln_relu_mm12(h, g2, b2, w2, bb2, a, 12);
    float outh[6];
    ln_relu_mm12(a, g3, b3, w3, bb3, outh, 6);
#pragma unroll
    for (int hh = 0; hh < 6; ++hh) btab[t * 6 + hh] = outh[hh];
}

// ---------------- expand bias to BTq[h][q][kv], pre-scaled by log2(e) ----------------
__global__ __launch_bounds__(256) void bias_expand_kernel(const float* __restrict__ btab,
                                                          float* __restrict__ BTq) {
    int blk = blockIdx.x;            // h*256 + q
    int h = blk >> 8;
    int q = blk & 255;
    int kv = threadIdx.x;
    int dii = (q >> 4) - (kv >> 4) + 15;
    int djj = (q & 15) - (kv & 15) + 15;
    BTq[(size_t)blk * 256 + kv] = btab[(dii * 31 + djj) * 6 + h] * LOG2E;
}

// ---------------- weight transpose + bf16 convert: W[K][N] f32 -> Wt[N][K] bf16 ------
__global__ __launch_bounds__(256) void transpose_w_kernel(const float* __restrict__ W,
                                                          ushortT* __restrict__ Wt,
                                                          int K, int N) {
    __shared__ float tile[32][33];
    int bx = blockIdx.x * 32;   // n
    int by = blockIdx.y * 32;   // k
    int tx = threadIdx.x, ty = threadIdx.y;   // 32, 8
#pragma unroll
    for (int i = 0; i < 32; i += 8)
        tile[ty + i][tx] = W[(size_t)(by + ty + i) * N + bx + tx];
    __syncthreads();
#pragma unroll
    for (int i = 0; i < 32; i += 8)
        Wt[(size_t)(bx + ty + i) * K + by + tx] = f2bf(tile[tx][ty + i]);
}

// ---------------- LayerNorm fp32 -> bf16, one wave per row (192) ---------------------
__global__ __launch_bounds__(256) void ln_kernel(const float* __restrict__ x,
                                                 const float* __restrict__ g,
                                                 const float* __restrict__ b,
                                                 ushortT* __restrict__ out) {
    int lane = threadIdx.x & 63;
    size_t row = (size_t)blockIdx.x * 4 + (threadIdx.x >> 6);
    const float* xr = x + row * DIM;
    float v0 = xr[lane], v1 = xr[lane + 64], v2 = xr[lane + 128];
    float s = v0 + v1 + v2;
    float ss = v0 * v0 + v1 * v1 + v2 * v2;
#pragma unroll
    for (int off = 32; off > 0; off >>= 1) {
        s += __shfl_xor(s, off);
        ss += __shfl_xor(ss, off);
    }
    float mean = s * (1.0f / DIM);
    float rstd = rsqrtf(ss * (1.0f / DIM) - mean * mean + 1e-5f);
    ushortT* o = out + row * DIM;
    o[lane]       = f2bf((v0 - mean) * rstd * g[lane]       + b[lane]);
    o[lane + 64]  = f2bf((v1 - mean) * rstd * g[lane + 64]  + b[lane + 64]);
    o[lane + 128] = f2bf((v2 - mean) * rstd * g[lane + 128] + b[lane + 128]);
}

// ---------------- MFMA GEMM: C = A(bf16 [M][K]) @ Wt(bf16 [N][K])^T + bias -----------
// BM=128, BN=64, BK=64; 256 threads = 4 waves (2x2); per-wave 64x32 (acc[4][2] f32x4)
// MODE 0: bf16 out, q-cols (<192) scaled by QSCALE_L2E ; 1: gelu->bf16 ;
// MODE 2: f32 out = resid + v ; 3: f32 out += v
template <int MODE>
__global__ __launch_bounds__(256) void mfma_gemm(const ushortT* __restrict__ A,
                                                 const ushortT* __restrict__ Wt,
                                                 const float* __restrict__ bias,
                                                 const float* __restrict__ resid,
                                                 void* __restrict__ outp,
                                                 int N, int K) {
    __shared__ ushortT As[128 * 64];
    __shared__ ushortT Bs[64 * 64];
    int tid = threadIdx.x;
    int lane = tid & 63, wid = tid >> 6;
    int l15 = lane & 15, l4 = lane >> 4;
    int wr = wid >> 1, wc = wid & 1;
    int bm = blockIdx.x * 128, bn = blockIdx.y * 64;

    f32x4 acc[4][2];
#pragma unroll
    for (int mf = 0; mf < 4; ++mf)
#pragma unroll
        for (int nf = 0; nf < 2; ++nf)
#pragma unroll
            for (int r = 0; r < 4; ++r) acc[mf][nf][r] = 0.f;

    const ushortT* agp = A + (size_t)(bm + (tid >> 3)) * K + (tid & 7) * 8;
    const ushortT* bgp = Wt + (size_t)(bn + (tid >> 3)) * K + (tid & 7) * 8;

    for (int k0 = 0; k0 < K; k0 += 64) {
#pragma unroll
        for (int i = 0; i < 4; ++i)
            GLOBAL_LOAD_LDS16(agp + (size_t)i * 32 * K + k0, As + i * 2048 + wid * 512);
#pragma unroll
        for (int i = 0; i < 2; ++i)
            GLOBAL_LOAD_LDS16(bgp + (size_t)i * 32 * K + k0, Bs + i * 2048 + wid * 512);
        __syncthreads();
#pragma unroll
        for (int ks = 0; ks < 2; ++ks) {
            short8v af[4], bf[2];
#pragma unroll
            for (int mf = 0; mf < 4; ++mf)
                af[mf] = *(const short8v*)&As[(wr * 64 + mf * 16 + l15) * 64 + ks * 32 + l4 * 8];
#pragma unroll
            for (int nf = 0; nf < 2; ++nf)
                bf[nf] = *(const short8v*)&Bs[(wc * 32 + nf * 16 + l15) * 64 + ks * 32 + l4 * 8];
#pragma unroll
            for (int mf = 0; mf < 4; ++mf)
#pragma unroll
                for (int nf = 0; nf < 2; ++nf)
                    acc[mf][nf] = __builtin_amdgcn_mfma_f32_16x16x32_bf16(af[mf], bf[nf], acc[mf][nf], 0, 0, 0);
        }
        __syncthreads();
    }
    // epilogue
#pragma unroll
    for (int mf = 0; mf < 4; ++mf) {
        size_t row = (size_t)bm + wr * 64 + mf * 16 + l4 * 4;
#pragma unroll
        for (int nf = 0; nf < 2; ++nf) {
            int col = bn + wc * 32 + nf * 16 + l15;
            float bv = bias[col];
#pragma unroll
            for (int r = 0; r < 4; ++r) {
                size_t off = (row + r) * (size_t)N + col;
                float v = acc[mf][nf][r] + bv;
                if (MODE == 0) {
                    if (col < 192) v *= QSCALE_L2E;   // fold attn scale*log2e into Q
                    ((ushortT*)outp)[off] = f2bf(v);
                } else if (MODE == 1) {
                    v = 0.5f * v * (1.0f + erff(v * 0.70710678118654752f));
                    ((ushortT*)outp)[off] = f2bf(v);
                } else if (MODE == 2) {
                    ((float*)outp)[off] = resid[off] + v;
                } else {
                    ((float*)outp)[off] += v;
                }
            }
        }
    }
}

// ---------------- MFMA flash attention (no-max softmax): block per (window, head) ----
// 4 waves x 64 q-rows; KV chunks of 32; Q/K frags direct from global; V^T + P in LDS.
// kv-slot permutation applied consistently to P (A-operand) and Vt (B-operand):
// physical slot 2c   <-> logical kv c      (c<16)
// physical slot 2c+1 <-> logical kv 16+c
__global__ __launch_bounds__(256) void attn_mfma_kernel(const ushortT* __restrict__ qkv,
                                                        const float* __restrict__ BTq,
                                                        ushortT* __restrict__ O) {
    __shared__ ushortT Vt[32][264];          // V^T padded: row stride 528B
    __shared__ unsigned int Ps[4][64][20];   // per-wave P chunk (bf16 pairs), stride 80B
    int wh = blockIdx.x;
    int w = wh / 6, h = wh - w * 6;
    int wi = w >> 4, wj = w & 15;
    int tid = threadIdx.x, lane = tid & 63, wid = tid >> 6;
    int l15 = lane & 15, l4 = lane >> 4;

    // stage V^T with kv-slot permutation: token t -> physical col
    {
        int t = tid;
        int pcol = (t & ~31) | (((t & 15) << 1) | ((t >> 4) & 1));
        size_t gr = (size_t)((wi * 16 + (t >> 4)) * 256 + wj * 16 + (t & 15));
        const ushortT* vp = qkv + gr * 576 + 384 + h * 32;
#pragma unroll
        for (int d0 = 0; d0 < 32; d0 += 8) {
            short8v u = *(const short8v*)(vp + d0);
#pragma unroll
            for (int j = 0; j < 8; ++j) Vt[d0 + j][pcol] = (ushortT)u[j];
        }
    }
    // Q fragments (A operand) direct from global (already scaled by QSCALE_L2E)
    short8v qf[4];
    int qbase = wid * 64;
#pragma unroll
    for (int mf = 0; mf < 4; ++mf) {
        int q = qbase + mf * 16 + l15;
        size_t gr = (size_t)((wi * 16 + (q >> 4)) * 256 + wj * 16 + (q & 15));
        qf[mf] = *(const short8v*)(qkv + gr * 576 + h * 32 + l4 * 8);
    }
    __syncthreads();

    float l_run[4][4];
    f32x4 accO[4][2];
#pragma unroll
    for (int mf = 0; mf < 4; ++mf)
#pragma unroll
        for (int r = 0; r < 4; ++r) {
            l_run[mf][r] = 0.f;
            accO[mf][0][r] = 0.f;
            accO[mf][1][r] = 0.f;
        }
    const float* bbase = BTq + ((size_t)h * 256 + qbase + 4 * l4) * 256 + l15;

    // K fragment loader (B operand) direct from global
    auto load_kf = [&](int kc, short8v* kf) {
#pragma unroll
        for (int cf = 0; cf < 2; ++cf) {
            int kv = kc * 32 + cf * 16 + l15;
            size_t gr = (size_t)((wi * 16 + (kv >> 4)) * 256 + wj * 16 + (kv & 15));
            kf[cf] = *(const short8v*)(qkv + gr * 576 + 192 + h * 32 + l4 * 8);
        }
    };

    short8v kfA[2], kfB[2];
    load_kf(0, kfA);

    for (int kc = 0; kc < 8; ++kc) {
        if (kc < 7) load_kf(kc + 1, kfB);      // prefetch next chunk's K
        // S = Q K^T (scaled, exp2 domain)
        f32x4 s[4][2];
        __builtin_amdgcn_s_setprio(1);
#pragma unroll
        for (int mf = 0; mf < 4; ++mf)
#pragma unroll
            for (int cf = 0; cf < 2; ++cf) {
#pragma unroll
                for (int r = 0; r < 4; ++r) s[mf][cf][r] = 0.f;
                s[mf][cf] = __builtin_amdgcn_mfma_f32_16x16x32_bf16(qf[mf], kfA[cf], s[mf][cf], 0, 0, 0);
            }
        __builtin_amdgcn_s_setprio(0);
        // softmax numerator: p = exp2(s + bias'), pack to bf16 pair, one b32 write
#pragma unroll
        for (int mf = 0; mf < 4; ++mf) {
#pragma unroll
            for (int r = 0; r < 4; ++r) {
                int bo = (mf * 16 + r) * 256 + kc * 32;
                float p0 = exp2f(s[mf][0][r] + bbase[bo]);
                float p1 = exp2f(s[mf][1][r] + bbase[bo + 16]);
                l_run[mf][r] += p0 + p1;
                unsigned int pk;
                asm("v_cvt_pk_bf16_f32 %0, %1, %2" : "=v"(pk) : "v"(p0), "v"(p1));
                Ps[wid][mf * 16 + 4 * l4 + r][l15] = pk;
            }
        }
        // PV: A = P (LDS, permuted slots), B = V^T (LDS, permuted slots)
        short8v vb[2];
#pragma unroll
        for (int nf = 0; nf < 2; ++nf)
            vb[nf] = *(const short8v*)&Vt[nf * 16 + l15][kc * 32 + l4 * 8];
        __builtin_amdgcn_s_setprio(1);
#pragma unroll
        for (int mf = 0; mf < 4; ++mf) {
            u32x4 pr = *(const u32x4*)&Ps[wid][mf * 16 + l15][l4 * 4];
            short8v pa = __builtin_bit_cast(short8v, pr);
#pragma unroll
            for (int nf = 0; nf < 2; ++nf)
                accO[mf][nf] = __builtin_amdgcn_mfma_f32_16x16x32_bf16(pa, vb[nf], accO[mf][nf], 0, 0, 0);
        }
        __builtin_amdgcn_s_setprio(0);
        kfA[0] = kfB[0]; kfA[1] = kfB[1];
    }
    // reduce l across the 16-lane col group, normalize, write O
#pragma unroll
    for (int mf = 0; mf < 4; ++mf)
#pragma unroll
        for (int r = 0; r < 4; ++r) {
            float l = l_run[mf][r];
            l += __shfl_xor(l, 1);
            l += __shfl_xor(l, 2);
            l += __shfl_xor(l, 4);
            l += __shfl_xor(l, 8);
            l_run[mf][r] = 1.0f / l;
        }
#pragma unroll
    for (int mf = 0; mf < 4; ++mf) {
        int q0 = qbase + mf * 16 + 4 * l4;
#pragma unroll
        for (int r = 0; r < 4; ++r) {
            int q = q0 + r;
            size_t gr = (size_t)((wi * 16 + (q >> 4)) * 256 + wj * 16 + (q & 15));
            ushortT* op = O + gr * 192 + h * 32 + l15;
            float inv = l_run[mf][r];
            op[0]  = f2bf(accO[mf][0][r] * inv);
            op[16] = f2bf(accO[mf][1][r] * inv);
        }
    }
}

// ---------------- launch --------------------------------------------------------------
extern "C" void kernel_launch(void* const* d_in, const int* in_sizes, int n_in,
                              void* d_out, int out_size, void* d_ws, size_t ws_size,
                              hipStream_t stream) {
    const float* x        = (const float*)d_in[0];
    const float* gamma1   = (const float*)d_in[1];
    const float* beta1    = (const float*)d_in[2];
    const float* qkv_w    = (const float*)d_in[3];
    const float* qkv_b    = (const float*)d_in[4];
    const float* proj_w   = (const float*)d_in[5];
    const float* proj_b   = (const float*)d_in[6];
    const float* pos_proj_w = (const float*)d_in[7];
    const float* pos_proj_b = (const float*)d_in[8];
    const float* ln1_g    = (const float*)d_in[9];
    const float* ln1_b    = (const float*)d_in[10];
    const float* pos1_w   = (const float*)d_in[11];
    const float* pos1_b   = (const float*)d_in[12];
    const float* ln2_g    = (const float*)d_in[13];
    const float* ln2_b    = (const float*)d_in[14];
    const float* pos2_w   = (const float*)d_in[15];
    const float* pos2_b   = (const float*)d_in[16];
    const float* ln3_g    = (const float*)d_in[17];
    const float* ln3_b    = (const float*)d_in[18];
    const float* pos3_w   = (const float*)d_in[19];
    const float* pos3_b   = (const float*)d_in[20];
    const float* gamma2   = (const float*)d_in[21];
    const float* beta2    = (const float*)d_in[22];
    const float* fc1_w    = (const float*)d_in[23];
    const float* fc1_b    = (const float*)d_in[24];
    const float* fc2_w    = (const float*)d_in[25];
    const float* fc2_b    = (const float*)d_in[26];
    float* out = (float*)d_out;

    char* ws = (char*)d_ws;
    // region0: qkv bf16 (75.5MB), later y1 bf16 (100.7MB)
    ushortT* qkv = (ushortT*)(ws + 0);
    ushortT* y1  = (ushortT*)(ws + 0);
    // region1: xn -> O -> xn2 (25.2MB)
    ushortT* xn   = (ushortT*)(ws + 100663296);
    ushortT* Obuf = xn;
    ushortT* xn2  = xn;
    float* btab = (float*)(ws + 125829120);          // 961*6 f32
    float* BTq  = (float*)(ws + 125861888);          // 6*256*256 f32 -> ends 127434752
    ushortT* qkv_wt = (ushortT*)(ws + 127434752);    // 576*192 bf16
    ushortT* proj_wt = (ushortT*)(ws + 127655936);   // 192*192 bf16
    ushortT* fc1_wt  = (ushortT*)(ws + 127729664);   // 768*192 bf16
    ushortT* fc2_wt  = (ushortT*)(ws + 128024576);   // 192*768 bf16

    // 0. weight transpose + bf16 convert
    transpose_w_kernel<<<dim3(QKV_N / 32, DIM / 32), dim3(32, 8), 0, stream>>>(qkv_w, qkv_wt, DIM, QKV_N);
    transpose_w_kernel<<<dim3(DIM / 32, DIM / 32), dim3(32, 8), 0, stream>>>(proj_w, proj_wt, DIM, DIM);
    transpose_w_kernel<<<dim3(HIDDEN / 32, DIM / 32), dim3(32, 8), 0, stream>>>(fc1_w, fc1_wt, DIM, HIDDEN);
    transpose_w_kernel<<<dim3(DIM / 32, HIDDEN / 32), dim3(32, 8), 0, stream>>>(fc2_w, fc2_wt, HIDDEN, DIM);
    // 1. position-bias MLP table
    pos_mlp_kernel<<<4, 256, 0, stream>>>(pos_proj_w, pos_proj_b,
                                          ln1_g, ln1_b, pos1_w, pos1_b,
                                          ln2_g, ln2_b, pos2_w, pos2_b,
                                          ln3_g, ln3_b, pos3_w, pos3_b, btab);
    // 2. expand to BTq[h][q][kv], *log2e
    bias_expand_kernel<<<1536, 256, 0, stream>>>(btab, BTq);
    // 3. LN1: x -> xn (bf16)
    ln_kernel<<<M_ROWS / 4, 256, 0, stream>>>(x, gamma1, beta1, xn);
    // 4. QKV GEMM (q-cols pre-scaled)
    mfma_gemm<0><<<dim3(M_ROWS / 128, QKV_N / 64), 256, 0, stream>>>(
        xn, qkv_wt, qkv_b, nullptr, qkv, QKV_N, DIM);
    // 5. attention -> Obuf (overwrites xn)
    attn_mfma_kernel<<<1536, 256, 0, stream>>>(qkv, BTq, Obuf);
    // 6. proj GEMM + residual -> d_out (f32)
    mfma_gemm<2><<<dim3(M_ROWS / 128, DIM / 64), 256, 0, stream>>>(
        Obuf, proj_wt, proj_b, x, out, DIM, DIM);
    // 7. LN2: d_out -> xn2 (overwrites Obuf)
    ln_kernel<<<M_ROWS / 4, 256, 0, stream>>>(out, gamma2, beta2, xn2);
    // 8. fc1 + GELU -> y1 (overwrites qkv)
    mfma_gemm<1><<<dim3(M_ROWS / 128, HIDDEN / 64), 256, 0, stream>>>(
        xn2, fc1_wt, fc1_b, nullptr, y1, HIDDEN, DIM);
    // 9. fc2 accumulated into d_out
    mfma_gemm<3><<<dim3(M_ROWS / 128, DIM / 64), 256, 0, stream>>>(
        y1, fc2_wt, fc2_b, nullptr, out, DIM, HIDDEN);
}

// Round 4
// 274.141 us; speedup vs baseline: 4.2505x; 1.0825x over previous
//
#include <hip/hip_runtime.h>
#include <hip/hip_bf16.h>

#define DIM 192
#define HEADS 6
#define QKV_N 576
#define HIDDEN 768
#define M_ROWS 65536

typedef unsigned short ushortT;
typedef __attribute__((ext_vector_type(8))) short short8v;
typedef __attribute__((ext_vector_type(4))) float f32x4;
typedef __attribute__((ext_vector_type(4))) unsigned int u32x4;

// 1/sqrt(32) * log2(e) folded into Q columns at QKV epilogue
#define QSCALE_L2E 0.2550348649f
#define LOG2E 1.4426950408889634f

__device__ __forceinline__ float bf2f(ushortT u) {
    union { unsigned int i; float f; } c; c.i = ((unsigned int)u) << 16; return c.f;
}
__device__ __forceinline__ ushortT f2bf(float f) {
    union { float f; unsigned int i; } c; c.f = f;
    unsigned int i = c.i;
    return (ushortT)((i + 0x7fffu + ((i >> 16) & 1u)) >> 16);
}

#define GLOBAL_LOAD_LDS16(gp, lp) \
    __builtin_amdgcn_global_load_lds((const __attribute__((address_space(1))) void*)(gp), \
                                     (__attribute__((address_space(3))) void*)(lp), 16, 0, 0)

// ---------------- small shared MLP helper -------------------------------------------
__device__ __forceinline__ void ln_relu_mm12(const float* in, const float* g, const float* b,
                                             const float* w, const float* bb, float* out, int nout) {
    float m = 0.f;
#pragma unroll
    for (int j = 0; j < 12; ++j) m += in[j];
    m *= (1.0f / 12.0f);
    float v = 0.f;
#pragma unroll
    for (int j = 0; j < 12; ++j) { float d = in[j] - m; v += d * d; }
    v *= (1.0f / 12.0f);
    float r = rsqrtf(v + 1e-5f);
    float t[12];
#pragma unroll
    for (int j = 0; j < 12; ++j) t[j] = fmaxf((in[j] - m) * r * g[j] + b[j], 0.0f);
    for (int j2 = 0; j2 < nout; ++j2) {
        float s = bb[j2];
#pragma unroll
        for (int j = 0; j < 12; ++j) s = fmaf(t[j], w[j * nout + j2], s);
        out[j2] = s;
    }
}

// ---------------- prep: 4 weight transposes + direct bias table ----------------------
// blocks 0..431: 32x32 transpose tiles; blocks 432..1967: BTq[h][q][kv] via inline MLP
__global__ __launch_bounds__(256) void prep_kernel(
        const float* __restrict__ qkv_w, const float* __restrict__ proj_w,
        const float* __restrict__ fc1_w, const float* __restrict__ fc2_w,
        ushortT* __restrict__ qkv_wt, ushortT* __restrict__ proj_wt,
        ushortT* __restrict__ fc1_wt, ushortT* __restrict__ fc2_wt,
        const float* __restrict__ pw, const float* __restrict__ pb,
        const float* __restrict__ g1, const float* __restrict__ b1,
        const float* __restrict__ w1, const float* __restrict__ bb1,
        const float* __restrict__ g2, const float* __restrict__ b2,
        const float* __restrict__ w2, const float* __restrict__ bb2,
        const float* __restrict__ g3, const float* __restrict__ b3,
        const float* __restrict__ w3, const float* __restrict__ bb3,
        float* __restrict__ BTq) {
    __shared__ float tile[32][33];
    int blk = blockIdx.x;
    int t = threadIdx.x;
    if (blk < 432) {
        const float* W; ushortT* Wt; int K, N, bx, by;
        if (blk < 108)      { W = qkv_w;  Wt = qkv_wt;  K = 192; N = 576; bx = blk % 18;        by = blk / 18; }
        else if (blk < 144) { int r = blk - 108; W = proj_w; Wt = proj_wt; K = 192; N = 192; bx = r % 6;  by = r / 6; }
        else if (blk < 288) { int r = blk - 144; W = fc1_w;  Wt = fc1_wt;  K = 192; N = 768; bx = r % 24; by = r / 24; }
        else                { int r = blk - 288; W = fc2_w;  Wt = fc2_wt;  K = 768; N = 192; bx = r % 6;  by = r / 6; }
        int tx = t & 31, ty = t >> 5;
        int bX = bx * 32, bY = by * 32;
#pragma unroll
        for (int i = 0; i < 32; i += 8)
            tile[ty + i][tx] = W[(size_t)(bY + ty + i) * N + bX + tx];
        __syncthreads();
#pragma unroll
        for (int i = 0; i < 32; i += 8)
            Wt[(size_t)(bX + ty + i) * K + bY + tx] = f2bf(tile[tx][ty + i]);
    } else {
        int blk2 = blk - 432;                 // h*256 + q
        int h = blk2 >> 8, q = blk2 & 255, kv = t;
        float di = (float)((q >> 4) - (kv >> 4));
        float dj = (float)((q & 15) - (kv & 15));
        float a[12], hh[12];
#pragma unroll
        for (int j = 0; j < 12; ++j) a[j] = di * pw[j] + dj * pw[12 + j] + pb[j];
        ln_relu_mm12(a, g1, b1, w1, bb1, hh, 12);
        ln_relu_mm12(hh, g2, b2, w2, bb2, a, 12);
        // last layer: only head h
        float m = 0.f;
#pragma unroll
        for (int j = 0; j < 12; ++j) m += a[j];
        m *= (1.0f / 12.0f);
        float v = 0.f;
#pragma unroll
        for (int j = 0; j < 12; ++j) { float d = a[j] - m; v += d * d; }
        v *= (1.0f / 12.0f);
        float r = rsqrtf(v + 1e-5f);
        float s = bb3[h];
#pragma unroll
        for (int j = 0; j < 12; ++j)
            s = fmaf(fmaxf((a[j] - m) * r * g3[j] + b3[j], 0.0f), w3[j * 6 + h], s);
        BTq[(size_t)blk2 * 256 + kv] = s * LOG2E;
    }
}

// ---------------- LayerNorm fp32 -> bf16, one wave per row (192) ---------------------
__global__ __launch_bounds__(256) void ln_kernel(const float* __restrict__ x,
                                                 const float* __restrict__ g,
                                                 const float* __restrict__ b,
                                                 ushortT* __restrict__ out) {
    int lane = threadIdx.x & 63;
    size_t row = (size_t)blockIdx.x * 4 + (threadIdx.x >> 6);
    const float* xr = x + row * DIM;
    float v0 = xr[lane], v1 = xr[lane + 64], v2 = xr[lane + 128];
    float s = v0 + v1 + v2;
    float ss = v0 * v0 + v1 * v1 + v2 * v2;
#pragma unroll
    for (int off = 32; off > 0; off >>= 1) {
        s += __shfl_xor(s, off);
        ss += __shfl_xor(ss, off);
    }
    float mean = s * (1.0f / DIM);
    float rstd = rsqrtf(ss * (1.0f / DIM) - mean * mean + 1e-5f);
    ushortT* o = out + row * DIM;
    o[lane]       = f2bf((v0 - mean) * rstd * g[lane]       + b[lane]);
    o[lane + 64]  = f2bf((v1 - mean) * rstd * g[lane + 64]  + b[lane + 64]);
    o[lane + 128] = f2bf((v2 - mean) * rstd * g[lane + 128] + b[lane + 128]);
}

// ---------------- MFMA GEMM: C = A(bf16 [M][K]) @ Wt(bf16 [N][K])^T + bias -----------
// BM=128, BN=64, BK=64; 4 waves (2x2); XOR chunk-swizzled LDS (16B granules)
// MODE 0: bf16 out, q-cols (<192) scaled by QSCALE_L2E ; 1: fast-gelu->bf16 ;
// MODE 2: f32 out = resid + v ; 3: f32 out += v
template <int MODE>
__global__ __launch_bounds__(256) void mfma_gemm(const ushortT* __restrict__ A,
                                                 const ushortT* __restrict__ Wt,
                                                 const float* __restrict__ bias,
                                                 const float* __restrict__ resid,
                                                 void* __restrict__ outp,
                                                 int N, int K) {
    __shared__ ushortT As[128 * 64];
    __shared__ ushortT Bs[64 * 64];
    int tid = threadIdx.x;
    int lane = tid & 63, wid = tid >> 6;
    int l15 = lane & 15, l4 = lane >> 4;
    int wr = wid >> 1, wc = wid & 1;
    int bm = blockIdx.x * 128, bn = blockIdx.y * 64;

    f32x4 acc[4][2];
#pragma unroll
    for (int mf = 0; mf < 4; ++mf)
#pragma unroll
        for (int nf = 0; nf < 2; ++nf)
#pragma unroll
            for (int r = 0; r < 4; ++r) acc[mf][nf][r] = 0.f;

    // swizzled global source: physical LDS chunk (tid&7) holds logical chunk (tid&7)^(srow&7)
    int srow = tid >> 3;
    int schunk = (tid & 7) ^ (srow & 7);
    const ushortT* agp = A + (size_t)(bm + srow) * K + schunk * 8;
    const ushortT* bgp = Wt + (size_t)(bn + srow) * K + schunk * 8;

    for (int k0 = 0; k0 < K; k0 += 64) {
#pragma unroll
        for (int i = 0; i < 4; ++i)
            GLOBAL_LOAD_LDS16(agp + (size_t)i * 32 * K + k0, As + i * 2048 + wid * 512);
#pragma unroll
        for (int i = 0; i < 2; ++i)
            GLOBAL_LOAD_LDS16(bgp + (size_t)i * 32 * K + k0, Bs + i * 2048 + wid * 512);
        __syncthreads();
#pragma unroll
        for (int ks = 0; ks < 2; ++ks) {
            short8v af[4], bf[2];
#pragma unroll
            for (int mf = 0; mf < 4; ++mf) {
                int row = wr * 64 + mf * 16 + l15;
                af[mf] = *(const short8v*)&As[row * 64 + (((ks * 4 + l4) ^ (l15 & 7)) << 3)];
            }
#pragma unroll
            for (int nf = 0; nf < 2; ++nf) {
                int row = wc * 32 + nf * 16 + l15;
                bf[nf] = *(const short8v*)&Bs[row * 64 + (((ks * 4 + l4) ^ (l15 & 7)) << 3)];
            }
#pragma unroll
            for (int mf = 0; mf < 4; ++mf)
#pragma unroll
                for (int nf = 0; nf < 2; ++nf)
                    acc[mf][nf] = __builtin_amdgcn_mfma_f32_16x16x32_bf16(af[mf], bf[nf], acc[mf][nf], 0, 0, 0);
        }
        __syncthreads();
    }
    // epilogue
#pragma unroll
    for (int mf = 0; mf < 4; ++mf) {
        size_t row = (size_t)bm + wr * 64 + mf * 16 + l4 * 4;
#pragma unroll
        for (int nf = 0; nf < 2; ++nf) {
            int col = bn + wc * 32 + nf * 16 + l15;
            float bv = bias[col];
#pragma unroll
            for (int r = 0; r < 4; ++r) {
                size_t off = (row + r) * (size_t)N + col;
                float v = acc[mf][nf][r] + bv;
                if (MODE == 0) {
                    if (col < 192) v *= QSCALE_L2E;   // fold attn scale*log2e into Q
                    ((ushortT*)outp)[off] = f2bf(v);
                } else if (MODE == 1) {
                    // fast gelu: x * sigmoid(1.5957691*(x + 0.044715 x^3)); exp2 domain
                    float x3 = v * v * v;
                    float z = fmaf(x3, -0.1029537917f, v * -2.302205077f);
                    float e = exp2f(z);
                    v = v * __builtin_amdgcn_rcpf(1.0f + e);
                    ((ushortT*)outp)[off] = f2bf(v);
                } else if (MODE == 2) {
                    ((float*)outp)[off] = resid[off] + v;
                } else {
                    ((float*)outp)[off] += v;
                }
            }
        }
    }
}

// ---------------- MFMA flash attention (no-max softmax): block per (window, head) ----
// 4 waves x 64 q-rows; KV chunks of 32; Q/K frags direct from global; V^T + P in LDS.
// kv-slot permutation applied consistently to P (A-operand) and Vt (B-operand)
__global__ __launch_bounds__(256) void attn_mfma_kernel(const ushortT* __restrict__ qkv,
                                                        const float* __restrict__ BTq,
                                                        ushortT* __restrict__ O) {
    __shared__ ushortT Vt[32][264];          // V^T padded: row stride 528B
    __shared__ unsigned int Ps[4][64][20];   // per-wave P chunk (bf16 pairs), stride 80B
    int wh = blockIdx.x;
    int w = wh / 6, h = wh - w * 6;
    int wi = w >> 4, wj = w & 15;
    int tid = threadIdx.x, lane = tid & 63, wid = tid >> 6;
    int l15 = lane & 15, l4 = lane >> 4;

    // stage V^T with kv-slot permutation: token t -> physical col
    {
        int t = tid;
        int pcol = (t & ~31) | (((t & 15) << 1) | ((t >> 4) & 1));
        size_t gr = (size_t)((wi * 16 + (t >> 4)) * 256 + wj * 16 + (t & 15));
        const ushortT* vp = qkv + gr * 576 + 384 + h * 32;
#pragma unroll
        for (int d0 = 0; d0 < 32; d0 += 8) {
            short8v u = *(const short8v*)(vp + d0);
#pragma unroll
            for (int j = 0; j < 8; ++j) Vt[d0 + j][pcol] = (ushortT)u[j];
        }
    }
    // Q fragments (A operand) direct from global (already scaled by QSCALE_L2E)
    short8v qf[4];
    int qbase = wid * 64;
#pragma unroll
    for (int mf = 0; mf < 4; ++mf) {
        int q = qbase + mf * 16 + l15;
        size_t gr = (size_t)((wi * 16 + (q >> 4)) * 256 + wj * 16 + (q & 15));
        qf[mf] = *(const short8v*)(qkv + gr * 576 + h * 32 + l4 * 8);
    }
    __syncthreads();

    float l_run[4][4];
    f32x4 accO[4][2];
#pragma unroll
    for (int mf = 0; mf < 4; ++mf)
#pragma unroll
        for (int r = 0; r < 4; ++r) {
            l_run[mf][r] = 0.f;
            accO[mf][0][r] = 0.f;
            accO[mf][1][r] = 0.f;
        }
    const float* bbase = BTq + ((size_t)h * 256 + qbase + 4 * l4) * 256 + l15;

    auto load_kf = [&](int kc, short8v* kf) {
#pragma unroll
        for (int cf = 0; cf < 2; ++cf) {
            int kv = kc * 32 + cf * 16 + l15;
            size_t gr = (size_t)((wi * 16 + (kv >> 4)) * 256 + wj * 16 + (kv & 15));
            kf[cf] = *(const short8v*)(qkv + gr * 576 + 192 + h * 32 + l4 * 8);
        }
    };

    short8v kfA[2], kfB[2];
    load_kf(0, kfA);

    for (int kc = 0; kc < 8; ++kc) {
        if (kc < 7) load_kf(kc + 1, kfB);      // prefetch next chunk's K
        // S = Q K^T (scaled, exp2 domain)
        f32x4 s[4][2];
        __builtin_amdgcn_s_setprio(1);
#pragma unroll
        for (int mf = 0; mf < 4; ++mf)
#pragma unroll
            for (int cf = 0; cf < 2; ++cf) {
#pragma unroll
                for (int r = 0; r < 4; ++r) s[mf][cf][r] = 0.f;
                s[mf][cf] = __builtin_amdgcn_mfma_f32_16x16x32_bf16(qf[mf], kfA[cf], s[mf][cf], 0, 0, 0);
            }
        __builtin_amdgcn_s_setprio(0);
        // softmax numerator: p = exp2(s + bias'), pack to bf16 pair, one b32 write
#pragma unroll
        for (int mf = 0; mf < 4; ++mf) {
#pragma unroll
            for (int r = 0; r < 4; ++r) {
                int bo = (mf * 16 + r) * 256 + kc * 32;
                float p0 = exp2f(s[mf][0][r] + bbase[bo]);
                float p1 = exp2f(s[mf][1][r] + bbase[bo + 16]);
                l_run[mf][r] += p0 + p1;
                unsigned int pk;
                asm("v_cvt_pk_bf16_f32 %0, %1, %2" : "=v"(pk) : "v"(p0), "v"(p1));
                Ps[wid][mf * 16 + 4 * l4 + r][l15] = pk;
            }
        }
        // PV: A = P (LDS, permuted slots), B = V^T (LDS, permuted slots)
        short8v vb[2];
#pragma unroll
        for (int nf = 0; nf < 2; ++nf)
            vb[nf] = *(const short8v*)&Vt[nf * 16 + l15][kc * 32 + l4 * 8];
        __builtin_amdgcn_s_setprio(1);
#pragma unroll
        for (int mf = 0; mf < 4; ++mf) {
            u32x4 pr = *(const u32x4*)&Ps[wid][mf * 16 + l15][l4 * 4];
            short8v pa = __builtin_bit_cast(short8v, pr);
#pragma unroll
            for (int nf = 0; nf < 2; ++nf)
                accO[mf][nf] = __builtin_amdgcn_mfma_f32_16x16x32_bf16(pa, vb[nf], accO[mf][nf], 0, 0, 0);
        }
        __builtin_amdgcn_s_setprio(0);
        kfA[0] = kfB[0]; kfA[1] = kfB[1];
    }
    // reduce l across the 16-lane col group, normalize, write O
#pragma unroll
    for (int mf = 0; mf < 4; ++mf)
#pragma unroll
        for (int r = 0; r < 4; ++r) {
            float l = l_run[mf][r];
            l += __shfl_xor(l, 1);
            l += __shfl_xor(l, 2);
            l += __shfl_xor(l, 4);
            l += __shfl_xor(l, 8);
            l_run[mf][r] = 1.0f / l;
        }
#pragma unroll
    for (int mf = 0; mf < 4; ++mf) {
        int q0 = qbase + mf * 16 + 4 * l4;
#pragma unroll
        for (int r = 0; r < 4; ++r) {
            int q = q0 + r;
            size_t gr = (size_t)((wi * 16 + (q >> 4)) * 256 + wj * 16 + (q & 15));
            ushortT* op = O + gr * 192 + h * 32 + l15;
            float inv = l_run[mf][r];
            op[0]  = f2bf(accO[mf][0][r] * inv);
            op[16] = f2bf(accO[mf][1][r] * inv);
        }
    }
}

// ---------------- launch --------------------------------------------------------------
extern "C" void kernel_launch(void* const* d_in, const int* in_sizes, int n_in,
                              void* d_out, int out_size, void* d_ws, size_t ws_size,
                              hipStream_t stream) {
    const float* x        = (const float*)d_in[0];
    const float* gamma1   = (const float*)d_in[1];
    const float* beta1    = (const float*)d_in[2];
    const float* qkv_w    = (const float*)d_in[3];
    const float* qkv_b    = (const float*)d_in[4];
    const float* proj_w   = (const float*)d_in[5];
    const float* proj_b   = (const float*)d_in[6];
    const float* pos_proj_w = (const float*)d_in[7];
    const float* pos_proj_b = (const float*)d_in[8];
    const float* ln1_g    = (const float*)d_in[9];
    const float* ln1_b    = (const float*)d_in[10];
    const float* pos1_w   = (const float*)d_in[11];
    const float* pos1_b   = (const float*)d_in[12];
    const float* ln2_g    = (const float*)d_in[13];
    const float* ln2_b    = (const float*)d_in[14];
    const float* pos2_w   = (const float*)d_in[15];
    const float* pos2_b   = (const float*)d_in[16];
    const float* ln3_g    = (const float*)d_in[17];
    const float* ln3_b    = (const float*)d_in[18];
    const float* pos3_w   = (const float*)d_in[19];
    const float* pos3_b   = (const float*)d_in[20];
    const float* gamma2   = (const float*)d_in[21];
    const float* beta2    = (const float*)d_in[22];
    const float* fc1_w    = (const float*)d_in[23];
    const float* fc1_b    = (const float*)d_in[24];
    const float* fc2_w    = (const float*)d_in[25];
    const float* fc2_b    = (const float*)d_in[26];
    float* out = (float*)d_out;

    char* ws = (char*)d_ws;
    // region0: qkv bf16 (75.5MB), later y1 bf16 (100.7MB)
    ushortT* qkv = (ushortT*)(ws + 0);
    ushortT* y1  = (ushortT*)(ws + 0);
    // region1: xn -> O -> xn2 (25.2MB)
    ushortT* xn   = (ushortT*)(ws + 100663296);
    ushortT* Obuf = xn;
    ushortT* xn2  = xn;
    float* BTq  = (float*)(ws + 125861888);          // 6*256*256 f32 -> ends 127434752
    ushortT* qkv_wt = (ushortT*)(ws + 127434752);    // 576*192 bf16
    ushortT* proj_wt = (ushortT*)(ws + 127655936);   // 192*192 bf16
    ushortT* fc1_wt  = (ushortT*)(ws + 127729664);   // 768*192 bf16
    ushortT* fc2_wt  = (ushortT*)(ws + 128024576);   // 192*768 bf16

    // 0. prep: transposes + bias table (one kernel)
    prep_kernel<<<1968, 256, 0, stream>>>(
        qkv_w, proj_w, fc1_w, fc2_w, qkv_wt, proj_wt, fc1_wt, fc2_wt,
        pos_proj_w, pos_proj_b, ln1_g, ln1_b, pos1_w, pos1_b,
        ln2_g, ln2_b, pos2_w, pos2_b, ln3_g, ln3_b, pos3_w, pos3_b, BTq);
    // 1. LN1: x -> xn (bf16)
    ln_kernel<<<M_ROWS / 4, 256, 0, stream>>>(x, gamma1, beta1, xn);
    // 2. QKV GEMM (q-cols pre-scaled)
    mfma_gemm<0><<<dim3(M_ROWS / 128, QKV_N / 64), 256, 0, stream>>>(
        xn, qkv_wt, qkv_b, nullptr, qkv, QKV_N, DIM);
    // 3. attention -> Obuf (overwrites xn)
    attn_mfma_kernel<<<1536, 256, 0, stream>>>(qkv, BTq, Obuf);
    // 4. proj GEMM + residual -> d_out (f32)
    mfma_gemm<2><<<dim3(M_ROWS / 128, DIM / 64), 256, 0, stream>>>(
        Obuf, proj_wt, proj_b, x, out, DIM, DIM);
    // 5. LN2: d_out -> xn2 (overwrites Obuf)
    ln_kernel<<<M_ROWS / 4, 256, 0, stream>>>(out, gamma2, beta2, xn2);
    // 6. fc1 + fast-GELU -> y1 (overwrites qkv)
    mfma_gemm<1><<<dim3(M_ROWS / 128, HIDDEN / 64), 256, 0, stream>>>(
        xn2, fc1_wt, fc1_b, nullptr, y1, HIDDEN, DIM);
    // 7. fc2 accumulated into d_out
    mfma_gemm<3><<<dim3(M_ROWS / 128, DIM / 64), 256, 0, stream>>>(
        y1, fc2_wt, fc2_b, nullptr, out, DIM, HIDDEN);
}

// Round 6
// 242.302 us; speedup vs baseline: 4.8091x; 1.1314x over previous
//
#include <hip/hip_runtime.h>
#include <hip/hip_bf16.h>

#define DIM 192
#define HEADS 6
#define QKV_N 576
#define HIDDEN 768
#define M_ROWS 65536

typedef unsigned short ushortT;
typedef __attribute__((ext_vector_type(8))) short short8v;
typedef __attribute__((ext_vector_type(4))) float f32x4;
typedef __attribute__((ext_vector_type(4))) unsigned int u32x4;

// 1/sqrt(32) * log2(e) folded into Q columns at QKV epilogue
#define QSCALE_L2E 0.2550348649f
#define LOG2E 1.4426950408889634f

__device__ __forceinline__ float bf2f(ushortT u) {
    union { unsigned int i; float f; } c; c.i = ((unsigned int)u) << 16; return c.f;
}
__device__ __forceinline__ ushortT f2bf(float f) {
    union { float f; unsigned int i; } c; c.f = f;
    unsigned int i = c.i;
    return (ushortT)((i + 0x7fffu + ((i >> 16) & 1u)) >> 16);
}

#define GLOBAL_LOAD_LDS16(gp, lp) \
    __builtin_amdgcn_global_load_lds((const __attribute__((address_space(1))) void*)(gp), \
                                     (__attribute__((address_space(3))) void*)(lp), 16, 0, 0)

// ---------------- small shared MLP helper -------------------------------------------
__device__ __forceinline__ void ln_relu_mm12(const float* in, const float* g, const float* b,
                                             const float* w, const float* bb, float* out, int nout) {
    float m = 0.f;
#pragma unroll
    for (int j = 0; j < 12; ++j) m += in[j];
    m *= (1.0f / 12.0f);
    float v = 0.f;
#pragma unroll
    for (int j = 0; j < 12; ++j) { float d = in[j] - m; v += d * d; }
    v *= (1.0f / 12.0f);
    float r = rsqrtf(v + 1e-5f);
    float t[12];
#pragma unroll
    for (int j = 0; j < 12; ++j) t[j] = fmaxf((in[j] - m) * r * g[j] + b[j], 0.0f);
    for (int j2 = 0; j2 < nout; ++j2) {
        float s = bb[j2];
#pragma unroll
        for (int j = 0; j < 12; ++j) s = fmaf(t[j], w[j * nout + j2], s);
        out[j2] = s;
    }
}

// ---------------- prep: 4 weight transposes + bias table in MFMA-fragment layout -----
// blocks 0..431: 32x32 transpose tiles; blocks 432..1967: BTf (h*256+q per block)
__global__ __launch_bounds__(256) void prep_kernel(
        const float* __restrict__ qkv_w, const float* __restrict__ proj_w,
        const float* __restrict__ fc1_w, const float* __restrict__ fc2_w,
        ushortT* __restrict__ qkv_wt, ushortT* __restrict__ proj_wt,
        ushortT* __restrict__ fc1_wt, ushortT* __restrict__ fc2_wt,
        const float* __restrict__ pw, const float* __restrict__ pb,
        const float* __restrict__ g1, const float* __restrict__ b1,
        const float* __restrict__ w1, const float* __restrict__ bb1,
        const float* __restrict__ g2, const float* __restrict__ b2,
        const float* __restrict__ w2, const float* __restrict__ bb2,
        const float* __restrict__ g3, const float* __restrict__ b3,
        const float* __restrict__ w3, const float* __restrict__ bb3,
        float* __restrict__ BTf) {
    __shared__ float tile[32][33];
    int blk = blockIdx.x;
    int t = threadIdx.x;
    if (blk < 432) {
        const float* W; ushortT* Wt; int K, N, bx, by;
        if (blk < 108)      { W = qkv_w;  Wt = qkv_wt;  K = 192; N = 576; bx = blk % 18;        by = blk / 18; }
        else if (blk < 144) { int r = blk - 108; W = proj_w; Wt = proj_wt; K = 192; N = 192; bx = r % 6;  by = r / 6; }
        else if (blk < 288) { int r = blk - 144; W = fc1_w;  Wt = fc1_wt;  K = 192; N = 768; bx = r % 24; by = r / 24; }
        else                { int r = blk - 288; W = fc2_w;  Wt = fc2_wt;  K = 768; N = 192; bx = r % 6;  by = r / 6; }
        int tx = t & 31, ty = t >> 5;
        int bX = bx * 32, bY = by * 32;
#pragma unroll
        for (int i = 0; i < 32; i += 8)
            tile[ty + i][tx] = W[(size_t)(bY + ty + i) * N + bX + tx];
        __syncthreads();
#pragma unroll
        for (int i = 0; i < 32; i += 8)
            Wt[(size_t)(bX + ty + i) * K + bY + tx] = f2bf(tile[tx][ty + i]);
    } else {
        int blk2 = blk - 432;                 // h*256 + q
        int h = blk2 >> 8, q = blk2 & 255, kv = t;
        float di = (float)((q >> 4) - (kv >> 4));
        float dj = (float)((q & 15) - (kv & 15));
        float a[12], hh[12];
#pragma unroll
        for (int j = 0; j < 12; ++j) a[j] = di * pw[j] + dj * pw[12 + j] + pb[j];
        ln_relu_mm12(a, g1, b1, w1, bb1, hh, 12);
        ln_relu_mm12(hh, g2, b2, w2, bb2, a, 12);
        // last layer: only head h
        float m = 0.f;
#pragma unroll
        for (int j = 0; j < 12; ++j) m += a[j];
        m *= (1.0f / 12.0f);
        float v = 0.f;
#pragma unroll
        for (int j = 0; j < 12; ++j) { float d = a[j] - m; v += d * d; }
        v *= (1.0f / 12.0f);
        float r = rsqrtf(v + 1e-5f);
        float s = bb3[h];
#pragma unroll
        for (int j = 0; j < 12; ++j)
            s = fmaf(fmaxf((a[j] - m) * r * g3[j] + b3[j], 0.0f), w3[j * 6 + h], s);
        // MFMA-fragment layout: seg = (h*8+kc)*32 + wid*8 + mf*2 + cf ; [lane][r]
        int wid = q >> 6, mf = (q >> 4) & 3, l4 = (q >> 2) & 3, rr = q & 3;
        int kc = kv >> 5, cc = kv & 31;
        int cf = (cc >> 4) & 1, l15 = cc & 15;
        int lane = l4 * 16 + l15;
        size_t off = ((size_t)((h * 8 + kc) * 32 + wid * 8 + mf * 2 + cf)) * 256 + lane * 4 + rr;
        BTf[off] = s * LOG2E;
    }
}

// ---------------- LayerNorm fp32 -> bf16, one wave per row (192) ---------------------
__global__ __launch_bounds__(256) void ln_kernel(const float* __restrict__ x,
                                                 const float* __restrict__ g,
                                                 const float* __restrict__ b,
                                                 ushortT* __restrict__ out) {
    int lane = threadIdx.x & 63;
    size_t row = (size_t)blockIdx.x * 4 + (threadIdx.x >> 6);
    const float* xr = x + row * DIM;
    float v0 = xr[lane], v1 = xr[lane + 64], v2 = xr[lane + 128];
    float s = v0 + v1 + v2;
    float ss = v0 * v0 + v1 * v1 + v2 * v2;
#pragma unroll
    for (int off = 32; off > 0; off >>= 1) {
        s += __shfl_xor(s, off);
        ss += __shfl_xor(ss, off);
    }
    float mean = s * (1.0f / DIM);
    float rstd = rsqrtf(ss * (1.0f / DIM) - mean * mean + 1e-5f);
    ushortT* o = out + row * DIM;
    o[lane]       = f2bf((v0 - mean) * rstd * g[lane]       + b[lane]);
    o[lane + 64]  = f2bf((v1 - mean) * rstd * g[lane + 64]  + b[lane + 64]);
    o[lane + 128] = f2bf((v2 - mean) * rstd * g[lane + 128] + b[lane + 128]);
}

// ---------------- MFMA GEMM: C = A(bf16 [M][K]) @ Wt(bf16 [N][K])^T + bias -----------
// BM=128, BN=64, BK=64; 4 waves (2x2); XOR chunk-swizzled LDS; 1D grid, A-major
// logical order + bijective XCD-chunk swizzle (grid%8==0).
// MODE 0: bf16 out, q-cols (<192) scaled by QSCALE_L2E ; 1: fast-gelu->bf16 ;
// MODE 2: f32 out = resid + v ; 3: f32 out += v
template <int MODE, int NY>
__global__ __launch_bounds__(256) void mfma_gemm(const ushortT* __restrict__ A,
                                                 const ushortT* __restrict__ Wt,
                                                 const float* __restrict__ bias,
                                                 const float* __restrict__ resid,
                                                 void* __restrict__ outp,
                                                 int N, int K) {
    __shared__ ushortT As[128 * 64];
    __shared__ ushortT Bs[64 * 64];
    int tid = threadIdx.x;
    int lane = tid & 63, wid = tid >> 6;
    int l15 = lane & 15, l4 = lane >> 4;
    int wr = wid >> 1, wc = wid & 1;
    // XCD-chunk swizzle: logical ids A-major; each XCD gets a contiguous chunk
    int p = blockIdx.x;
    int cpx = gridDim.x >> 3;
    int logical = (p & 7) * cpx + (p >> 3);
    int bx = logical / NY;
    int by = logical - bx * NY;
    int bm = bx * 128, bn = by * 64;

    f32x4 acc[4][2];
#pragma unroll
    for (int mf = 0; mf < 4; ++mf)
#pragma unroll
        for (int nf = 0; nf < 2; ++nf)
#pragma unroll
            for (int r = 0; r < 4; ++r) acc[mf][nf][r] = 0.f;

    // swizzled global source: physical LDS chunk (tid&7) holds logical chunk (tid&7)^(srow&7)
    int srow = tid >> 3;
    int schunk = (tid & 7) ^ (srow & 7);
    const ushortT* agp = A + (size_t)(bm + srow) * K + schunk * 8;
    const ushortT* bgp = Wt + (size_t)(bn + srow) * K + schunk * 8;

    for (int k0 = 0; k0 < K; k0 += 64) {
#pragma unroll
        for (int i = 0; i < 4; ++i)
            GLOBAL_LOAD_LDS16(agp + (size_t)i * 32 * K + k0, As + i * 2048 + wid * 512);
#pragma unroll
        for (int i = 0; i < 2; ++i)
            GLOBAL_LOAD_LDS16(bgp + (size_t)i * 32 * K + k0, Bs + i * 2048 + wid * 512);
        __syncthreads();
#pragma unroll
        for (int ks = 0; ks < 2; ++ks) {
            short8v af[4], bf[2];
#pragma unroll
            for (int mf = 0; mf < 4; ++mf) {
                int row = wr * 64 + mf * 16 + l15;
                af[mf] = *(const short8v*)&As[row * 64 + (((ks * 4 + l4) ^ (l15 & 7)) << 3)];
            }
#pragma unroll
            for (int nf = 0; nf < 2; ++nf) {
                int row = wc * 32 + nf * 16 + l15;
                bf[nf] = *(const short8v*)&Bs[row * 64 + (((ks * 4 + l4) ^ (l15 & 7)) << 3)];
            }
#pragma unroll
            for (int mf = 0; mf < 4; ++mf)
#pragma unroll
                for (int nf = 0; nf < 2; ++nf)
                    acc[mf][nf] = __builtin_amdgcn_mfma_f32_16x16x32_bf16(af[mf], bf[nf], acc[mf][nf], 0, 0, 0);
        }
        __syncthreads();
    }
    // epilogue
#pragma unroll
    for (int mf = 0; mf < 4; ++mf) {
        size_t row = (size_t)bm + wr * 64 + mf * 16 + l4 * 4;
#pragma unroll
        for (int nf = 0; nf < 2; ++nf) {
            int col = bn + wc * 32 + nf * 16 + l15;
            float bv = bias[col];
#pragma unroll
            for (int r = 0; r < 4; ++r) {
                size_t off = (row + r) * (size_t)N + col;
                float v = acc[mf][nf][r] + bv;
                if (MODE == 0) {
                    if (col < 192) v *= QSCALE_L2E;   // fold attn scale*log2e into Q
                    ((ushortT*)outp)[off] = f2bf(v);
                } else if (MODE == 1) {
                    // fast gelu: x * sigmoid(1.5957691*(x + 0.044715 x^3)); exp2 domain
                    float x3 = v * v * v;
                    float z = fmaf(x3, -0.1029537917f, v * -2.302205077f);
                    float e = exp2f(z);
                    v = v * __builtin_amdgcn_rcpf(1.0f + e);
                    ((ushortT*)outp)[off] = f2bf(v);
                } else if (MODE == 2) {
                    ((float*)outp)[off] = resid[off] + v;
                } else {
                    ((float*)outp)[off] += v;
                }
            }
        }
    }
}

// ---------------- MFMA flash attention (no-max softmax, bias via MFMA C) -------------
__global__ __launch_bounds__(256) void attn_mfma_kernel(const ushortT* __restrict__ qkv,
                                                        const float* __restrict__ BTf,
                                                        ushortT* __restrict__ O) {
    __shared__ ushortT Vt[32][264];          // V^T padded: row stride 528B
    __shared__ unsigned int Ps[4][64][20];   // per-wave P chunk (bf16 pairs), stride 80B
    int wh = blockIdx.x;
    int w = wh / 6, h = wh - w * 6;
    int wi = w >> 4, wj = w & 15;
    int tid = threadIdx.x, lane = tid & 63, wid = tid >> 6;
    int l15 = lane & 15, l4 = lane >> 4;

    // stage V^T with kv-slot permutation: token t -> physical col
    {
        int t = tid;
        int pcol = (t & ~31) | (((t & 15) << 1) | ((t >> 4) & 1));
        size_t gr = (size_t)((wi * 16 + (t >> 4)) * 256 + wj * 16 + (t & 15));
        const ushortT* vp = qkv + gr * 576 + 384 + h * 32;
#pragma unroll
        for (int d0 = 0; d0 < 32; d0 += 8) {
            short8v u = *(const short8v*)(vp + d0);
#pragma unroll
            for (int j = 0; j < 8; ++j) Vt[d0 + j][pcol] = (ushortT)u[j];
        }
    }
    // Q fragments (A operand) direct from global (already scaled by QSCALE_L2E)
    short8v qf[4];
    int qbase = wid * 64;
#pragma unroll
    for (int mf = 0; mf < 4; ++mf) {
        int q = qbase + mf * 16 + l15;
        size_t gr = (size_t)((wi * 16 + (q >> 4)) * 256 + wj * 16 + (q & 15));
        qf[mf] = *(const short8v*)(qkv + gr * 576 + h * 32 + l4 * 8);
    }
    __syncthreads();

    float l_run[4][4];
    f32x4 accO[4][2];
#pragma unroll
    for (int mf = 0; mf < 4; ++mf)
#pragma unroll
        for (int r = 0; r < 4; ++r) {
            l_run[mf][r] = 0.f;
            accO[mf][0][r] = 0.f;
            accO[mf][1][r] = 0.f;
        }
    // bias fragments base: seg = (h*8+kc)*32 + wid*8 + mf*2 + cf, each seg 256 f32
    const float* btb = BTf + ((size_t)(h * 8) * 32 + wid * 8) * 256 + lane * 4;

    auto load_kf = [&](int kc, short8v* kf) {
#pragma unroll
        for (int cf = 0; cf < 2; ++cf) {
            int kv = kc * 32 + cf * 16 + l15;
            size_t gr = (size_t)((wi * 16 + (kv >> 4)) * 256 + wj * 16 + (kv & 15));
            kf[cf] = *(const short8v*)(qkv + gr * 576 + 192 + h * 32 + l4 * 8);
        }
    };

    short8v kfA[2], kfB[2];
    load_kf(0, kfA);

    for (int kc = 0; kc < 8; ++kc) {
        if (kc < 7) load_kf(kc + 1, kfB);      // prefetch next chunk's K
        // S = Q K^T + bias (bias preloaded into MFMA C operand)
        f32x4 s[4][2];
#pragma unroll
        for (int mf = 0; mf < 4; ++mf)
#pragma unroll
            for (int cf = 0; cf < 2; ++cf)
                s[mf][cf] = *(const f32x4*)(btb + (size_t)(kc * 32 + mf * 2 + cf) * 256);
        __builtin_amdgcn_s_setprio(1);
#pragma unroll
        for (int mf = 0; mf < 4; ++mf)
#pragma unroll
            for (int cf = 0; cf < 2; ++cf)
                s[mf][cf] = __builtin_amdgcn_mfma_f32_16x16x32_bf16(qf[mf], kfA[cf], s[mf][cf], 0, 0, 0);
        __builtin_amdgcn_s_setprio(0);
        // softmax numerator: p = exp2(s), pack to bf16 pair, one b32 write
#pragma unroll
        for (int mf = 0; mf < 4; ++mf) {
#pragma unroll
            for (int r = 0; r < 4; ++r) {
                float p0 = exp2f(s[mf][0][r]);
                float p1 = exp2f(s[mf][1][r]);
                l_run[mf][r] += p0 + p1;
                unsigned int pk;
                asm("v_cvt_pk_bf16_f32 %0, %1, %2" : "=v"(pk) : "v"(p0), "v"(p1));
                Ps[wid][mf * 16 + 4 * l4 + r][l15] = pk;
            }
        }
        // PV: A = P (LDS, permuted slots), B = V^T (LDS, permuted slots)
        short8v vb[2];
#pragma unroll
        for (int nf = 0; nf < 2; ++nf)
            vb[nf] = *(const short8v*)&Vt[nf * 16 + l15][kc * 32 + l4 * 8];
        __builtin_amdgcn_s_setprio(1);
#pragma unroll
        for (int mf = 0; mf < 4; ++mf) {
            u32x4 pr = *(const u32x4*)&Ps[wid][mf * 16 + l15][l4 * 4];
            short8v pa = __builtin_bit_cast(short8v, pr);
#pragma unroll
            for (int nf = 0; nf < 2; ++nf)
                accO[mf][nf] = __builtin_amdgcn_mfma_f32_16x16x32_bf16(pa, vb[nf], accO[mf][nf], 0, 0, 0);
        }
        __builtin_amdgcn_s_setprio(0);
        kfA[0] = kfB[0]; kfA[1] = kfB[1];
    }
    // reduce l across the 16-lane col group, normalize, write O
#pragma unroll
    for (int mf = 0; mf < 4; ++mf)
#pragma unroll
        for (int r = 0; r < 4; ++r) {
            float l = l_run[mf][r];
            l += __shfl_xor(l, 1);
            l += __shfl_xor(l, 2);
            l += __shfl_xor(l, 4);
            l += __shfl_xor(l, 8);
            l_run[mf][r] = 1.0f / l;
        }
#pragma unroll
    for (int mf = 0; mf < 4; ++mf) {
        int q0 = qbase + mf * 16 + 4 * l4;
#pragma unroll
        for (int r = 0; r < 4; ++r) {
            int q = q0 + r;
            size_t gr = (size_t)((wi * 16 + (q >> 4)) * 256 + wj * 16 + (q & 15));
            ushortT* op = O + gr * 192 + h * 32 + l15;
            float inv = l_run[mf][r];
            op[0]  = f2bf(accO[mf][0][r] * inv);
            op[16] = f2bf(accO[mf][1][r] * inv);
        }
    }
}

// ---------------- launch --------------------------------------------------------------
extern "C" void kernel_launch(void* const* d_in, const int* in_sizes, int n_in,
                              void* d_out, int out_size, void* d_ws, size_t ws_size,
                              hipStream_t stream) {
    const float* x        = (const float*)d_in[0];
    const float* gamma1   = (const float*)d_in[1];
    const float* beta1    = (const float*)d_in[2];
    const float* qkv_w    = (const float*)d_in[3];
    const float* qkv_b    = (const float*)d_in[4];
    const float* proj_w   = (const float*)d_in[5];
    const float* proj_b   = (const float*)d_in[6];
    const float* pos_proj_w = (const float*)d_in[7];
    const float* pos_proj_b = (const float*)d_in[8];
    const float* ln1_g    = (const float*)d_in[9];
    const float* ln1_b    = (const float*)d_in[10];
    const float* pos1_w   = (const float*)d_in[11];
    const float* pos1_b   = (const float*)d_in[12];
    const float* ln2_g    = (const float*)d_in[13];
    const float* ln2_b    = (const float*)d_in[14];
    const float* pos2_w   = (const float*)d_in[15];
    const float* pos2_b   = (const float*)d_in[16];
    const float* ln3_g    = (const float*)d_in[17];
    const float* ln3_b    = (const float*)d_in[18];
    const float* pos3_w   = (const float*)d_in[19];
    const float* pos3_b   = (const float*)d_in[20];
    const float* gamma2   = (const float*)d_in[21];
    const float* beta2    = (const float*)d_in[22];
    const float* fc1_w    = (const float*)d_in[23];
    const float* fc1_b    = (const float*)d_in[24];
    const float* fc2_w    = (const float*)d_in[25];
    const float* fc2_b    = (const float*)d_in[26];
    float* out = (float*)d_out;

    char* ws = (char*)d_ws;
    // region0: qkv bf16 (75.5MB), later y1 bf16 (100.7MB)
    ushortT* qkv = (ushortT*)(ws + 0);
    ushortT* y1  = (ushortT*)(ws + 0);
    // region1: xn -> Obuf -> xn2 (25.2MB) ends 125829120
    ushortT* xn   = (ushortT*)(ws + 100663296);
    ushortT* Obuf = xn;
    ushortT* xn2  = xn;
    ushortT* qkv_wt  = (ushortT*)(ws + 125829120);   // 221184 B -> 126050304
    ushortT* proj_wt = (ushortT*)(ws + 126050304);   //  73728 B -> 126124032
    ushortT* fc1_wt  = (ushortT*)(ws + 126124032);   // 294912 B -> 126418944
    ushortT* fc2_wt  = (ushortT*)(ws + 126418944);   // 294912 B -> 126713856
    float*   BTf     = (float*)(ws + 126713856);     // 1572864 B -> 128286720

    // 0. prep: transposes + bias table (one kernel)
    prep_kernel<<<1968, 256, 0, stream>>>(
        qkv_w, proj_w, fc1_w, fc2_w, qkv_wt, proj_wt, fc1_wt, fc2_wt,
        pos_proj_w, pos_proj_b, ln1_g, ln1_b, pos1_w, pos1_b,
        ln2_g, ln2_b, pos2_w, pos2_b, ln3_g, ln3_b, pos3_w, pos3_b, BTf);
    // 1. LN1: x -> xn (bf16)
    ln_kernel<<<M_ROWS / 4, 256, 0, stream>>>(x, gamma1, beta1, xn);
    // 2. QKV GEMM (q-cols pre-scaled), 1D grid A-major + XCD swizzle
    mfma_gemm<0, 9><<<(M_ROWS / 128) * (QKV_N / 64), 256, 0, stream>>>(
        xn, qkv_wt, qkv_b, nullptr, qkv, QKV_N, DIM);
    // 3. attention -> Obuf (overwrites xn)
    attn_mfma_kernel<<<1536, 256, 0, stream>>>(qkv, BTf, Obuf);
    // 4. proj GEMM + residual -> out (f32)
    mfma_gemm<2, 3><<<(M_ROWS / 128) * (DIM / 64), 256, 0, stream>>>(
        Obuf, proj_wt, proj_b, x, out, DIM, DIM);
    // 5. LN2: out -> xn2 (overwrites Obuf)
    ln_kernel<<<M_ROWS / 4, 256, 0, stream>>>(out, gamma2, beta2, xn2);
    // 6. fc1 + fast-GELU -> y1 (overwrites qkv)
    mfma_gemm<1, 12><<<(M_ROWS / 128) * (HIDDEN / 64), 256, 0, stream>>>(
        xn2, fc1_wt, fc1_b, nullptr, y1, HIDDEN, DIM);
    // 7. fc2 accumulated into d_out
    mfma_gemm<3, 3><<<(M_ROWS / 128) * (DIM / 64), 256, 0, stream>>>(
        y1, fc2_wt, fc2_b, nullptr, out, DIM, HIDDEN);
}

// Round 7
// 232.597 us; speedup vs baseline: 5.0097x; 1.0417x over previous
//
#include <hip/hip_runtime.h>
#include <hip/hip_bf16.h>

#define DIM 192
#define HEADS 6
#define QKV_N 576
#define HIDDEN 768
#define M_ROWS 65536

typedef unsigned short ushortT;
typedef __attribute__((ext_vector_type(8))) short short8v;
typedef __attribute__((ext_vector_type(4))) float f32x4;
typedef __attribute__((ext_vector_type(4))) unsigned int u32x4;

// 1/sqrt(32) * log2(e) folded into Q columns at QKV epilogue
#define QSCALE_L2E 0.2550348649f
#define LOG2E 1.4426950408889634f

__device__ __forceinline__ float bf2f(ushortT u) {
    union { unsigned int i; float f; } c; c.i = ((unsigned int)u) << 16; return c.f;
}
__device__ __forceinline__ ushortT f2bf(float f) {
    union { float f; unsigned int i; } c; c.f = f;
    unsigned int i = c.i;
    return (ushortT)((i + 0x7fffu + ((i >> 16) & 1u)) >> 16);
}

#define GLOBAL_LOAD_LDS16(gp, lp) \
    __builtin_amdgcn_global_load_lds((const __attribute__((address_space(1))) void*)(gp), \
                                     (__attribute__((address_space(3))) void*)(lp), 16, 0, 0)

// ---------------- small shared MLP helper -------------------------------------------
__device__ __forceinline__ void ln_relu_mm12(const float* in, const float* g, const float* b,
                                             const float* w, const float* bb, float* out, int nout) {
    float m = 0.f;
#pragma unroll
    for (int j = 0; j < 12; ++j) m += in[j];
    m *= (1.0f / 12.0f);
    float v = 0.f;
#pragma unroll
    for (int j = 0; j < 12; ++j) { float d = in[j] - m; v += d * d; }
    v *= (1.0f / 12.0f);
    float r = rsqrtf(v + 1e-5f);
    float t[12];
#pragma unroll
    for (int j = 0; j < 12; ++j) t[j] = fmaxf((in[j] - m) * r * g[j] + b[j], 0.0f);
    for (int j2 = 0; j2 < nout; ++j2) {
        float s = bb[j2];
#pragma unroll
        for (int j = 0; j < 12; ++j) s = fmaf(t[j], w[j * nout + j2], s);
        out[j2] = s;
    }
}

// ---------------- prep: 4 weight transposes + bias table in MFMA-fragment layout -----
// blocks 0..431: 32x32 transpose tiles; blocks 432..1967: BTf (h*256+q per block)
__global__ __launch_bounds__(256) void prep_kernel(
        const float* __restrict__ qkv_w, const float* __restrict__ proj_w,
        const float* __restrict__ fc1_w, const float* __restrict__ fc2_w,
        ushortT* __restrict__ qkv_wt, ushortT* __restrict__ proj_wt,
        ushortT* __restrict__ fc1_wt, ushortT* __restrict__ fc2_wt,
        const float* __restrict__ pw, const float* __restrict__ pb,
        const float* __restrict__ g1, const float* __restrict__ b1,
        const float* __restrict__ w1, const float* __restrict__ bb1,
        const float* __restrict__ g2, const float* __restrict__ b2,
        const float* __restrict__ w2, const float* __restrict__ bb2,
        const float* __restrict__ g3, const float* __restrict__ b3,
        const float* __restrict__ w3, const float* __restrict__ bb3,
        float* __restrict__ BTf) {
    __shared__ float tile[32][33];
    int blk = blockIdx.x;
    int t = threadIdx.x;
    if (blk < 432) {
        const float* W; ushortT* Wt; int K, N, bx, by;
        if (blk < 108)      { W = qkv_w;  Wt = qkv_wt;  K = 192; N = 576; bx = blk % 18;        by = blk / 18; }
        else if (blk < 144) { int r = blk - 108; W = proj_w; Wt = proj_wt; K = 192; N = 192; bx = r % 6;  by = r / 6; }
        else if (blk < 288) { int r = blk - 144; W = fc1_w;  Wt = fc1_wt;  K = 192; N = 768; bx = r % 24; by = r / 24; }
        else                { int r = blk - 288; W = fc2_w;  Wt = fc2_wt;  K = 768; N = 192; bx = r % 6;  by = r / 6; }
        int tx = t & 31, ty = t >> 5;
        int bX = bx * 32, bY = by * 32;
#pragma unroll
        for (int i = 0; i < 32; i += 8)
            tile[ty + i][tx] = W[(size_t)(bY + ty + i) * N + bX + tx];
        __syncthreads();
#pragma unroll
        for (int i = 0; i < 32; i += 8)
            Wt[(size_t)(bX + ty + i) * K + bY + tx] = f2bf(tile[tx][ty + i]);
    } else {
        int blk2 = blk - 432;                 // h*256 + q
        int h = blk2 >> 8, q = blk2 & 255, kv = t;
        float di = (float)((q >> 4) - (kv >> 4));
        float dj = (float)((q & 15) - (kv & 15));
        float a[12], hh[12];
#pragma unroll
        for (int j = 0; j < 12; ++j) a[j] = di * pw[j] + dj * pw[12 + j] + pb[j];
        ln_relu_mm12(a, g1, b1, w1, bb1, hh, 12);
        ln_relu_mm12(hh, g2, b2, w2, bb2, a, 12);
        // last layer: only head h
        float m = 0.f;
#pragma unroll
        for (int j = 0; j < 12; ++j) m += a[j];
        m *= (1.0f / 12.0f);
        float v = 0.f;
#pragma unroll
        for (int j = 0; j < 12; ++j) { float d = a[j] - m; v += d * d; }
        v *= (1.0f / 12.0f);
        float r = rsqrtf(v + 1e-5f);
        float s = bb3[h];
#pragma unroll
        for (int j = 0; j < 12; ++j)
            s = fmaf(fmaxf((a[j] - m) * r * g3[j] + b3[j], 0.0f), w3[j * 6 + h], s);
        // MFMA-fragment layout: seg = (h*8+kc)*32 + wid*8 + mf*2 + cf ; [lane][r]
        int wid = q >> 6, mf = (q >> 4) & 3, l4 = (q >> 2) & 3, rr = q & 3;
        int kc = kv >> 5, cc = kv & 31;
        int cf = (cc >> 4) & 1, l15 = cc & 15;
        int lane = l4 * 16 + l15;
        size_t off = ((size_t)((h * 8 + kc) * 32 + wid * 8 + mf * 2 + cf)) * 256 + lane * 4 + rr;
        BTf[off] = s * LOG2E;
    }
}

// ---------------- LayerNorm fp32 -> bf16, one wave per row (192) ---------------------
__global__ __launch_bounds__(256) void ln_kernel(const float* __restrict__ x,
                                                 const float* __restrict__ g,
                                                 const float* __restrict__ b,
                                                 ushortT* __restrict__ out) {
    int lane = threadIdx.x & 63;
    size_t row = (size_t)blockIdx.x * 4 + (threadIdx.x >> 6);
    const float* xr = x + row * DIM;
    float v0 = xr[lane], v1 = xr[lane + 64], v2 = xr[lane + 128];
    float s = v0 + v1 + v2;
    float ss = v0 * v0 + v1 * v1 + v2 * v2;
#pragma unroll
    for (int off = 32; off > 0; off >>= 1) {
        s += __shfl_xor(s, off);
        ss += __shfl_xor(ss, off);
    }
    float mean = s * (1.0f / DIM);
    float rstd = rsqrtf(ss * (1.0f / DIM) - mean * mean + 1e-5f);
    ushortT* o = out + row * DIM;
    o[lane]       = f2bf((v0 - mean) * rstd * g[lane]       + b[lane]);
    o[lane + 64]  = f2bf((v1 - mean) * rstd * g[lane + 64]  + b[lane + 64]);
    o[lane + 128] = f2bf((v2 - mean) * rstd * g[lane + 128] + b[lane + 128]);
}

// ---------------- MFMA GEMM, double-buffered LDS + counted vmcnt ---------------------
// BM=128, BN=64, BK=64; 4 waves (2x2); XOR chunk-swizzled LDS; 1D grid, A-major
// logical order + bijective XCD-chunk swizzle (grid%8==0). KK = compile-time K.
// Per K-step: STAGE(next) -> vmcnt(6) -> barrier -> MFMA(cur) -> barrier.
// MODE 0: bf16 out, q-cols (<192) scaled by QSCALE_L2E ; 1: fast-gelu->bf16 ;
// MODE 2: f32 out = resid + v ; 3: f32 out += v
template <int MODE, int NY, int KK>
__global__ __launch_bounds__(256) void mfma_gemm(const ushortT* __restrict__ A,
                                                 const ushortT* __restrict__ Wt,
                                                 const float* __restrict__ bias,
                                                 const float* __restrict__ resid,
                                                 void* __restrict__ outp,
                                                 int N) {
    __shared__ ushortT As[2][128 * 64];
    __shared__ ushortT Bs[2][64 * 64];
    const int NT = KK / 64;
    int tid = threadIdx.x;
    int lane = tid & 63, wid = tid >> 6;
    int l15 = lane & 15, l4 = lane >> 4;
    int wr = wid >> 1, wc = wid & 1;
    // XCD-chunk swizzle: logical ids A-major; each XCD gets a contiguous chunk
    int p = blockIdx.x;
    int cpx = gridDim.x >> 3;
    int logical = (p & 7) * cpx + (p >> 3);
    int bx = logical / NY;
    int by = logical - bx * NY;
    int bm = bx * 128, bn = by * 64;

    f32x4 acc[4][2];
#pragma unroll
    for (int mf = 0; mf < 4; ++mf)
#pragma unroll
        for (int nf = 0; nf < 2; ++nf)
#pragma unroll
            for (int r = 0; r < 4; ++r) acc[mf][nf][r] = 0.f;

    // swizzled global source: physical LDS chunk (tid&7) holds logical chunk (tid&7)^(srow&7)
    int srow = tid >> 3;
    int schunk = (tid & 7) ^ (srow & 7);
    const ushortT* agp = A + (size_t)(bm + srow) * KK + schunk * 8;
    const ushortT* bgp = Wt + (size_t)(bn + srow) * KK + schunk * 8;

    auto STAGE = [&](int buf, int t) {
        int k0 = t * 64;
#pragma unroll
        for (int i = 0; i < 4; ++i)
            GLOBAL_LOAD_LDS16(agp + (size_t)i * 32 * KK + k0, &As[buf][i * 2048 + wid * 512]);
#pragma unroll
        for (int i = 0; i < 2; ++i)
            GLOBAL_LOAD_LDS16(bgp + (size_t)i * 32 * KK + k0, &Bs[buf][i * 2048 + wid * 512]);
    };

    STAGE(0, 0);
    for (int t = 0; t < NT; ++t) {
        int cur = t & 1;
        if (t + 1 < NT) {
            STAGE(cur ^ 1, t + 1);
            asm volatile("s_waitcnt vmcnt(6)" ::: "memory");   // cur tile landed, next in flight
        } else {
            asm volatile("s_waitcnt vmcnt(0)" ::: "memory");
        }
        __builtin_amdgcn_s_barrier();
        const ushortT* Asc = As[cur];
        const ushortT* Bsc = Bs[cur];
#pragma unroll
        for (int ks = 0; ks < 2; ++ks) {
            short8v af[4], bf[2];
#pragma unroll
            for (int mf = 0; mf < 4; ++mf) {
                int row = wr * 64 + mf * 16 + l15;
                af[mf] = *(const short8v*)&Asc[row * 64 + (((ks * 4 + l4) ^ (l15 & 7)) << 3)];
            }
#pragma unroll
            for (int nf = 0; nf < 2; ++nf) {
                int row = wc * 32 + nf * 16 + l15;
                bf[nf] = *(const short8v*)&Bsc[row * 64 + (((ks * 4 + l4) ^ (l15 & 7)) << 3)];
            }
#pragma unroll
            for (int mf = 0; mf < 4; ++mf)
#pragma unroll
                for (int nf = 0; nf < 2; ++nf)
                    acc[mf][nf] = __builtin_amdgcn_mfma_f32_16x16x32_bf16(af[mf], bf[nf], acc[mf][nf], 0, 0, 0);
        }
        __builtin_amdgcn_s_barrier();                          // cur free for overwrite
    }
    // epilogue
#pragma unroll
    for (int mf = 0; mf < 4; ++mf) {
        size_t row = (size_t)bm + wr * 64 + mf * 16 + l4 * 4;
#pragma unroll
        for (int nf = 0; nf < 2; ++nf) {
            int col = bn + wc * 32 + nf * 16 + l15;
            float bv = bias[col];
#pragma unroll
            for (int r = 0; r < 4; ++r) {
                size_t off = (row + r) * (size_t)N + col;
                float v = acc[mf][nf][r] + bv;
                if (MODE == 0) {
                    if (col < 192) v *= QSCALE_L2E;   // fold attn scale*log2e into Q
                    ((ushortT*)outp)[off] = f2bf(v);
                } else if (MODE == 1) {
                    // fast gelu: x * sigmoid(1.5957691*(x + 0.044715 x^3)); exp2 domain
                    float x3 = v * v * v;
                    float z = fmaf(x3, -0.1029537917f, v * -2.302205077f);
                    float e = exp2f(z);
                    v = v * __builtin_amdgcn_rcpf(1.0f + e);
                    ((ushortT*)outp)[off] = f2bf(v);
                } else if (MODE == 2) {
                    ((float*)outp)[off] = resid[off] + v;
                } else {
                    ((float*)outp)[off] += v;
                }
            }
        }
    }
}

// ---------------- MFMA flash attention (no-max softmax, bias dbuf via MFMA C) --------
__global__ __launch_bounds__(256) void attn_mfma_kernel(const ushortT* __restrict__ qkv,
                                                        const float* __restrict__ BTf,
                                                        ushortT* __restrict__ O) {
    __shared__ ushortT Vt[32][264];          // V^T padded: row stride 528B
    __shared__ unsigned int Ps[4][64][20];   // per-wave P chunk (bf16 pairs), stride 80B
    int wh = blockIdx.x;
    int w = wh / 6, h = wh - w * 6;
    int wi = w >> 4, wj = w & 15;
    int tid = threadIdx.x, lane = tid & 63, wid = tid >> 6;
    int l15 = lane & 15, l4 = lane >> 4;

    // stage V^T with kv-slot permutation: token t -> physical col
    {
        int t = tid;
        int pcol = (t & ~31) | (((t & 15) << 1) | ((t >> 4) & 1));
        size_t gr = (size_t)((wi * 16 + (t >> 4)) * 256 + wj * 16 + (t & 15));
        const ushortT* vp = qkv + gr * 576 + 384 + h * 32;
#pragma unroll
        for (int d0 = 0; d0 < 32; d0 += 8) {
            short8v u = *(const short8v*)(vp + d0);
#pragma unroll
            for (int j = 0; j < 8; ++j) Vt[d0 + j][pcol] = (ushortT)u[j];
        }
    }
    // Q fragments (A operand) direct from global (already scaled by QSCALE_L2E)
    short8v qf[4];
    int qbase = wid * 64;
#pragma unroll
    for (int mf = 0; mf < 4; ++mf) {
        int q = qbase + mf * 16 + l15;
        size_t gr = (size_t)((wi * 16 + (q >> 4)) * 256 + wj * 16 + (q & 15));
        qf[mf] = *(const short8v*)(qkv + gr * 576 + h * 32 + l4 * 8);
    }
    __syncthreads();

    float l_run[4][4];
    f32x4 accO[4][2];
#pragma unroll
    for (int mf = 0; mf < 4; ++mf)
#pragma unroll
        for (int r = 0; r < 4; ++r) {
            l_run[mf][r] = 0.f;
            accO[mf][0][r] = 0.f;
            accO[mf][1][r] = 0.f;
        }
    // bias fragments base: seg = (h*8+kc)*32 + wid*8 + mf*2 + cf, each seg 256 f32
    const float* btb = BTf + ((size_t)(h * 8) * 32 + wid * 8) * 256 + lane * 4;

    auto load_kf = [&](int kc, short8v* kf) {
#pragma unroll
        for (int cf = 0; cf < 2; ++cf) {
            int kv = kc * 32 + cf * 16 + l15;
            size_t gr = (size_t)((wi * 16 + (kv >> 4)) * 256 + wj * 16 + (kv & 15));
            kf[cf] = *(const short8v*)(qkv + gr * 576 + 192 + h * 32 + l4 * 8);
        }
    };

    f32x4 bias_buf[8];
    auto load_bias = [&](int kc) {
#pragma unroll
        for (int i = 0; i < 8; ++i)
            bias_buf[i] = *(const f32x4*)(btb + (size_t)(kc * 32 + i) * 256);
    };

    short8v kfA[2], kfB[2];
    load_kf(0, kfA);
    load_bias(0);

    for (int kc = 0; kc < 8; ++kc) {
        if (kc < 7) load_kf(kc + 1, kfB);      // prefetch next chunk's K
        // S = Q K^T + bias (bias as MFMA C-in, preloaded last chunk)
        f32x4 s[4][2];
        __builtin_amdgcn_s_setprio(1);
#pragma unroll
        for (int mf = 0; mf < 4; ++mf)
#pragma unroll
            for (int cf = 0; cf < 2; ++cf)
                s[mf][cf] = __builtin_amdgcn_mfma_f32_16x16x32_bf16(qf[mf], kfA[cf], bias_buf[mf * 2 + cf], 0, 0, 0);
        __builtin_amdgcn_s_setprio(0);
        if (kc < 7) load_bias(kc + 1);         // prefetch next chunk's bias fragments
        // softmax numerator: p = exp2(s), pack to bf16 pair, one b32 write
#pragma unroll
        for (int mf = 0; mf < 4; ++mf) {
#pragma unroll
            for (int r = 0; r < 4; ++r) {
                float p0 = exp2f(s[mf][0][r]);
                float p1 = exp2f(s[mf][1][r]);
                l_run[mf][r] += p0 + p1;
                unsigned int pk;
                asm("v_cvt_pk_bf16_f32 %0, %1, %2" : "=v"(pk) : "v"(p0), "v"(p1));
                Ps[wid][mf * 16 + 4 * l4 + r][l15] = pk;
            }
        }
        // PV: A = P (LDS, permuted slots), B = V^T (LDS, permuted slots)
        short8v vb[2];
#pragma unroll
        for (int nf = 0; nf < 2; ++nf)
            vb[nf] = *(const short8v*)&Vt[nf * 16 + l15][kc * 32 + l4 * 8];
        __builtin_amdgcn_s_setprio(1);
#pragma unroll
        for (int mf = 0; mf < 4; ++mf) {
            u32x4 pr = *(const u32x4*)&Ps[wid][mf * 16 + l15][l4 * 4];
            short8v pa = __builtin_bit_cast(short8v, pr);
#pragma unroll
            for (int nf = 0; nf < 2; ++nf)
                accO[mf][nf] = __builtin_amdgcn_mfma_f32_16x16x32_bf16(pa, vb[nf], accO[mf][nf], 0, 0, 0);
        }
        __builtin_amdgcn_s_setprio(0);
        kfA[0] = kfB[0]; kfA[1] = kfB[1];
    }
    // reduce l across the 16-lane col group, normalize, write O
#pragma unroll
    for (int mf = 0; mf < 4; ++mf)
#pragma unroll
        for (int r = 0; r < 4; ++r) {
            float l = l_run[mf][r];
            l += __shfl_xor(l, 1);
            l += __shfl_xor(l, 2);
            l += __shfl_xor(l, 4);
            l += __shfl_xor(l, 8);
            l_run[mf][r] = 1.0f / l;
        }
#pragma unroll
    for (int mf = 0; mf < 4; ++mf) {
        int q0 = qbase + mf * 16 + 4 * l4;
#pragma unroll
        for (int r = 0; r < 4; ++r) {
            int q = q0 + r;
            size_t gr = (size_t)((wi * 16 + (q >> 4)) * 256 + wj * 16 + (q & 15));
            ushortT* op = O + gr * 192 + h * 32 + l15;
            float inv = l_run[mf][r];
            op[0]  = f2bf(accO[mf][0][r] * inv);
            op[16] = f2bf(accO[mf][1][r] * inv);
        }
    }
}

// ---------------- launch --------------------------------------------------------------
extern "C" void kernel_launch(void* const* d_in, const int* in_sizes, int n_in,
                              void* d_out, int out_size, void* d_ws, size_t ws_size,
                              hipStream_t stream) {
    const float* x        = (const float*)d_in[0];
    const float* gamma1   = (const float*)d_in[1];
    const float* beta1    = (const float*)d_in[2];
    const float* qkv_w    = (const float*)d_in[3];
    const float* qkv_b    = (const float*)d_in[4];
    const float* proj_w   = (const float*)d_in[5];
    const float* proj_b   = (const float*)d_in[6];
    const float* pos_proj_w = (const float*)d_in[7];
    const float* pos_proj_b = (const float*)d_in[8];
    const float* ln1_g    = (const float*)d_in[9];
    const float* ln1_b    = (const float*)d_in[10];
    const float* pos1_w   = (const float*)d_in[11];
    const float* pos1_b   = (const float*)d_in[12];
    const float* ln2_g    = (const float*)d_in[13];
    const float* ln2_b    = (const float*)d_in[14];
    const float* pos2_w   = (const float*)d_in[15];
    const float* pos2_b   = (const float*)d_in[16];
    const float* ln3_g    = (const float*)d_in[17];
    const float* ln3_b    = (const float*)d_in[18];
    const float* pos3_w   = (const float*)d_in[19];
    const float* pos3_b   = (const float*)d_in[20];
    const float* gamma2   = (const float*)d_in[21];
    const float* beta2    = (const float*)d_in[22];
    const float* fc1_w    = (const float*)d_in[23];
    const float* fc1_b    = (const float*)d_in[24];
    const float* fc2_w    = (const float*)d_in[25];
    const float* fc2_b    = (const float*)d_in[26];
    float* out = (float*)d_out;

    char* ws = (char*)d_ws;
    // region0: qkv bf16 (75.5MB), later y1 bf16 (100.7MB)
    ushortT* qkv = (ushortT*)(ws + 0);
    ushortT* y1  = (ushortT*)(ws + 0);
    // region1: xn -> Obuf -> xn2 (25.2MB) ends 125829120
    ushortT* xn   = (ushortT*)(ws + 100663296);
    ushortT* Obuf = xn;
    ushortT* xn2  = xn;
    ushortT* qkv_wt  = (ushortT*)(ws + 125829120);   // 221184 B -> 126050304
    ushortT* proj_wt = (ushortT*)(ws + 126050304);   //  73728 B -> 126124032
    ushortT* fc1_wt  = (ushortT*)(ws + 126124032);   // 294912 B -> 126418944
    ushortT* fc2_wt  = (ushortT*)(ws + 126418944);   // 294912 B -> 126713856
    float*   BTf     = (float*)(ws + 126713856);     // 1572864 B -> 128286720

    // 0. prep: transposes + bias table (one kernel)
    prep_kernel<<<1968, 256, 0, stream>>>(
        qkv_w, proj_w, fc1_w, fc2_w, qkv_wt, proj_wt, fc1_wt, fc2_wt,
        pos_proj_w, pos_proj_b, ln1_g, ln1_b, pos1_w, pos1_b,
        ln2_g, ln2_b, pos2_w, pos2_b, ln3_g, ln3_b, pos3_w, pos3_b, BTf);
    // 1. LN1: x -> xn (bf16)
    ln_kernel<<<M_ROWS / 4, 256, 0, stream>>>(x, gamma1, beta1, xn);
    // 2. QKV GEMM (q-cols pre-scaled), 1D grid A-major + XCD swizzle, dbuf
    mfma_gemm<0, 9, 192><<<(M_ROWS / 128) * (QKV_N / 64), 256, 0, stream>>>(
        xn, qkv_wt, qkv_b, nullptr, qkv, QKV_N);
    // 3. attention -> Obuf (overwrites xn)
    attn_mfma_kernel<<<1536, 256, 0, stream>>>(qkv, BTf, Obuf);
    // 4. proj GEMM + residual -> out (f32)
    mfma_gemm<2, 3, 192><<<(M_ROWS / 128) * (DIM / 64), 256, 0, stream>>>(
        Obuf, proj_wt, proj_b, x, out, DIM);
    // 5. LN2: out -> xn2 (overwrites Obuf)
    ln_kernel<<<M_ROWS / 4, 256, 0, stream>>>(out, gamma2, beta2, xn2);
    // 6. fc1 + fast-GELU -> y1 (overwrites qkv)
    mfma_gemm<1, 12, 192><<<(M_ROWS / 128) * (HIDDEN / 64), 256, 0, stream>>>(
        xn2, fc1_wt, fc1_b, nullptr, y1, HIDDEN);
    // 7. fc2 accumulated into d_out
    mfma_gemm<3, 3, 768><<<(M_ROWS / 128) * (DIM / 64), 256, 0, stream>>>(
        y1, fc2_wt, fc2_b, nullptr, out, DIM);
}

// Round 8
// 230.491 us; speedup vs baseline: 5.0555x; 1.0091x over previous
//
#include <hip/hip_runtime.h>
#include <hip/hip_bf16.h>

#define DIM 192
#define HEADS 6
#define QKV_N 576
#define HIDDEN 768
#define M_ROWS 65536

typedef unsigned short ushortT;
typedef __attribute__((ext_vector_type(8))) short short8v;
typedef __attribute__((ext_vector_type(4))) float f32x4;
typedef __attribute__((ext_vector_type(4))) unsigned int u32x4;

// 1/sqrt(32) * log2(e) folded into Q columns at QKV epilogue
#define QSCALE_L2E 0.2550348649f
#define LOG2E 1.4426950408889634f

__device__ __forceinline__ float bf2f(ushortT u) {
    union { unsigned int i; float f; } c; c.i = ((unsigned int)u) << 16; return c.f;
}
__device__ __forceinline__ ushortT f2bf(float f) {
    union { float f; unsigned int i; } c; c.f = f;
    unsigned int i = c.i;
    return (ushortT)((i + 0x7fffu + ((i >> 16) & 1u)) >> 16);
}

#define GLOBAL_LOAD_LDS16(gp, lp) \
    __builtin_amdgcn_global_load_lds((const __attribute__((address_space(1))) void*)(gp), \
                                     (__attribute__((address_space(3))) void*)(lp), 16, 0, 0)

// ---------------- small shared MLP helper -------------------------------------------
__device__ __forceinline__ void ln_relu_mm12(const float* in, const float* g, const float* b,
                                             const float* w, const float* bb, float* out, int nout) {
    float m = 0.f;
#pragma unroll
    for (int j = 0; j < 12; ++j) m += in[j];
    m *= (1.0f / 12.0f);
    float v = 0.f;
#pragma unroll
    for (int j = 0; j < 12; ++j) { float d = in[j] - m; v += d * d; }
    v *= (1.0f / 12.0f);
    float r = rsqrtf(v + 1e-5f);
    float t[12];
#pragma unroll
    for (int j = 0; j < 12; ++j) t[j] = fmaxf((in[j] - m) * r * g[j] + b[j], 0.0f);
    for (int j2 = 0; j2 < nout; ++j2) {
        float s = bb[j2];
#pragma unroll
        for (int j = 0; j < 12; ++j) s = fmaf(t[j], w[j * nout + j2], s);
        out[j2] = s;
    }
}

// ---------------- prep: 4 weight transposes + bias table in MFMA-fragment layout -----
// blocks 0..431: 32x32 transpose tiles; blocks 432..1967: BTf (h*256+q per block)
__global__ __launch_bounds__(256) void prep_kernel(
        const float* __restrict__ qkv_w, const float* __restrict__ proj_w,
        const float* __restrict__ fc1_w, const float* __restrict__ fc2_w,
        ushortT* __restrict__ qkv_wt, ushortT* __restrict__ proj_wt,
        ushortT* __restrict__ fc1_wt, ushortT* __restrict__ fc2_wt,
        const float* __restrict__ pw, const float* __restrict__ pb,
        const float* __restrict__ g1, const float* __restrict__ b1,
        const float* __restrict__ w1, const float* __restrict__ bb1,
        const float* __restrict__ g2, const float* __restrict__ b2,
        const float* __restrict__ w2, const float* __restrict__ bb2,
        const float* __restrict__ g3, const float* __restrict__ b3,
        const float* __restrict__ w3, const float* __restrict__ bb3,
        float* __restrict__ BTf) {
    __shared__ float tile[32][33];
    int blk = blockIdx.x;
    int t = threadIdx.x;
    if (blk < 432) {
        const float* W; ushortT* Wt; int K, N, bx, by;
        if (blk < 108)      { W = qkv_w;  Wt = qkv_wt;  K = 192; N = 576; bx = blk % 18;        by = blk / 18; }
        else if (blk < 144) { int r = blk - 108; W = proj_w; Wt = proj_wt; K = 192; N = 192; bx = r % 6;  by = r / 6; }
        else if (blk < 288) { int r = blk - 144; W = fc1_w;  Wt = fc1_wt;  K = 192; N = 768; bx = r % 24; by = r / 24; }
        else                { int r = blk - 288; W = fc2_w;  Wt = fc2_wt;  K = 768; N = 192; bx = r % 6;  by = r / 6; }
        int tx = t & 31, ty = t >> 5;
        int bX = bx * 32, bY = by * 32;
#pragma unroll
        for (int i = 0; i < 32; i += 8)
            tile[ty + i][tx] = W[(size_t)(bY + ty + i) * N + bX + tx];
        __syncthreads();
#pragma unroll
        for (int i = 0; i < 32; i += 8)
            Wt[(size_t)(bX + ty + i) * K + bY + tx] = f2bf(tile[tx][ty + i]);
    } else {
        int blk2 = blk - 432;                 // h*256 + q
        int h = blk2 >> 8, q = blk2 & 255, kv = t;
        float di = (float)((q >> 4) - (kv >> 4));
        float dj = (float)((q & 15) - (kv & 15));
        float a[12], hh[12];
#pragma unroll
        for (int j = 0; j < 12; ++j) a[j] = di * pw[j] + dj * pw[12 + j] + pb[j];
        ln_relu_mm12(a, g1, b1, w1, bb1, hh, 12);
        ln_relu_mm12(hh, g2, b2, w2, bb2, a, 12);
        // last layer: only head h
        float m = 0.f;
#pragma unroll
        for (int j = 0; j < 12; ++j) m += a[j];
        m *= (1.0f / 12.0f);
        float v = 0.f;
#pragma unroll
        for (int j = 0; j < 12; ++j) { float d = a[j] - m; v += d * d; }
        v *= (1.0f / 12.0f);
        float r = rsqrtf(v + 1e-5f);
        float s = bb3[h];
#pragma unroll
        for (int j = 0; j < 12; ++j)
            s = fmaf(fmaxf((a[j] - m) * r * g3[j] + b3[j], 0.0f), w3[j * 6 + h], s);
        // MFMA-fragment layout: seg = (h*8+kc)*32 + wid*8 + mf*2 + cf ; [lane][r]
        int wid = q >> 6, mf = (q >> 4) & 3, l4 = (q >> 2) & 3, rr = q & 3;
        int kc = kv >> 5, cc = kv & 31;
        int cf = (cc >> 4) & 1, l15 = cc & 15;
        int lane = l4 * 16 + l15;
        size_t off = ((size_t)((h * 8 + kc) * 32 + wid * 8 + mf * 2 + cf)) * 256 + lane * 4 + rr;
        BTf[off] = s * LOG2E;
    }
}

// ---------------- LayerNorm fp32 -> bf16, one wave per row (192) ---------------------
__global__ __launch_bounds__(256) void ln_kernel(const float* __restrict__ x,
                                                 const float* __restrict__ g,
                                                 const float* __restrict__ b,
                                                 ushortT* __restrict__ out) {
    int lane = threadIdx.x & 63;
    size_t row = (size_t)blockIdx.x * 4 + (threadIdx.x >> 6);
    const float* xr = x + row * DIM;
    float v0 = xr[lane], v1 = xr[lane + 64], v2 = xr[lane + 128];
    float s = v0 + v1 + v2;
    float ss = v0 * v0 + v1 * v1 + v2 * v2;
#pragma unroll
    for (int off = 32; off > 0; off >>= 1) {
        s += __shfl_xor(s, off);
        ss += __shfl_xor(ss, off);
    }
    float mean = s * (1.0f / DIM);
    float rstd = rsqrtf(ss * (1.0f / DIM) - mean * mean + 1e-5f);
    ushortT* o = out + row * DIM;
    o[lane]       = f2bf((v0 - mean) * rstd * g[lane]       + b[lane]);
    o[lane + 64]  = f2bf((v1 - mean) * rstd * g[lane + 64]  + b[lane + 64]);
    o[lane + 128] = f2bf((v2 - mean) * rstd * g[lane + 128] + b[lane + 128]);
}

// ---------------- MFMA GEMM, double-buffered LDS + counted vmcnt ---------------------
// BM=128, BN=64, BK=64; 4 waves (2x2); XOR chunk-swizzled LDS; 1D grid, A-major
// logical order + bijective XCD-chunk swizzle (grid%8==0). KK = compile-time K.
// Per K-step: STAGE(next) -> vmcnt(6) -> barrier -> MFMA(cur) -> barrier.
// MODE 0: bf16 out, q-cols (<192) scaled by QSCALE_L2E ; 1: fast-gelu->bf16 ;
// MODE 2: f32 out = resid + v ; 3: f32 out += v
template <int MODE, int NY, int KK>
__global__ __launch_bounds__(256) void mfma_gemm(const ushortT* __restrict__ A,
                                                 const ushortT* __restrict__ Wt,
                                                 const float* __restrict__ bias,
                                                 const float* __restrict__ resid,
                                                 void* __restrict__ outp,
                                                 int N) {
    __shared__ ushortT As[2][128 * 64];
    __shared__ ushortT Bs[2][64 * 64];
    const int NT = KK / 64;
    int tid = threadIdx.x;
    int lane = tid & 63, wid = tid >> 6;
    int l15 = lane & 15, l4 = lane >> 4;
    int wr = wid >> 1, wc = wid & 1;
    // XCD-chunk swizzle: logical ids A-major; each XCD gets a contiguous chunk
    int p = blockIdx.x;
    int cpx = gridDim.x >> 3;
    int logical = (p & 7) * cpx + (p >> 3);
    int bx = logical / NY;
    int by = logical - bx * NY;
    int bm = bx * 128, bn = by * 64;

    f32x4 acc[4][2];
#pragma unroll
    for (int mf = 0; mf < 4; ++mf)
#pragma unroll
        for (int nf = 0; nf < 2; ++nf)
#pragma unroll
            for (int r = 0; r < 4; ++r) acc[mf][nf][r] = 0.f;

    // swizzled global source: physical LDS chunk (tid&7) holds logical chunk (tid&7)^(srow&7)
    int srow = tid >> 3;
    int schunk = (tid & 7) ^ (srow & 7);
    const ushortT* agp = A + (size_t)(bm + srow) * KK + schunk * 8;
    const ushortT* bgp = Wt + (size_t)(bn + srow) * KK + schunk * 8;

    auto STAGE = [&](int buf, int t) {
        int k0 = t * 64;
#pragma unroll
        for (int i = 0; i < 4; ++i)
            GLOBAL_LOAD_LDS16(agp + (size_t)i * 32 * KK + k0, &As[buf][i * 2048 + wid * 512]);
#pragma unroll
        for (int i = 0; i < 2; ++i)
            GLOBAL_LOAD_LDS16(bgp + (size_t)i * 32 * KK + k0, &Bs[buf][i * 2048 + wid * 512]);
    };

    STAGE(0, 0);
    for (int t = 0; t < NT; ++t) {
        int cur = t & 1;
        if (t + 1 < NT) {
            STAGE(cur ^ 1, t + 1);
            asm volatile("s_waitcnt vmcnt(6)" ::: "memory");   // cur tile landed, next in flight
        } else {
            asm volatile("s_waitcnt vmcnt(0)" ::: "memory");
        }
        __builtin_amdgcn_s_barrier();
        const ushortT* Asc = As[cur];
        const ushortT* Bsc = Bs[cur];
#pragma unroll
        for (int ks = 0; ks < 2; ++ks) {
            short8v af[4], bf[2];
#pragma unroll
            for (int mf = 0; mf < 4; ++mf) {
                int row = wr * 64 + mf * 16 + l15;
                af[mf] = *(const short8v*)&Asc[row * 64 + (((ks * 4 + l4) ^ (l15 & 7)) << 3)];
            }
#pragma unroll
            for (int nf = 0; nf < 2; ++nf) {
                int row = wc * 32 + nf * 16 + l15;
                bf[nf] = *(const short8v*)&Bsc[row * 64 + (((ks * 4 + l4) ^ (l15 & 7)) << 3)];
            }
#pragma unroll
            for (int mf = 0; mf < 4; ++mf)
#pragma unroll
                for (int nf = 0; nf < 2; ++nf)
                    acc[mf][nf] = __builtin_amdgcn_mfma_f32_16x16x32_bf16(af[mf], bf[nf], acc[mf][nf], 0, 0, 0);
        }
        __builtin_amdgcn_s_barrier();                          // cur free for overwrite
    }
    // epilogue
#pragma unroll
    for (int mf = 0; mf < 4; ++mf) {
        size_t row = (size_t)bm + wr * 64 + mf * 16 + l4 * 4;
#pragma unroll
        for (int nf = 0; nf < 2; ++nf) {
            int col = bn + wc * 32 + nf * 16 + l15;
            float bv = bias[col];
#pragma unroll
            for (int r = 0; r < 4; ++r) {
                size_t off = (row + r) * (size_t)N + col;
                float v = acc[mf][nf][r] + bv;
                if (MODE == 0) {
                    if (col < 192) v *= QSCALE_L2E;   // fold attn scale*log2e into Q
                    ((ushortT*)outp)[off] = f2bf(v);
                } else if (MODE == 1) {
                    // fast gelu: x * sigmoid(1.5957691*(x + 0.044715 x^3)); exp2 domain
                    float x3 = v * v * v;
                    float z = fmaf(x3, -0.1029537917f, v * -2.302205077f);
                    float e = exp2f(z);
                    v = v * __builtin_amdgcn_rcpf(1.0f + e);
                    ((ushortT*)outp)[off] = f2bf(v);
                } else if (MODE == 2) {
                    ((float*)outp)[off] = resid[off] + v;
                } else {
                    ((float*)outp)[off] += v;
                }
            }
        }
    }
}

// ---------------- MFMA flash attention (no-max softmax, per-mf interleave) -----------
// 4 waves x 64 q-rows; TLP-first: launch_bounds(256,4) forces <=128 regs ->
// 4 blocks/CU. No K/bias prefetch; per-mf {QK^T -> softmax -> PV} keeps s at 8 regs.
__global__ __launch_bounds__(256, 4) void attn_mfma_kernel(const ushortT* __restrict__ qkv,
                                                           const float* __restrict__ BTf,
                                                           ushortT* __restrict__ O) {
    __shared__ ushortT Vt[32][264];          // V^T padded: row stride 528B
    __shared__ unsigned int Ps[4][64][20];   // per-wave P chunk (bf16 pairs), stride 80B
    int wh = blockIdx.x;
    int w = wh / 6, h = wh - w * 6;
    int wi = w >> 4, wj = w & 15;
    int tid = threadIdx.x, lane = tid & 63, wid = tid >> 6;
    int l15 = lane & 15, l4 = lane >> 4;

    // stage V^T with kv-slot permutation: token t -> physical col
    {
        int t = tid;
        int pcol = (t & ~31) | (((t & 15) << 1) | ((t >> 4) & 1));
        size_t gr = (size_t)((wi * 16 + (t >> 4)) * 256 + wj * 16 + (t & 15));
        const ushortT* vp = qkv + gr * 576 + 384 + h * 32;
#pragma unroll
        for (int d0 = 0; d0 < 32; d0 += 8) {
            short8v u = *(const short8v*)(vp + d0);
#pragma unroll
            for (int j = 0; j < 8; ++j) Vt[d0 + j][pcol] = (ushortT)u[j];
        }
    }
    // Q fragments (A operand) direct from global (already scaled by QSCALE_L2E)
    short8v qf[4];
    int qbase = wid * 64;
#pragma unroll
    for (int mf = 0; mf < 4; ++mf) {
        int q = qbase + mf * 16 + l15;
        size_t gr = (size_t)((wi * 16 + (q >> 4)) * 256 + wj * 16 + (q & 15));
        qf[mf] = *(const short8v*)(qkv + gr * 576 + h * 32 + l4 * 8);
    }
    __syncthreads();

    float l_run[4][4];
    f32x4 accO[4][2];
#pragma unroll
    for (int mf = 0; mf < 4; ++mf)
#pragma unroll
        for (int r = 0; r < 4; ++r) {
            l_run[mf][r] = 0.f;
            accO[mf][0][r] = 0.f;
            accO[mf][1][r] = 0.f;
        }
    // bias fragments base: seg = (h*8+kc)*32 + wid*8 + mf*2 + cf, each seg 256 f32
    const float* btb = BTf + ((size_t)(h * 8) * 32 + wid * 8) * 256 + lane * 4;

    for (int kc = 0; kc < 8; ++kc) {
        // K fragments for this chunk (B operand) direct from global
        short8v kf[2];
#pragma unroll
        for (int cf = 0; cf < 2; ++cf) {
            int kv = kc * 32 + cf * 16 + l15;
            size_t gr = (size_t)((wi * 16 + (kv >> 4)) * 256 + wj * 16 + (kv & 15));
            kf[cf] = *(const short8v*)(qkv + gr * 576 + 192 + h * 32 + l4 * 8);
        }
        // V fragments for this chunk (B operand) from LDS
        short8v vb[2];
#pragma unroll
        for (int nf = 0; nf < 2; ++nf)
            vb[nf] = *(const short8v*)&Vt[nf * 16 + l15][kc * 32 + l4 * 8];
        // per-mf: QK^T (+bias C-in) -> softmax -> PV
#pragma unroll
        for (int mf = 0; mf < 4; ++mf) {
            f32x4 s0 = *(const f32x4*)(btb + (size_t)(kc * 32 + mf * 2 + 0) * 256);
            f32x4 s1 = *(const f32x4*)(btb + (size_t)(kc * 32 + mf * 2 + 1) * 256);
            __builtin_amdgcn_s_setprio(1);
            s0 = __builtin_amdgcn_mfma_f32_16x16x32_bf16(qf[mf], kf[0], s0, 0, 0, 0);
            s1 = __builtin_amdgcn_mfma_f32_16x16x32_bf16(qf[mf], kf[1], s1, 0, 0, 0);
            __builtin_amdgcn_s_setprio(0);
#pragma unroll
            for (int r = 0; r < 4; ++r) {
                float p0 = exp2f(s0[r]);
                float p1 = exp2f(s1[r]);
                l_run[mf][r] += p0 + p1;
                unsigned int pk;
                asm("v_cvt_pk_bf16_f32 %0, %1, %2" : "=v"(pk) : "v"(p0), "v"(p1));
                Ps[wid][mf * 16 + 4 * l4 + r][l15] = pk;
            }
            u32x4 pr = *(const u32x4*)&Ps[wid][mf * 16 + l15][l4 * 4];
            short8v pa = __builtin_bit_cast(short8v, pr);
            __builtin_amdgcn_s_setprio(1);
            accO[mf][0] = __builtin_amdgcn_mfma_f32_16x16x32_bf16(pa, vb[0], accO[mf][0], 0, 0, 0);
            accO[mf][1] = __builtin_amdgcn_mfma_f32_16x16x32_bf16(pa, vb[1], accO[mf][1], 0, 0, 0);
            __builtin_amdgcn_s_setprio(0);
        }
    }
    // reduce l across the 16-lane col group, normalize, write O
#pragma unroll
    for (int mf = 0; mf < 4; ++mf)
#pragma unroll
        for (int r = 0; r < 4; ++r) {
            float l = l_run[mf][r];
            l += __shfl_xor(l, 1);
            l += __shfl_xor(l, 2);
            l += __shfl_xor(l, 4);
            l += __shfl_xor(l, 8);
            l_run[mf][r] = 1.0f / l;
        }
#pragma unroll
    for (int mf = 0; mf < 4; ++mf) {
        int q0 = qbase + mf * 16 + 4 * l4;
#pragma unroll
        for (int r = 0; r < 4; ++r) {
            int q = q0 + r;
            size_t gr = (size_t)((wi * 16 + (q >> 4)) * 256 + wj * 16 + (q & 15));
            ushortT* op = O + gr * 192 + h * 32 + l15;
            float inv = l_run[mf][r];
            op[0]  = f2bf(accO[mf][0][r] * inv);
            op[16] = f2bf(accO[mf][1][r] * inv);
        }
    }
}

// ---------------- launch --------------------------------------------------------------
extern "C" void kernel_launch(void* const* d_in, const int* in_sizes, int n_in,
                              void* d_out, int out_size, void* d_ws, size_t ws_size,
                              hipStream_t stream) {
    const float* x        = (const float*)d_in[0];
    const float* gamma1   = (const float*)d_in[1];
    const float* beta1    = (const float*)d_in[2];
    const float* qkv_w    = (const float*)d_in[3];
    const float* qkv_b    = (const float*)d_in[4];
    const float* proj_w   = (const float*)d_in[5];
    const float* proj_b   = (const float*)d_in[6];
    const float* pos_proj_w = (const float*)d_in[7];
    const float* pos_proj_b = (const float*)d_in[8];
    const float* ln1_g    = (const float*)d_in[9];
    const float* ln1_b    = (const float*)d_in[10];
    const float* pos1_w   = (const float*)d_in[11];
    const float* pos1_b   = (const float*)d_in[12];
    const float* ln2_g    = (const float*)d_in[13];
    const float* ln2_b    = (const float*)d_in[14];
    const float* pos2_w   = (const float*)d_in[15];
    const float* pos2_b   = (const float*)d_in[16];
    const float* ln3_g    = (const float*)d_in[17];
    const float* ln3_b    = (const float*)d_in[18];
    const float* pos3_w   = (const float*)d_in[19];
    const float* pos3_b   = (const float*)d_in[20];
    const float* gamma2   = (const float*)d_in[21];
    const float* beta2    = (const float*)d_in[22];
    const float* fc1_w    = (const float*)d_in[23];
    const float* fc1_b    = (const float*)d_in[24];
    const float* fc2_w    = (const float*)d_in[25];
    const float* fc2_b    = (const float*)d_in[26];
    float* out = (float*)d_out;

    char* ws = (char*)d_ws;
    // region0: qkv bf16 (75.5MB), later y1 bf16 (100.7MB)
    ushortT* qkv = (ushortT*)(ws + 0);
    ushortT* y1  = (ushortT*)(ws + 0);
    // region1: xn -> Obuf -> xn2 (25.2MB) ends 125829120
    ushortT* xn   = (ushortT*)(ws + 100663296);
    ushortT* Obuf = xn;
    ushortT* xn2  = xn;
    ushortT* qkv_wt  = (ushortT*)(ws + 125829120);   // 221184 B -> 126050304
    ushortT* proj_wt = (ushortT*)(ws + 126050304);   //  73728 B -> 126124032
    ushortT* fc1_wt  = (ushortT*)(ws + 126124032);   // 294912 B -> 126418944
    ushortT* fc2_wt  = (ushortT*)(ws + 126418944);   // 294912 B -> 126713856
    float*   BTf     = (float*)(ws + 126713856);     // 1572864 B -> 128286720

    // 0. prep: transposes + bias table (one kernel)
    prep_kernel<<<1968, 256, 0, stream>>>(
        qkv_w, proj_w, fc1_w, fc2_w, qkv_wt, proj_wt, fc1_wt, fc2_wt,
        pos_proj_w, pos_proj_b, ln1_g, ln1_b, pos1_w, pos1_b,
        ln2_g, ln2_b, pos2_w, pos2_b, ln3_g, ln3_b, pos3_w, pos3_b, BTf);
    // 1. LN1: x -> xn (bf16)
    ln_kernel<<<M_ROWS / 4, 256, 0, stream>>>(x, gamma1, beta1, xn);
    // 2. QKV GEMM (q-cols pre-scaled), 1D grid A-major + XCD swizzle, dbuf
    mfma_gemm<0, 9, 192><<<(M_ROWS / 128) * (QKV_N / 64), 256, 0, stream>>>(
        xn, qkv_wt, qkv_b, nullptr, qkv, QKV_N);
    // 3. attention -> Obuf (overwrites xn)
    attn_mfma_kernel<<<1536, 256, 0, stream>>>(qkv, BTf, Obuf);
    // 4. proj GEMM + residual -> out (f32)
    mfma_gemm<2, 3, 192><<<(M_ROWS / 128) * (DIM / 64), 256, 0, stream>>>(
        Obuf, proj_wt, proj_b, x, out, DIM);
    // 5. LN2: out -> xn2 (overwrites Obuf)
    ln_kernel<<<M_ROWS / 4, 256, 0, stream>>>(out, gamma2, beta2, xn2);
    // 6. fc1 + fast-GELU -> y1 (overwrites qkv)
    mfma_gemm<1, 12, 192><<<(M_ROWS / 128) * (HIDDEN / 64), 256, 0, stream>>>(
        xn2, fc1_wt, fc1_b, nullptr, y1, HIDDEN);
    // 7. fc2 accumulated into d_out
    mfma_gemm<3, 3, 768><<<(M_ROWS / 128) * (DIM / 64), 256, 0, stream>>>(
        y1, fc2_wt, fc2_b, nullptr, out, DIM);
}

// Round 9
// 216.466 us; speedup vs baseline: 5.3830x; 1.0648x over previous
//
#include <hip/hip_runtime.h>
#include <hip/hip_bf16.h>

#define DIM 192
#define HEADS 6
#define QKV_N 576
#define HIDDEN 768
#define M_ROWS 65536

typedef unsigned short ushortT;
typedef __attribute__((ext_vector_type(8))) short short8v;
typedef __attribute__((ext_vector_type(4))) float f32x4;
typedef __attribute__((ext_vector_type(4))) unsigned int u32x4;

// 1/sqrt(32) * log2(e) folded into Q columns at QKV epilogue
#define QSCALE_L2E 0.2550348649f
#define LOG2E 1.4426950408889634f

__device__ __forceinline__ float bf2f(ushortT u) {
    union { unsigned int i; float f; } c; c.i = ((unsigned int)u) << 16; return c.f;
}
__device__ __forceinline__ ushortT f2bf(float f) {
    union { float f; unsigned int i; } c; c.f = f;
    unsigned int i = c.i;
    return (ushortT)((i + 0x7fffu + ((i >> 16) & 1u)) >> 16);
}
__device__ __forceinline__ float fast_gelu(float v) {
    // x * sigmoid(1.5957691*(x + 0.044715 x^3)); exp2 domain (proven r4)
    float x3 = v * v * v;
    float z = fmaf(x3, -0.1029537917f, v * -2.302205077f);
    float e = exp2f(z);
    return v * __builtin_amdgcn_rcpf(1.0f + e);
}

#define GLOBAL_LOAD_LDS16(gp, lp) \
    __builtin_amdgcn_global_load_lds((const __attribute__((address_space(1))) void*)(gp), \
                                     (__attribute__((address_space(3))) void*)(lp), 16, 0, 0)

// ---------------- small shared MLP helper -------------------------------------------
__device__ __forceinline__ void ln_relu_mm12(const float* in, const float* g, const float* b,
                                             const float* w, const float* bb, float* out, int nout) {
    float m = 0.f;
#pragma unroll
    for (int j = 0; j < 12; ++j) m += in[j];
    m *= (1.0f / 12.0f);
    float v = 0.f;
#pragma unroll
    for (int j = 0; j < 12; ++j) { float d = in[j] - m; v += d * d; }
    v *= (1.0f / 12.0f);
    float r = rsqrtf(v + 1e-5f);
    float t[12];
#pragma unroll
    for (int j = 0; j < 12; ++j) t[j] = fmaxf((in[j] - m) * r * g[j] + b[j], 0.0f);
    for (int j2 = 0; j2 < nout; ++j2) {
        float s = bb[j2];
#pragma unroll
        for (int j = 0; j < 12; ++j) s = fmaf(t[j], w[j * nout + j2], s);
        out[j2] = s;
    }
}

// ---------------- prep: 4 weight transposes + bias table in MFMA-fragment layout -----
// blocks 0..431: 32x32 transpose tiles (fc2 gets k-slot permutation within 32-groups);
// blocks 432..1967: BTf (h*256+q per block)
__global__ __launch_bounds__(256) void prep_kernel(
        const float* __restrict__ qkv_w, const float* __restrict__ proj_w,
        const float* __restrict__ fc1_w, const float* __restrict__ fc2_w,
        ushortT* __restrict__ qkv_wt, ushortT* __restrict__ proj_wt,
        ushortT* __restrict__ fc1_wt, ushortT* __restrict__ fc2_wt,
        const float* __restrict__ pw, const float* __restrict__ pb,
        const float* __restrict__ g1, const float* __restrict__ b1,
        const float* __restrict__ w1, const float* __restrict__ bb1,
        const float* __restrict__ g2, const float* __restrict__ b2,
        const float* __restrict__ w2, const float* __restrict__ bb2,
        const float* __restrict__ g3, const float* __restrict__ b3,
        const float* __restrict__ w3, const float* __restrict__ bb3,
        float* __restrict__ BTf) {
    __shared__ float tile[32][33];
    int blk = blockIdx.x;
    int t = threadIdx.x;
    if (blk < 432) {
        const float* W; ushortT* Wt; int K, N, bx, by; bool perm = false;
        if (blk < 108)      { W = qkv_w;  Wt = qkv_wt;  K = 192; N = 576; bx = blk % 18;        by = blk / 18; }
        else if (blk < 144) { int r = blk - 108; W = proj_w; Wt = proj_wt; K = 192; N = 192; bx = r % 6;  by = r / 6; }
        else if (blk < 288) { int r = blk - 144; W = fc1_w;  Wt = fc1_wt;  K = 192; N = 768; bx = r % 24; by = r / 24; }
        else                { int r = blk - 288; W = fc2_w;  Wt = fc2_wt;  K = 768; N = 192; bx = r % 6;  by = r / 6; perm = true; }
        int tx = t & 31, ty = t >> 5;
        int bX = bx * 32, bY = by * 32;
#pragma unroll
        for (int i = 0; i < 32; i += 8)
            tile[ty + i][tx] = W[(size_t)(bY + ty + i) * N + bX + tx];
        __syncthreads();
        // k-col within 32-group; fc2 gets pk-permutation: k -> 2*(k&15) + (k>>4)
        int kcol = perm ? (((tx & 15) << 1) | (tx >> 4)) : tx;
#pragma unroll
        for (int i = 0; i < 32; i += 8)
            Wt[(size_t)(bX + ty + i) * K + bY + kcol] = f2bf(tile[tx][ty + i]);
    } else {
        int blk2 = blk - 432;                 // h*256 + q
        int h = blk2 >> 8, q = blk2 & 255, kv = t;
        float di = (float)((q >> 4) - (kv >> 4));
        float dj = (float)((q & 15) - (kv & 15));
        float a[12], hh[12];
#pragma unroll
        for (int j = 0; j < 12; ++j) a[j] = di * pw[j] + dj * pw[12 + j] + pb[j];
        ln_relu_mm12(a, g1, b1, w1, bb1, hh, 12);
        ln_relu_mm12(hh, g2, b2, w2, bb2, a, 12);
        // last layer: only head h
        float m = 0.f;
#pragma unroll
        for (int j = 0; j < 12; ++j) m += a[j];
        m *= (1.0f / 12.0f);
        float v = 0.f;
#pragma unroll
        for (int j = 0; j < 12; ++j) { float d = a[j] - m; v += d * d; }
        v *= (1.0f / 12.0f);
        float r = rsqrtf(v + 1e-5f);
        float s = bb3[h];
#pragma unroll
        for (int j = 0; j < 12; ++j)
            s = fmaf(fmaxf((a[j] - m) * r * g3[j] + b3[j], 0.0f), w3[j * 6 + h], s);
        // MFMA-fragment layout: seg = (h*8+kc)*32 + wid*8 + mf*2 + cf ; [lane][r]
        int wid = q >> 6, mf = (q >> 4) & 3, l4 = (q >> 2) & 3, rr = q & 3;
        int kc = kv >> 5, cc = kv & 31;
        int cf = (cc >> 4) & 1, l15 = cc & 15;
        int lane = l4 * 16 + l15;
        size_t off = ((size_t)((h * 8 + kc) * 32 + wid * 8 + mf * 2 + cf)) * 256 + lane * 4 + rr;
        BTf[off] = s * LOG2E;
    }
}

// ---------------- LayerNorm fp32 -> bf16, one wave per row (192) ---------------------
__global__ __launch_bounds__(256) void ln_kernel(const float* __restrict__ x,
                                                 const float* __restrict__ g,
                                                 const float* __restrict__ b,
                                                 ushortT* __restrict__ out) {
    int lane = threadIdx.x & 63;
    size_t row = (size_t)blockIdx.x * 4 + (threadIdx.x >> 6);
    const float* xr = x + row * DIM;
    float v0 = xr[lane], v1 = xr[lane + 64], v2 = xr[lane + 128];
    float s = v0 + v1 + v2;
    float ss = v0 * v0 + v1 * v1 + v2 * v2;
#pragma unroll
    for (int off = 32; off > 0; off >>= 1) {
        s += __shfl_xor(s, off);
        ss += __shfl_xor(ss, off);
    }
    float mean = s * (1.0f / DIM);
    float rstd = rsqrtf(ss * (1.0f / DIM) - mean * mean + 1e-5f);
    ushortT* o = out + row * DIM;
    o[lane]       = f2bf((v0 - mean) * rstd * g[lane]       + b[lane]);
    o[lane + 64]  = f2bf((v1 - mean) * rstd * g[lane + 64]  + b[lane + 64]);
    o[lane + 128] = f2bf((v2 - mean) * rstd * g[lane + 128] + b[lane + 128]);
}

// ---------------- MFMA GEMM, double-buffered LDS + counted vmcnt ---------------------
// BM=128, BN=64, BK=64; 4 waves (2x2); XOR chunk-swizzled LDS; 1D grid, A-major
// logical order + bijective XCD-chunk swizzle (grid%8==0). KK = compile-time K.
// MODE 0: bf16 out, q-cols (<192) scaled by QSCALE_L2E ; 2: f32 out = resid + v
template <int MODE, int NY, int KK>
__global__ __launch_bounds__(256) void mfma_gemm(const ushortT* __restrict__ A,
                                                 const ushortT* __restrict__ Wt,
                                                 const float* __restrict__ bias,
                                                 const float* __restrict__ resid,
                                                 void* __restrict__ outp,
                                                 int N) {
    __shared__ ushortT As[2][128 * 64];
    __shared__ ushortT Bs[2][64 * 64];
    const int NT = KK / 64;
    int tid = threadIdx.x;
    int lane = tid & 63, wid = tid >> 6;
    int l15 = lane & 15, l4 = lane >> 4;
    int wr = wid >> 1, wc = wid & 1;
    int p = blockIdx.x;
    int cpx = gridDim.x >> 3;
    int logical = (p & 7) * cpx + (p >> 3);
    int bx = logical / NY;
    int by = logical - bx * NY;
    int bm = bx * 128, bn = by * 64;

    f32x4 acc[4][2];
#pragma unroll
    for (int mf = 0; mf < 4; ++mf)
#pragma unroll
        for (int nf = 0; nf < 2; ++nf)
#pragma unroll
            for (int r = 0; r < 4; ++r) acc[mf][nf][r] = 0.f;

    int srow = tid >> 3;
    int schunk = (tid & 7) ^ (srow & 7);
    const ushortT* agp = A + (size_t)(bm + srow) * KK + schunk * 8;
    const ushortT* bgp = Wt + (size_t)(bn + srow) * KK + schunk * 8;

    auto STAGE = [&](int buf, int t) {
        int k0 = t * 64;
#pragma unroll
        for (int i = 0; i < 4; ++i)
            GLOBAL_LOAD_LDS16(agp + (size_t)i * 32 * KK + k0, &As[buf][i * 2048 + wid * 512]);
#pragma unroll
        for (int i = 0; i < 2; ++i)
            GLOBAL_LOAD_LDS16(bgp + (size_t)i * 32 * KK + k0, &Bs[buf][i * 2048 + wid * 512]);
    };

    STAGE(0, 0);
    for (int t = 0; t < NT; ++t) {
        int cur = t & 1;
        if (t + 1 < NT) {
            STAGE(cur ^ 1, t + 1);
            asm volatile("s_waitcnt vmcnt(6)" ::: "memory");
        } else {
            asm volatile("s_waitcnt vmcnt(0)" ::: "memory");
        }
        __builtin_amdgcn_s_barrier();
        const ushortT* Asc = As[cur];
        const ushortT* Bsc = Bs[cur];
#pragma unroll
        for (int ks = 0; ks < 2; ++ks) {
            short8v af[4], bf[2];
#pragma unroll
            for (int mf = 0; mf < 4; ++mf) {
                int row = wr * 64 + mf * 16 + l15;
                af[mf] = *(const short8v*)&Asc[row * 64 + (((ks * 4 + l4) ^ (l15 & 7)) << 3)];
            }
#pragma unroll
            for (int nf = 0; nf < 2; ++nf) {
                int row = wc * 32 + nf * 16 + l15;
                bf[nf] = *(const short8v*)&Bsc[row * 64 + (((ks * 4 + l4) ^ (l15 & 7)) << 3)];
            }
#pragma unroll
            for (int mf = 0; mf < 4; ++mf)
#pragma unroll
                for (int nf = 0; nf < 2; ++nf)
                    acc[mf][nf] = __builtin_amdgcn_mfma_f32_16x16x32_bf16(af[mf], bf[nf], acc[mf][nf], 0, 0, 0);
        }
        __builtin_amdgcn_s_barrier();
    }
#pragma unroll
    for (int mf = 0; mf < 4; ++mf) {
        size_t row = (size_t)bm + wr * 64 + mf * 16 + l4 * 4;
#pragma unroll
        for (int nf = 0; nf < 2; ++nf) {
            int col = bn + wc * 32 + nf * 16 + l15;
            float bv = bias[col];
#pragma unroll
            for (int r = 0; r < 4; ++r) {
                size_t off = (row + r) * (size_t)N + col;
                float v = acc[mf][nf][r] + bv;
                if (MODE == 0) {
                    if (col < 192) v *= QSCALE_L2E;
                    ((ushortT*)outp)[off] = f2bf(v);
                } else {
                    ((float*)outp)[off] = resid[off] + v;
                }
            }
        }
    }
}

// ---------------- fused MLP: LN2 + fc1 + GELU + fc2 + residual -----------------------
// 64 rows/block, 4 waves (wave w owns rows w*16..+15). out (f32) is read (LN src +
// residual) and written in place; block-exclusive row ownership, no restrict.
// As[64][192] bf16 XOR-swizzled; per hidden chunk of 64: Bs1 (fc1 rows), Bs2 (fc2
// k-slice, k-permuted at prep) staged; y routed through Yl (cvt_pk pairs, XOR chunks).
__global__ __launch_bounds__(256, 2) void mlp_kernel(float* out,
                                                     const ushortT* __restrict__ fc1t,
                                                     const ushortT* __restrict__ fc2t,
                                                     const float* __restrict__ fc1b,
                                                     const float* __restrict__ fc2b,
                                                     const float* __restrict__ g,
                                                     const float* __restrict__ b) {
    __shared__ ushortT As[64 * 192];
    __shared__ ushortT Bs1[64 * 192];
    __shared__ ushortT Bs2[192 * 64];
    __shared__ unsigned int Yl[4][16 * 32];
    int tid = threadIdx.x, lane = tid & 63, wid = tid >> 6;
    int l15 = lane & 15, l4 = lane >> 4;
    size_t bm = (size_t)blockIdx.x * 64;

    // ---- LN2 prologue: out rows -> As (bf16, swizzled) ----
    {
        int row = tid >> 2, part = tid & 3;
        const float* xr = out + (bm + row) * 192 + part * 48;
        float v[48];
        float s = 0.f, ss = 0.f;
#pragma unroll
        for (int i = 0; i < 48; ++i) { v[i] = xr[i]; s += v[i]; ss += v[i] * v[i]; }
        s += __shfl_xor(s, 1); ss += __shfl_xor(ss, 1);
        s += __shfl_xor(s, 2); ss += __shfl_xor(ss, 2);
        float mean = s * (1.0f / 192.0f);
        float rstd = rsqrtf(ss * (1.0f / 192.0f) - mean * mean + 1e-5f);
#pragma unroll
        for (int c = 0; c < 6; ++c) {
            int chunk = part * 6 + c;             // 0..23
            int kt = chunk >> 3, w = chunk & 7;
            int wp = w ^ (row & 7);
            short8v pk8;
#pragma unroll
            for (int j = 0; j < 8; ++j) {
                int col = part * 48 + c * 8 + j;
                float nv = (v[c * 8 + j] - mean) * rstd * g[col] + b[col];
                pk8[j] = (short)f2bf(nv);
            }
            *(short8v*)&As[row * 192 + kt * 64 + wp * 8] = pk8;
        }
    }
    // staging source offsets (constant across chunks)
    int aoff1[6], aoff2[6];
#pragma unroll
    for (int i = 0; i < 6; ++i) {
        int u = tid + i * 256;
        int r1 = u / 24, rem = u - r1 * 24;
        int kt = rem >> 3, wp = rem & 7;
        aoff1[i] = r1 * 192 + kt * 64 + ((wp ^ (r1 & 7)) << 3);
        int r2 = u >> 3, wp2 = u & 7;
        aoff2[i] = r2 * 768 + ((wp2 ^ (r2 & 7)) << 3);
    }
    __syncthreads();

    f32x4 accO[12];
#pragma unroll
    for (int nf = 0; nf < 12; ++nf)
#pragma unroll
        for (int r = 0; r < 4; ++r) accO[nf][r] = 0.f;

    int arow = wid * 16 + l15;
    for (int hc = 0; hc < 12; ++hc) {
#pragma unroll
        for (int i = 0; i < 6; ++i)
            GLOBAL_LOAD_LDS16(fc1t + hc * 12288 + aoff1[i], &Bs1[(wid * 64 + i * 256) * 8]);
#pragma unroll
        for (int i = 0; i < 6; ++i)
            GLOBAL_LOAD_LDS16(fc2t + hc * 64 + aoff2[i], &Bs2[(wid * 64 + i * 256) * 8]);
        asm volatile("s_waitcnt vmcnt(0)" ::: "memory");
        __builtin_amdgcn_s_barrier();
        // GEMM1: y[16][64] per wave; fc1 bias via MFMA C-in
        f32x4 ya[4];
#pragma unroll
        for (int n = 0; n < 4; ++n) {
            float bv = fc1b[hc * 64 + n * 16 + l15];
            ya[n][0] = bv; ya[n][1] = bv; ya[n][2] = bv; ya[n][3] = bv;
        }
        __builtin_amdgcn_s_setprio(1);
#pragma unroll
        for (int kt = 0; kt < 3; ++kt)
#pragma unroll
            for (int ks = 0; ks < 2; ++ks) {
                int wp = ((ks * 4 + l4) ^ (l15 & 7)) << 3;
                short8v af = *(const short8v*)&As[arow * 192 + kt * 64 + wp];
#pragma unroll
                for (int n = 0; n < 4; ++n) {
                    short8v bf = *(const short8v*)&Bs1[(n * 16 + l15) * 192 + kt * 64 + wp];
                    ya[n] = __builtin_amdgcn_mfma_f32_16x16x32_bf16(af, bf, ya[n], 0, 0, 0);
                }
            }
        __builtin_amdgcn_s_setprio(0);
        // GELU + pack pairs (n,n+1) -> Yl rows 4*l4+r, XOR chunk swizzle
#pragma unroll
        for (int r = 0; r < 4; ++r) {
            int row = 4 * l4 + r;
            int key = row & 7;
#pragma unroll
            for (int gg = 0; gg < 2; ++gg) {
                float y0 = fast_gelu(ya[gg * 2 + 0][r]);
                float y1 = fast_gelu(ya[gg * 2 + 1][r]);
                unsigned int pk;
                asm("v_cvt_pk_bf16_f32 %0, %1, %2" : "=v"(pk) : "v"(y0), "v"(y1));
                int ucol = gg * 16 + l15;
                int ch = (ucol >> 2) ^ key;
                Yl[wid][row * 32 + ch * 4 + (ucol & 3)] = pk;
            }
        }
        // GEMM2: accO[192 cols] += y(A) @ fc2slice(B)
        __builtin_amdgcn_s_setprio(1);
#pragma unroll
        for (int gg = 0; gg < 2; ++gg) {
            u32x4 pr = *(const u32x4*)&Yl[wid][l15 * 32 + (((gg * 4 + l4) ^ (l15 & 7)) << 2)];
            short8v pa = __builtin_bit_cast(short8v, pr);
#pragma unroll
            for (int nf = 0; nf < 12; ++nf) {
                short8v bf = *(const short8v*)&Bs2[(nf * 16 + l15) * 64 + (((gg * 4 + l4) ^ (l15 & 7)) << 3)];
                accO[nf] = __builtin_amdgcn_mfma_f32_16x16x32_bf16(pa, bf, accO[nf], 0, 0, 0);
            }
        }
        __builtin_amdgcn_s_setprio(0);
        __builtin_amdgcn_s_barrier();   // Bs free for next chunk
    }
    // epilogue: out += fc2 bias + acc (residual already in out)
    size_t row0 = bm + wid * 16 + l4 * 4;
#pragma unroll
    for (int nf = 0; nf < 12; ++nf) {
        int col = nf * 16 + l15;
        float bv = fc2b[col];
#pragma unroll
        for (int r = 0; r < 4; ++r) {
            size_t off = (row0 + r) * 192 + col;
            out[off] = out[off] + bv + accO[nf][r];
        }
    }
}

// ---------------- MFMA flash attention (no-max softmax, per-mf interleave) -----------
__global__ __launch_bounds__(256, 4) void attn_mfma_kernel(const ushortT* __restrict__ qkv,
                                                           const float* __restrict__ BTf,
                                                           ushortT* __restrict__ O) {
    __shared__ ushortT Vt[32][264];
    __shared__ unsigned int Ps[4][64][20];
    int wh = blockIdx.x;
    int w = wh / 6, h = wh - w * 6;
    int wi = w >> 4, wj = w & 15;
    int tid = threadIdx.x, lane = tid & 63, wid = tid >> 6;
    int l15 = lane & 15, l4 = lane >> 4;

    {
        int t = tid;
        int pcol = (t & ~31) | (((t & 15) << 1) | ((t >> 4) & 1));
        size_t gr = (size_t)((wi * 16 + (t >> 4)) * 256 + wj * 16 + (t & 15));
        const ushortT* vp = qkv + gr * 576 + 384 + h * 32;
#pragma unroll
        for (int d0 = 0; d0 < 32; d0 += 8) {
            short8v u = *(const short8v*)(vp + d0);
#pragma unroll
            for (int j = 0; j < 8; ++j) Vt[d0 + j][pcol] = (ushortT)u[j];
        }
    }
    short8v qf[4];
    int qbase = wid * 64;
#pragma unroll
    for (int mf = 0; mf < 4; ++mf) {
        int q = qbase + mf * 16 + l15;
        size_t gr = (size_t)((wi * 16 + (q >> 4)) * 256 + wj * 16 + (q & 15));
        qf[mf] = *(const short8v*)(qkv + gr * 576 + h * 32 + l4 * 8);
    }
    __syncthreads();

    float l_run[4][4];
    f32x4 accO[4][2];
#pragma unroll
    for (int mf = 0; mf < 4; ++mf)
#pragma unroll
        for (int r = 0; r < 4; ++r) {
            l_run[mf][r] = 0.f;
            accO[mf][0][r] = 0.f;
            accO[mf][1][r] = 0.f;
        }
    const float* btb = BTf + ((size_t)(h * 8) * 32 + wid * 8) * 256 + lane * 4;

    for (int kc = 0; kc < 8; ++kc) {
        short8v kf[2];
#pragma unroll
        for (int cf = 0; cf < 2; ++cf) {
            int kv = kc * 32 + cf * 16 + l15;
            size_t gr = (size_t)((wi * 16 + (kv >> 4)) * 256 + wj * 16 + (kv & 15));
            kf[cf] = *(const short8v*)(qkv + gr * 576 + 192 + h * 32 + l4 * 8);
        }
        short8v vb[2];
#pragma unroll
        for (int nf = 0; nf < 2; ++nf)
            vb[nf] = *(const short8v*)&Vt[nf * 16 + l15][kc * 32 + l4 * 8];
#pragma unroll
        for (int mf = 0; mf < 4; ++mf) {
            f32x4 s0 = *(const f32x4*)(btb + (size_t)(kc * 32 + mf * 2 + 0) * 256);
            f32x4 s1 = *(const f32x4*)(btb + (size_t)(kc * 32 + mf * 2 + 1) * 256);
            __builtin_amdgcn_s_setprio(1);
            s0 = __builtin_amdgcn_mfma_f32_16x16x32_bf16(qf[mf], kf[0], s0, 0, 0, 0);
            s1 = __builtin_amdgcn_mfma_f32_16x16x32_bf16(qf[mf], kf[1], s1, 0, 0, 0);
            __builtin_amdgcn_s_setprio(0);
#pragma unroll
            for (int r = 0; r < 4; ++r) {
                float p0 = exp2f(s0[r]);
                float p1 = exp2f(s1[r]);
                l_run[mf][r] += p0 + p1;
                unsigned int pk;
                asm("v_cvt_pk_bf16_f32 %0, %1, %2" : "=v"(pk) : "v"(p0), "v"(p1));
                Ps[wid][mf * 16 + 4 * l4 + r][l15] = pk;
            }
            u32x4 pr = *(const u32x4*)&Ps[wid][mf * 16 + l15][l4 * 4];
            short8v pa = __builtin_bit_cast(short8v, pr);
            __builtin_amdgcn_s_setprio(1);
            accO[mf][0] = __builtin_amdgcn_mfma_f32_16x16x32_bf16(pa, vb[0], accO[mf][0], 0, 0, 0);
            accO[mf][1] = __builtin_amdgcn_mfma_f32_16x16x32_bf16(pa, vb[1], accO[mf][1], 0, 0, 0);
            __builtin_amdgcn_s_setprio(0);
        }
    }
#pragma unroll
    for (int mf = 0; mf < 4; ++mf)
#pragma unroll
        for (int r = 0; r < 4; ++r) {
            float l = l_run[mf][r];
            l += __shfl_xor(l, 1);
            l += __shfl_xor(l, 2);
            l += __shfl_xor(l, 4);
            l += __shfl_xor(l, 8);
            l_run[mf][r] = 1.0f / l;
        }
#pragma unroll
    for (int mf = 0; mf < 4; ++mf) {
        int q0 = qbase + mf * 16 + 4 * l4;
#pragma unroll
        for (int r = 0; r < 4; ++r) {
            int q = q0 + r;
            size_t gr = (size_t)((wi * 16 + (q >> 4)) * 256 + wj * 16 + (q & 15));
            ushortT* op = O + gr * 192 + h * 32 + l15;
            float inv = l_run[mf][r];
            op[0]  = f2bf(accO[mf][0][r] * inv);
            op[16] = f2bf(accO[mf][1][r] * inv);
        }
    }
}

// ---------------- launch --------------------------------------------------------------
extern "C" void kernel_launch(void* const* d_in, const int* in_sizes, int n_in,
                              void* d_out, int out_size, void* d_ws, size_t ws_size,
                              hipStream_t stream) {
    const float* x        = (const float*)d_in[0];
    const float* gamma1   = (const float*)d_in[1];
    const float* beta1    = (const float*)d_in[2];
    const float* qkv_w    = (const float*)d_in[3];
    const float* qkv_b    = (const float*)d_in[4];
    const float* proj_w   = (const float*)d_in[5];
    const float* proj_b   = (const float*)d_in[6];
    const float* pos_proj_w = (const float*)d_in[7];
    const float* pos_proj_b = (const float*)d_in[8];
    const float* ln1_g    = (const float*)d_in[9];
    const float* ln1_b    = (const float*)d_in[10];
    const float* pos1_w   = (const float*)d_in[11];
    const float* pos1_b   = (const float*)d_in[12];
    const float* ln2_g    = (const float*)d_in[13];
    const float* ln2_b    = (const float*)d_in[14];
    const float* pos2_w   = (const float*)d_in[15];
    const float* pos2_b   = (const float*)d_in[16];
    const float* ln3_g    = (const float*)d_in[17];
    const float* ln3_b    = (const float*)d_in[18];
    const float* pos3_w   = (const float*)d_in[19];
    const float* pos3_b   = (const float*)d_in[20];
    const float* gamma2   = (const float*)d_in[21];
    const float* beta2    = (const float*)d_in[22];
    const float* fc1_w    = (const float*)d_in[23];
    const float* fc1_b    = (const float*)d_in[24];
    const float* fc2_w    = (const float*)d_in[25];
    const float* fc2_b    = (const float*)d_in[26];
    float* out = (float*)d_out;

    char* ws = (char*)d_ws;
    ushortT* qkv = (ushortT*)(ws + 0);               // 75.5MB
    ushortT* xn   = (ushortT*)(ws + 100663296);      // 25.2MB (xn -> Obuf)
    ushortT* Obuf = xn;
    ushortT* qkv_wt  = (ushortT*)(ws + 125829120);
    ushortT* proj_wt = (ushortT*)(ws + 126050304);
    ushortT* fc1_wt  = (ushortT*)(ws + 126124032);
    ushortT* fc2_wt  = (ushortT*)(ws + 126418944);
    float*   BTf     = (float*)(ws + 126713856);

    // 0. prep: transposes (+ fc2 k-permutation) + bias table
    prep_kernel<<<1968, 256, 0, stream>>>(
        qkv_w, proj_w, fc1_w, fc2_w, qkv_wt, proj_wt, fc1_wt, fc2_wt,
        pos_proj_w, pos_proj_b, ln1_g, ln1_b, pos1_w, pos1_b,
        ln2_g, ln2_b, pos2_w, pos2_b, ln3_g, ln3_b, pos3_w, pos3_b, BTf);
    // 1. LN1: x -> xn (bf16)
    ln_kernel<<<M_ROWS / 4, 256, 0, stream>>>(x, gamma1, beta1, xn);
    // 2. QKV GEMM (q-cols pre-scaled)
    mfma_gemm<0, 9, 192><<<(M_ROWS / 128) * (QKV_N / 64), 256, 0, stream>>>(
        xn, qkv_wt, qkv_b, nullptr, qkv, QKV_N);
    // 3. attention -> Obuf (overwrites xn)
    attn_mfma_kernel<<<1536, 256, 0, stream>>>(qkv, BTf, Obuf);
    // 4. proj GEMM + residual -> out (f32)
    mfma_gemm<2, 3, 192><<<(M_ROWS / 128) * (DIM / 64), 256, 0, stream>>>(
        Obuf, proj_wt, proj_b, x, out, DIM);
    // 5. fused MLP: LN2 + fc1 + GELU + fc2 + residual, in-place on out
    mlp_kernel<<<M_ROWS / 64, 256, 0, stream>>>(
        out, fc1_wt, fc2_wt, fc1_b, fc2_b, gamma2, beta2);
}

// Round 10
// 206.376 us; speedup vs baseline: 5.6462x; 1.0489x over previous
//
#include <hip/hip_runtime.h>
#include <hip/hip_bf16.h>

#define DIM 192
#define HEADS 6
#define QKV_N 576
#define HIDDEN 768
#define M_ROWS 65536

typedef unsigned short ushortT;
typedef __attribute__((ext_vector_type(8))) short short8v;
typedef __attribute__((ext_vector_type(4))) float f32x4;
typedef __attribute__((ext_vector_type(4))) unsigned int u32x4;

// 1/sqrt(32) * log2(e) folded into Q columns at QKV epilogue
#define QSCALE_L2E 0.2550348649f
#define LOG2E 1.4426950408889634f

__device__ __forceinline__ float bf2f(ushortT u) {
    union { unsigned int i; float f; } c; c.i = ((unsigned int)u) << 16; return c.f;
}
__device__ __forceinline__ ushortT f2bf(float f) {
    union { float f; unsigned int i; } c; c.f = f;
    unsigned int i = c.i;
    return (ushortT)((i + 0x7fffu + ((i >> 16) & 1u)) >> 16);
}
__device__ __forceinline__ float fast_gelu(float v) {
    // x * sigmoid(1.5957691*(x + 0.044715 x^3)); exp2 domain (proven r4)
    float x3 = v * v * v;
    float z = fmaf(x3, -0.1029537917f, v * -2.302205077f);
    float e = exp2f(z);
    return v * __builtin_amdgcn_rcpf(1.0f + e);
}

#define GLOBAL_LOAD_LDS16(gp, lp) \
    __builtin_amdgcn_global_load_lds((const __attribute__((address_space(1))) void*)(gp), \
                                     (__attribute__((address_space(3))) void*)(lp), 16, 0, 0)

// ---------------- small shared MLP helper -------------------------------------------
__device__ __forceinline__ void ln_relu_mm12(const float* in, const float* g, const float* b,
                                             const float* w, const float* bb, float* out, int nout) {
    float m = 0.f;
#pragma unroll
    for (int j = 0; j < 12; ++j) m += in[j];
    m *= (1.0f / 12.0f);
    float v = 0.f;
#pragma unroll
    for (int j = 0; j < 12; ++j) { float d = in[j] - m; v += d * d; }
    v *= (1.0f / 12.0f);
    float r = rsqrtf(v + 1e-5f);
    float t[12];
#pragma unroll
    for (int j = 0; j < 12; ++j) t[j] = fmaxf((in[j] - m) * r * g[j] + b[j], 0.0f);
    for (int j2 = 0; j2 < nout; ++j2) {
        float s = bb[j2];
#pragma unroll
        for (int j = 0; j < 12; ++j) s = fmaf(t[j], w[j * nout + j2], s);
        out[j2] = s;
    }
}

// ---------------- prep: 4 weight transposes + bias table in MFMA-fragment layout -----
// blocks 0..431: 32x32 transpose tiles (fc2 gets k-slot permutation within 32-groups);
// blocks 432..1967: BTf (h*256+q per block)
__global__ __launch_bounds__(256) void prep_kernel(
        const float* __restrict__ qkv_w, const float* __restrict__ proj_w,
        const float* __restrict__ fc1_w, const float* __restrict__ fc2_w,
        ushortT* __restrict__ qkv_wt, ushortT* __restrict__ proj_wt,
        ushortT* __restrict__ fc1_wt, ushortT* __restrict__ fc2_wt,
        const float* __restrict__ pw, const float* __restrict__ pb,
        const float* __restrict__ g1, const float* __restrict__ b1,
        const float* __restrict__ w1, const float* __restrict__ bb1,
        const float* __restrict__ g2, const float* __restrict__ b2,
        const float* __restrict__ w2, const float* __restrict__ bb2,
        const float* __restrict__ g3, const float* __restrict__ b3,
        const float* __restrict__ w3, const float* __restrict__ bb3,
        float* __restrict__ BTf) {
    __shared__ float tile[32][33];
    int blk = blockIdx.x;
    int t = threadIdx.x;
    if (blk < 432) {
        const float* W; ushortT* Wt; int K, N, bx, by; bool perm = false;
        if (blk < 108)      { W = qkv_w;  Wt = qkv_wt;  K = 192; N = 576; bx = blk % 18;        by = blk / 18; }
        else if (blk < 144) { int r = blk - 108; W = proj_w; Wt = proj_wt; K = 192; N = 192; bx = r % 6;  by = r / 6; }
        else if (blk < 288) { int r = blk - 144; W = fc1_w;  Wt = fc1_wt;  K = 192; N = 768; bx = r % 24; by = r / 24; }
        else                { int r = blk - 288; W = fc2_w;  Wt = fc2_wt;  K = 768; N = 192; bx = r % 6;  by = r / 6; perm = true; }
        int tx = t & 31, ty = t >> 5;
        int bX = bx * 32, bY = by * 32;
#pragma unroll
        for (int i = 0; i < 32; i += 8)
            tile[ty + i][tx] = W[(size_t)(bY + ty + i) * N + bX + tx];
        __syncthreads();
        // k-col within 32-group; fc2 gets pk-permutation: k -> 2*(k&15) + (k>>4)
        int kcol = perm ? (((tx & 15) << 1) | (tx >> 4)) : tx;
#pragma unroll
        for (int i = 0; i < 32; i += 8)
            Wt[(size_t)(bX + ty + i) * K + bY + kcol] = f2bf(tile[tx][ty + i]);
    } else {
        int blk2 = blk - 432;                 // h*256 + q
        int h = blk2 >> 8, q = blk2 & 255, kv = t;
        float di = (float)((q >> 4) - (kv >> 4));
        float dj = (float)((q & 15) - (kv & 15));
        float a[12], hh[12];
#pragma unroll
        for (int j = 0; j < 12; ++j) a[j] = di * pw[j] + dj * pw[12 + j] + pb[j];
        ln_relu_mm12(a, g1, b1, w1, bb1, hh, 12);
        ln_relu_mm12(hh, g2, b2, w2, bb2, a, 12);
        // last layer: only head h
        float m = 0.f;
#pragma unroll
        for (int j = 0; j < 12; ++j) m += a[j];
        m *= (1.0f / 12.0f);
        float v = 0.f;
#pragma unroll
        for (int j = 0; j < 12; ++j) { float d = a[j] - m; v += d * d; }
        v *= (1.0f / 12.0f);
        float r = rsqrtf(v + 1e-5f);
        float s = bb3[h];
#pragma unroll
        for (int j = 0; j < 12; ++j)
            s = fmaf(fmaxf((a[j] - m) * r * g3[j] + b3[j], 0.0f), w3[j * 6 + h], s);
        // MFMA-fragment layout: seg = (h*8+kc)*32 + wid*8 + mf*2 + cf ; [lane][r]
        int wid = q >> 6, mf = (q >> 4) & 3, l4 = (q >> 2) & 3, rr = q & 3;
        int kc = kv >> 5, cc = kv & 31;
        int cf = (cc >> 4) & 1, l15 = cc & 15;
        int lane = l4 * 16 + l15;
        size_t off = ((size_t)((h * 8 + kc) * 32 + wid * 8 + mf * 2 + cf)) * 256 + lane * 4 + rr;
        BTf[off] = s * LOG2E;
    }
}

// ---------------- LayerNorm fp32 -> bf16, one wave per row (192) ---------------------
__global__ __launch_bounds__(256) void ln_kernel(const float* __restrict__ x,
                                                 const float* __restrict__ g,
                                                 const float* __restrict__ b,
                                                 ushortT* __restrict__ out) {
    int lane = threadIdx.x & 63;
    size_t row = (size_t)blockIdx.x * 4 + (threadIdx.x >> 6);
    const float* xr = x + row * DIM;
    float v0 = xr[lane], v1 = xr[lane + 64], v2 = xr[lane + 128];
    float s = v0 + v1 + v2;
    float ss = v0 * v0 + v1 * v1 + v2 * v2;
#pragma unroll
    for (int off = 32; off > 0; off >>= 1) {
        s += __shfl_xor(s, off);
        ss += __shfl_xor(ss, off);
    }
    float mean = s * (1.0f / DIM);
    float rstd = rsqrtf(ss * (1.0f / DIM) - mean * mean + 1e-5f);
    ushortT* o = out + row * DIM;
    o[lane]       = f2bf((v0 - mean) * rstd * g[lane]       + b[lane]);
    o[lane + 64]  = f2bf((v1 - mean) * rstd * g[lane + 64]  + b[lane + 64]);
    o[lane + 128] = f2bf((v2 - mean) * rstd * g[lane + 128] + b[lane + 128]);
}

// ---------------- MFMA GEMM, double-buffered LDS + counted vmcnt ---------------------
// BM=128, BN=64, BK=64; 4 waves (2x2); XOR chunk-swizzled LDS; 1D grid, A-major
// logical order + bijective XCD-chunk swizzle (grid%8==0). KK = compile-time K.
// MODE 0: bf16 out, q-cols (<192) scaled by QSCALE_L2E ; 2: f32 out = resid + v
template <int MODE, int NY, int KK>
__global__ __launch_bounds__(256) void mfma_gemm(const ushortT* __restrict__ A,
                                                 const ushortT* __restrict__ Wt,
                                                 const float* __restrict__ bias,
                                                 const float* __restrict__ resid,
                                                 void* __restrict__ outp,
                                                 int N) {
    __shared__ ushortT As[2][128 * 64];
    __shared__ ushortT Bs[2][64 * 64];
    const int NT = KK / 64;
    int tid = threadIdx.x;
    int lane = tid & 63, wid = tid >> 6;
    int l15 = lane & 15, l4 = lane >> 4;
    int wr = wid >> 1, wc = wid & 1;
    int p = blockIdx.x;
    int cpx = gridDim.x >> 3;
    int logical = (p & 7) * cpx + (p >> 3);
    int bx = logical / NY;
    int by = logical - bx * NY;
    int bm = bx * 128, bn = by * 64;

    f32x4 acc[4][2];
#pragma unroll
    for (int mf = 0; mf < 4; ++mf)
#pragma unroll
        for (int nf = 0; nf < 2; ++nf)
#pragma unroll
            for (int r = 0; r < 4; ++r) acc[mf][nf][r] = 0.f;

    int srow = tid >> 3;
    int schunk = (tid & 7) ^ (srow & 7);
    const ushortT* agp = A + (size_t)(bm + srow) * KK + schunk * 8;
    const ushortT* bgp = Wt + (size_t)(bn + srow) * KK + schunk * 8;

    auto STAGE = [&](int buf, int t) {
        int k0 = t * 64;
#pragma unroll
        for (int i = 0; i < 4; ++i)
            GLOBAL_LOAD_LDS16(agp + (size_t)i * 32 * KK + k0, &As[buf][i * 2048 + wid * 512]);
#pragma unroll
        for (int i = 0; i < 2; ++i)
            GLOBAL_LOAD_LDS16(bgp + (size_t)i * 32 * KK + k0, &Bs[buf][i * 2048 + wid * 512]);
    };

    STAGE(0, 0);
    for (int t = 0; t < NT; ++t) {
        int cur = t & 1;
        if (t + 1 < NT) {
            STAGE(cur ^ 1, t + 1);
            asm volatile("s_waitcnt vmcnt(6)" ::: "memory");
        } else {
            asm volatile("s_waitcnt vmcnt(0)" ::: "memory");
        }
        __builtin_amdgcn_s_barrier();
        const ushortT* Asc = As[cur];
        const ushortT* Bsc = Bs[cur];
#pragma unroll
        for (int ks = 0; ks < 2; ++ks) {
            short8v af[4], bf[2];
#pragma unroll
            for (int mf = 0; mf < 4; ++mf) {
                int row = wr * 64 + mf * 16 + l15;
                af[mf] = *(const short8v*)&Asc[row * 64 + (((ks * 4 + l4) ^ (l15 & 7)) << 3)];
            }
#pragma unroll
            for (int nf = 0; nf < 2; ++nf) {
                int row = wc * 32 + nf * 16 + l15;
                bf[nf] = *(const short8v*)&Bsc[row * 64 + (((ks * 4 + l4) ^ (l15 & 7)) << 3)];
            }
#pragma unroll
            for (int mf = 0; mf < 4; ++mf)
#pragma unroll
                for (int nf = 0; nf < 2; ++nf)
                    acc[mf][nf] = __builtin_amdgcn_mfma_f32_16x16x32_bf16(af[mf], bf[nf], acc[mf][nf], 0, 0, 0);
        }
        __builtin_amdgcn_s_barrier();
    }
#pragma unroll
    for (int mf = 0; mf < 4; ++mf) {
        size_t row = (size_t)bm + wr * 64 + mf * 16 + l4 * 4;
#pragma unroll
        for (int nf = 0; nf < 2; ++nf) {
            int col = bn + wc * 32 + nf * 16 + l15;
            float bv = bias[col];
#pragma unroll
            for (int r = 0; r < 4; ++r) {
                size_t off = (row + r) * (size_t)N + col;
                float v = acc[mf][nf][r] + bv;
                if (MODE == 0) {
                    if (col < 192) v *= QSCALE_L2E;
                    ((ushortT*)outp)[off] = f2bf(v);
                } else {
                    ((float*)outp)[off] = resid[off] + v;
                }
            }
        }
    }
}

// ---------------- fused MLP v2: LN2 + fc1 + GELU + fc2 + residual --------------------
// 64 rows/block, 4 waves (wave w owns rows w*16..+15). A-operand (LN'd x) lives in
// REGISTERS in MFMA A-frag layout (row=l15, k=l4*8+j within each (kt,ks) 32-block);
// LN reduce via shfl_xor(16/32) across the 4 lanes sharing a row. LDS: Bs1 dbuf 48K +
// Bs2 24K + Yl 8K = 80KB -> 2 blocks/CU. Counted vmcnt, no full drains (T4).
__global__ __launch_bounds__(256, 2) void mlp_kernel(float* out,
                                                     const ushortT* __restrict__ fc1t,
                                                     const ushortT* __restrict__ fc2t,
                                                     const float* __restrict__ fc1b,
                                                     const float* __restrict__ fc2b,
                                                     const float* __restrict__ g,
                                                     const float* __restrict__ b) {
    __shared__ ushortT Bs1[2][64 * 192];
    __shared__ ushortT Bs2[192 * 64];
    __shared__ unsigned int Yl[4][16 * 32];
    int tid = threadIdx.x, lane = tid & 63, wid = tid >> 6;
    int l15 = lane & 15, l4 = lane >> 4;
    size_t bm = (size_t)blockIdx.x * 64;

    // staging source offsets (constant across chunks)
    int aoff1[6], aoff2[6];
#pragma unroll
    for (int i = 0; i < 6; ++i) {
        int u = tid + i * 256;
        int r1 = u / 24, rem = u - r1 * 24;
        int kt = rem >> 3, wp = rem & 7;
        aoff1[i] = r1 * 192 + kt * 64 + ((wp ^ (r1 & 7)) << 3);
        int r2 = u >> 3, wp2 = u & 7;
        aoff2[i] = r2 * 768 + ((wp2 ^ (r2 & 7)) << 3);
    }
    auto STAGE_B1 = [&](int buf, int hc) {
#pragma unroll
        for (int i = 0; i < 6; ++i)
            GLOBAL_LOAD_LDS16(fc1t + hc * 12288 + aoff1[i], &Bs1[buf][(wid * 64 + i * 256) * 8]);
    };
    auto STAGE_B2 = [&](int hc) {
#pragma unroll
        for (int i = 0; i < 6; ++i)
            GLOBAL_LOAD_LDS16(fc2t + hc * 64 + aoff2[i], &Bs2[(wid * 64 + i * 256) * 8]);
    };

    STAGE_B1(0, 0);   // first fc1 slice in flight under the LN prologue

    // ---- LN2 prologue directly into A-fragments (registers) ----
    short8v af[6];
    {
        int row = wid * 16 + l15;
        const float* xr = out + (bm + row) * 192;
        float v[6][8];
        float s = 0.f, ss = 0.f;
#pragma unroll
        for (int f = 0; f < 6; ++f) {
            int base = (f >> 1) * 64 + (f & 1) * 32 + l4 * 8;
            f32x4 a0 = *(const f32x4*)(xr + base);
            f32x4 a1 = *(const f32x4*)(xr + base + 4);
#pragma unroll
            for (int j = 0; j < 4; ++j) {
                v[f][j] = a0[j]; v[f][4 + j] = a1[j];
                s += a0[j] + a1[j];
                ss += a0[j] * a0[j] + a1[j] * a1[j];
            }
        }
        s += __shfl_xor(s, 16); ss += __shfl_xor(ss, 16);
        s += __shfl_xor(s, 32); ss += __shfl_xor(ss, 32);
        float mean = s * (1.0f / 192.0f);
        float rstd = rsqrtf(ss * (1.0f / 192.0f) - mean * mean + 1e-5f);
#pragma unroll
        for (int f = 0; f < 6; ++f) {
            int base = (f >> 1) * 64 + (f & 1) * 32 + l4 * 8;
#pragma unroll
            for (int j = 0; j < 8; ++j)
                af[f][j] = (short)f2bf((v[f][j] - mean) * rstd * g[base + j] + b[base + j]);
        }
    }

    f32x4 accO[12];
#pragma unroll
    for (int nf = 0; nf < 12; ++nf)
#pragma unroll
        for (int r = 0; r < 4; ++r) accO[nf][r] = 0.f;

    for (int hc = 0; hc < 12; ++hc) {
        int cur = hc & 1;
        if (hc < 11) STAGE_B1(cur ^ 1, hc + 1);
        STAGE_B2(hc);
        if (hc < 11) asm volatile("s_waitcnt vmcnt(12)" ::: "memory");  // B1(cur) landed
        else         asm volatile("s_waitcnt vmcnt(6)"  ::: "memory");
        __builtin_amdgcn_s_barrier();
        // GEMM1: y[16][64] per wave; fc1 bias via MFMA C-in
        f32x4 ya[4];
#pragma unroll
        for (int n = 0; n < 4; ++n) {
            float bv = fc1b[hc * 64 + n * 16 + l15];
            ya[n][0] = bv; ya[n][1] = bv; ya[n][2] = bv; ya[n][3] = bv;
        }
        __builtin_amdgcn_s_setprio(1);
#pragma unroll
        for (int kt = 0; kt < 3; ++kt)
#pragma unroll
            for (int ks = 0; ks < 2; ++ks) {
                int wp = ((ks * 4 + l4) ^ (l15 & 7)) << 3;
#pragma unroll
                for (int n = 0; n < 4; ++n) {
                    short8v bf = *(const short8v*)&Bs1[cur][(n * 16 + l15) * 192 + kt * 64 + wp];
                    ya[n] = __builtin_amdgcn_mfma_f32_16x16x32_bf16(af[kt * 2 + ks], bf, ya[n], 0, 0, 0);
                }
            }
        __builtin_amdgcn_s_setprio(0);
        // GELU + pack pairs (n,n+1) -> Yl rows 4*l4+r, XOR chunk swizzle
#pragma unroll
        for (int r = 0; r < 4; ++r) {
            int row = 4 * l4 + r;
            int key = row & 7;
#pragma unroll
            for (int gg = 0; gg < 2; ++gg) {
                float y0 = fast_gelu(ya[gg * 2 + 0][r]);
                float y1 = fast_gelu(ya[gg * 2 + 1][r]);
                unsigned int pk;
                asm("v_cvt_pk_bf16_f32 %0, %1, %2" : "=v"(pk) : "v"(y0), "v"(y1));
                int ucol = gg * 16 + l15;
                int ch = (ucol >> 2) ^ key;
                Yl[wid][row * 32 + ch * 4 + (ucol & 3)] = pk;
            }
        }
        if (hc < 11) asm volatile("s_waitcnt vmcnt(6)" ::: "memory");   // B2(hc) landed
        else         asm volatile("s_waitcnt vmcnt(0)" ::: "memory");
        __builtin_amdgcn_s_barrier();
        // GEMM2: accO[192 cols] += y(A) @ fc2slice(B)
        __builtin_amdgcn_s_setprio(1);
#pragma unroll
        for (int gg = 0; gg < 2; ++gg) {
            u32x4 pr = *(const u32x4*)&Yl[wid][l15 * 32 + (((gg * 4 + l4) ^ (l15 & 7)) << 2)];
            short8v pa = __builtin_bit_cast(short8v, pr);
#pragma unroll
            for (int nf = 0; nf < 12; ++nf) {
                short8v bf = *(const short8v*)&Bs2[(nf * 16 + l15) * 64 + (((gg * 4 + l4) ^ (l15 & 7)) << 3)];
                accO[nf] = __builtin_amdgcn_mfma_f32_16x16x32_bf16(pa, bf, accO[nf], 0, 0, 0);
            }
        }
        __builtin_amdgcn_s_setprio(0);
        __builtin_amdgcn_s_barrier();   // Bs2/Bs1[cur] free for overwrite next chunk
    }
    // epilogue: out += fc2 bias + acc (residual already in out)
    size_t row0 = bm + wid * 16 + l4 * 4;
#pragma unroll
    for (int nf = 0; nf < 12; ++nf) {
        int col = nf * 16 + l15;
        float bv = fc2b[col];
#pragma unroll
        for (int r = 0; r < 4; ++r) {
            size_t off = (row0 + r) * 192 + col;
            out[off] = out[off] + bv + accO[nf][r];
        }
    }
}

// ---------------- MFMA flash attention (no-max softmax, per-mf interleave) -----------
__global__ __launch_bounds__(256, 4) void attn_mfma_kernel(const ushortT* __restrict__ qkv,
                                                           const float* __restrict__ BTf,
                                                           ushortT* __restrict__ O) {
    __shared__ ushortT Vt[32][264];
    __shared__ unsigned int Ps[4][64][20];
    int wh = blockIdx.x;
    int w = wh / 6, h = wh - w * 6;
    int wi = w >> 4, wj = w & 15;
    int tid = threadIdx.x, lane = tid & 63, wid = tid >> 6;
    int l15 = lane & 15, l4 = lane >> 4;

    {
        int t = tid;
        int pcol = (t & ~31) | (((t & 15) << 1) | ((t >> 4) & 1));
        size_t gr = (size_t)((wi * 16 + (t >> 4)) * 256 + wj * 16 + (t & 15));
        const ushortT* vp = qkv + gr * 576 + 384 + h * 32;
#pragma unroll
        for (int d0 = 0; d0 < 32; d0 += 8) {
            short8v u = *(const short8v*)(vp + d0);
#pragma unroll
            for (int j = 0; j < 8; ++j) Vt[d0 + j][pcol] = (ushortT)u[j];
        }
    }
    short8v qf[4];
    int qbase = wid * 64;
#pragma unroll
    for (int mf = 0; mf < 4; ++mf) {
        int q = qbase + mf * 16 + l15;
        size_t gr = (size_t)((wi * 16 + (q >> 4)) * 256 + wj * 16 + (q & 15));
        qf[mf] = *(const short8v*)(qkv + gr * 576 + h * 32 + l4 * 8);
    }
    __syncthreads();

    float l_run[4][4];
    f32x4 accO[4][2];
#pragma unroll
    for (int mf = 0; mf < 4; ++mf)
#pragma unroll
        for (int r = 0; r < 4; ++r) {
            l_run[mf][r] = 0.f;
            accO[mf][0][r] = 0.f;
            accO[mf][1][r] = 0.f;
        }
    const float* btb = BTf + ((size_t)(h * 8) * 32 + wid * 8) * 256 + lane * 4;

    for (int kc = 0; kc < 8; ++kc) {
        short8v kf[2];
#pragma unroll
        for (int cf = 0; cf < 2; ++cf) {
            int kv = kc * 32 + cf * 16 + l15;
            size_t gr = (size_t)((wi * 16 + (kv >> 4)) * 256 + wj * 16 + (kv & 15));
            kf[cf] = *(const short8v*)(qkv + gr * 576 + 192 + h * 32 + l4 * 8);
        }
        short8v vb[2];
#pragma unroll
        for (int nf = 0; nf < 2; ++nf)
            vb[nf] = *(const short8v*)&Vt[nf * 16 + l15][kc * 32 + l4 * 8];
#pragma unroll
        for (int mf = 0; mf < 4; ++mf) {
            f32x4 s0 = *(const f32x4*)(btb + (size_t)(kc * 32 + mf * 2 + 0) * 256);
            f32x4 s1 = *(const f32x4*)(btb + (size_t)(kc * 32 + mf * 2 + 1) * 256);
            __builtin_amdgcn_s_setprio(1);
            s0 = __builtin_amdgcn_mfma_f32_16x16x32_bf16(qf[mf], kf[0], s0, 0, 0, 0);
            s1 = __builtin_amdgcn_mfma_f32_16x16x32_bf16(qf[mf], kf[1], s1, 0, 0, 0);
            __builtin_amdgcn_s_setprio(0);
#pragma unroll
            for (int r = 0; r < 4; ++r) {
                float p0 = exp2f(s0[r]);
                float p1 = exp2f(s1[r]);
                l_run[mf][r] += p0 + p1;
                unsigned int pk;
                asm("v_cvt_pk_bf16_f32 %0, %1, %2" : "=v"(pk) : "v"(p0), "v"(p1));
                Ps[wid][mf * 16 + 4 * l4 + r][l15] = pk;
            }
            u32x4 pr = *(const u32x4*)&Ps[wid][mf * 16 + l15][l4 * 4];
            short8v pa = __builtin_bit_cast(short8v, pr);
            __builtin_amdgcn_s_setprio(1);
            accO[mf][0] = __builtin_amdgcn_mfma_f32_16x16x32_bf16(pa, vb[0], accO[mf][0], 0, 0, 0);
            accO[mf][1] = __builtin_amdgcn_mfma_f32_16x16x32_bf16(pa, vb[1], accO[mf][1], 0, 0, 0);
            __builtin_amdgcn_s_setprio(0);
        }
    }
#pragma unroll
    for (int mf = 0; mf < 4; ++mf)
#pragma unroll
        for (int r = 0; r < 4; ++r) {
            float l = l_run[mf][r];
            l += __shfl_xor(l, 1);
            l += __shfl_xor(l, 2);
            l += __shfl_xor(l, 4);
            l += __shfl_xor(l, 8);
            l_run[mf][r] = 1.0f / l;
        }
#pragma unroll
    for (int mf = 0; mf < 4; ++mf) {
        int q0 = qbase + mf * 16 + 4 * l4;
#pragma unroll
        for (int r = 0; r < 4; ++r) {
            int q = q0 + r;
            size_t gr = (size_t)((wi * 16 + (q >> 4)) * 256 + wj * 16 + (q & 15));
            ushortT* op = O + gr * 192 + h * 32 + l15;
            float inv = l_run[mf][r];
            op[0]  = f2bf(accO[mf][0][r] * inv);
            op[16] = f2bf(accO[mf][1][r] * inv);
        }
    }
}

// ---------------- launch --------------------------------------------------------------
extern "C" void kernel_launch(void* const* d_in, const int* in_sizes, int n_in,
                              void* d_out, int out_size, void* d_ws, size_t ws_size,
                              hipStream_t stream) {
    const float* x        = (const float*)d_in[0];
    const float* gamma1   = (const float*)d_in[1];
    const float* beta1    = (const float*)d_in[2];
    const float* qkv_w    = (const float*)d_in[3];
    const float* qkv_b    = (const float*)d_in[4];
    const float* proj_w   = (const float*)d_in[5];
    const float* proj_b   = (const float*)d_in[6];
    const float* pos_proj_w = (const float*)d_in[7];
    const float* pos_proj_b = (const float*)d_in[8];
    const float* ln1_g    = (const float*)d_in[9];
    const float* ln1_b    = (const float*)d_in[10];
    const float* pos1_w   = (const float*)d_in[11];
    const float* pos1_b   = (const float*)d_in[12];
    const float* ln2_g    = (const float*)d_in[13];
    const float* ln2_b    = (const float*)d_in[14];
    const float* pos2_w   = (const float*)d_in[15];
    const float* pos2_b   = (const float*)d_in[16];
    const float* ln3_g    = (const float*)d_in[17];
    const float* ln3_b    = (const float*)d_in[18];
    const float* pos3_w   = (const float*)d_in[19];
    const float* pos3_b   = (const float*)d_in[20];
    const float* gamma2   = (const float*)d_in[21];
    const float* beta2    = (const float*)d_in[22];
    const float* fc1_w    = (const float*)d_in[23];
    const float* fc1_b    = (const float*)d_in[24];
    const float* fc2_w    = (const float*)d_in[25];
    const float* fc2_b    = (const float*)d_in[26];
    float* out = (float*)d_out;

    char* ws = (char*)d_ws;
    ushortT* qkv = (ushortT*)(ws + 0);               // 75.5MB
    ushortT* xn   = (ushortT*)(ws + 100663296);      // 25.2MB (xn -> Obuf)
    ushortT* Obuf = xn;
    ushortT* qkv_wt  = (ushortT*)(ws + 125829120);
    ushortT* proj_wt = (ushortT*)(ws + 126050304);
    ushortT* fc1_wt  = (ushortT*)(ws + 126124032);
    ushortT* fc2_wt  = (ushortT*)(ws + 126418944);
    float*   BTf     = (float*)(ws + 126713856);

    // 0. prep: transposes (+ fc2 k-permutation) + bias table
    prep_kernel<<<1968, 256, 0, stream>>>(
        qkv_w, proj_w, fc1_w, fc2_w, qkv_wt, proj_wt, fc1_wt, fc2_wt,
        pos_proj_w, pos_proj_b, ln1_g, ln1_b, pos1_w, pos1_b,
        ln2_g, ln2_b, pos2_w, pos2_b, ln3_g, ln3_b, pos3_w, pos3_b, BTf);
    // 1. LN1: x -> xn (bf16)
    ln_kernel<<<M_ROWS / 4, 256, 0, stream>>>(x, gamma1, beta1, xn);
    // 2. QKV GEMM (q-cols pre-scaled)
    mfma_gemm<0, 9, 192><<<(M_ROWS / 128) * (QKV_N / 64), 256, 0, stream>>>(
        xn, qkv_wt, qkv_b, nullptr, qkv, QKV_N);
    // 3. attention -> Obuf (overwrites xn)
    attn_mfma_kernel<<<1536, 256, 0, stream>>>(qkv, BTf, Obuf);
    // 4. proj GEMM + residual -> out (f32)
    mfma_gemm<2, 3, 192><<<(M_ROWS / 128) * (DIM / 64), 256, 0, stream>>>(
        Obuf, proj_wt, proj_b, x, out, DIM);
    // 5. fused MLP v2: LN2 + fc1 + GELU + fc2 + residual, in-place on out
    mlp_kernel<<<M_ROWS / 64, 256, 0, stream>>>(
        out, fc1_wt, fc2_wt, fc1_b, fc2_b, gamma2, beta2);
}